// Round 3
// baseline (1495.822 us; speedup 1.0000x reference)
//
#include <hip/hip_runtime.h>

typedef unsigned short ushort_t;

#define N_NODES 50000
#define N_EDGES 1600000
#define NB      64
#define IN_F    16
#define HF      128
#define LF      64
#define NC      6
#define EPSBN   1e-5f

// output element offsets (element units, dtype-agnostic)
#define OPRED_OFF 0
#define OMU_OFF   384
#define OLV_OFF   3200384
#define ONOI_OFF  6400384

// bf16 bits -> float (exact)
__device__ __forceinline__ float bf2f(ushort_t v) {
    union { unsigned u; float f; } x; x.u = ((unsigned)v) << 16; return x.f;
}
// float -> bf16 bits, round-to-nearest-even (finite values)
__device__ __forceinline__ ushort_t f2bf(float f) {
    union { float f; unsigned u; } x; x.f = f;
    unsigned u = x.u;
    unsigned r = (u + 0x7FFFu + ((u >> 16) & 1u)) >> 16;
    return (ushort_t)r;
}
__device__ __forceinline__ int clampi(int v, int lo, int hi) {
    return v < lo ? lo : (v > hi ? hi : v);
}
// write output element honoring detected dtype (f32 flag)
__device__ __forceinline__ void wout(void* outp, int f32, int idx, float v) {
    if (f32) ((float*)outp)[idx] = v;
    else     ((ushort_t*)outp)[idx] = f2bf(v);
}

// ============ dtype detection ============
// flags[0] = 1 if float arrays are fp32 (else bf16)
// flags[1] = 1 if int arrays are int64 (else int32)
__global__ void detect_k(const ushort_t* win_raw, const int* ei_raw, int* flags) {
    __shared__ int c0s, c1s;
    int t = threadIdx.x;
    if (t == 0) { c0s = 0; c1s = 0; }
    __syncthreads();
    // If fp32: even ushort positions are low mantissa halves -> random exponents, ~46% huge.
    // If bf16: they are real weights, |v| <= 0.25.
    float v = bf2f(win_raw[2 * t]);
    if (!(fabsf(v) <= 1e3f)) atomicAdd(&c0s, 1);   // huge or NaN pattern
    // If int64: odd int32 positions are upper halves == 0 (values < 2^31).
    if (ei_raw[2 * t + 1] != 0) atomicAdd(&c1s, 1);
    __syncthreads();
    if (t == 0) {
        flags[0] = (c0s >= 16) ? 1 : 0;
        flags[1] = (c1s == 0) ? 1 : 0;
    }
}

// ============ convert all float inputs to fp32 in cbuf ============
#define NSEG 34
#define CTOTAL 2482376
struct ConvArgs {
    const void* src[NSEG];
    int pre[NSEG + 1];
};
__global__ __launch_bounds__(256) void convert_all_k(ConvArgs a, float* __restrict__ dst,
                                                     const int* __restrict__ flags) {
    int g = blockIdx.x * 256 + threadIdx.x;
    if (g >= CTOTAL) return;
    int lo = 0, hi = NSEG - 1;
    while (lo < hi) { int mid = (lo + hi + 1) >> 1; if (a.pre[mid] <= g) lo = mid; else hi = mid - 1; }
    int o = g - a.pre[lo];
    float v;
    if (flags[0]) v = ((const float*)a.src[lo])[o];
    else          v = bf2f(((const ushort_t*)a.src[lo])[o]);
    dst[g] = v;
}

// ============ init / prep (all-fp32 sources) ============
__global__ void init_k(float* deg, int* hist, float* gpool, float* zsum, float* cnt,
                       float* Wcat, float* bcat, float* sc1, float* sh1, float* sc2, float* sh2,
                       const float* Wmu, const float* bmu, const float* Wlv, const float* blv,
                       const float* g1, const float* be1, const float* rm1, const float* rv1,
                       const float* g2, const float* be2, const float* rm2, const float* rv2) {
    int i = blockIdx.x * 256 + threadIdx.x;
    if (i < N_NODES) { deg[i] = 1.0f; hist[i] = 0; }
    if (i < NB * LF) { gpool[i] = 0.f; zsum[i] = 0.f; }
    if (i < NB) cnt[i] = 0.f;
    if (i < HF * HF) {
        int k = i >> 7, c = i & 127;
        Wcat[i] = (c < 64) ? Wmu[k * 64 + c] : Wlv[k * 64 + (c - 64)];
    }
    if (i < HF) {
        bcat[i] = (i < 64) ? bmu[i] : blv[i - 64];
        float s1 = g1[i] * rsqrtf(rv1[i] + EPSBN);
        sc1[i] = s1; sh1[i] = be1[i] - rm1[i] * s1;
        float s2 = g2[i] * rsqrtf(rv2[i] + EPSBN);
        sc2[i] = s2; sh2[i] = be2[i] - rm2[i] * s2;
    }
}

// ============ degree + histogram ============
__global__ void scatter_deg_k(const int* ei, const float* ew, float* deg, int* hist,
                              const int* flags) {
    int e = blockIdx.x * 256 + threadIdx.x;
    if (e >= N_EDGES) return;
    int i64 = flags[1];
    int di = N_EDGES + e;
    int d = clampi(ei[i64 ? 2 * di : di], 0, N_NODES - 1);
    atomicAdd(&deg[d], ew[e]);
    atomicAdd(&hist[d], 1);
}

__global__ void dinv_k(const float* deg, float* dinv) {
    int n = blockIdx.x * 256 + threadIdx.x;
    if (n < N_NODES) dinv[n] = rsqrtf(deg[n]);
}

// ============ scan (counting sort by dst) ============
__global__ void scan_blocks_k(const int* hist, int* offs, int* bsums) {
    __shared__ int sh[1024];
    int tid = threadIdx.x;
    int i = blockIdx.x * 1024 + tid;
    int v = (i < N_NODES) ? hist[i] : 0;
    sh[tid] = v;
    __syncthreads();
    for (int d = 1; d < 1024; d <<= 1) {
        int t = (tid >= d) ? sh[tid - d] : 0;
        __syncthreads();
        sh[tid] += t;
        __syncthreads();
    }
    int incl = sh[tid];
    if (i < N_NODES) offs[i] = incl - v;
    if (tid == 1023) bsums[blockIdx.x] = incl;
}

__global__ void scan_sums_k(int* bsums, int nb) {
    if (threadIdx.x == 0 && blockIdx.x == 0) {
        int acc = 0;
        for (int b = 0; b < nb; b++) { int v = bsums[b]; bsums[b] = acc; acc += v; }
    }
}

__global__ void scan_fin_k(int* offs, int* cursor, const int* bsums) {
    int i = blockIdx.x * 1024 + threadIdx.x;
    if (i < N_NODES) {
        int v = offs[i] + bsums[i >> 10];
        offs[i] = v; cursor[i] = v;
    }
    if (i == 0) offs[N_NODES] = N_EDGES;
}

__global__ void scatter_edges_k(const int* ei, const float* ew, const float* dinv,
                                int* cursor, ushort_t* srcS, float* wS, const int* flags) {
    int e = blockIdx.x * 256 + threadIdx.x;
    if (e >= N_EDGES) return;
    int i64 = flags[1];
    int di = N_EDGES + e;
    int s = clampi(ei[i64 ? 2 * e : e], 0, N_NODES - 1);
    int d = clampi(ei[i64 ? 2 * di : di], 0, N_NODES - 1);
    int p = atomicAdd(&cursor[d], 1);
    srcS[p] = (ushort_t)s;
    wS[p] = ew[e] * dinv[s] * dinv[d];
}

// ============ input GEMM: x[N,16] @ W_in[16,128] + b ============
__global__ __launch_bounds__(128) void gemm_in_k(const float* __restrict__ x,
                                                 const float* __restrict__ Win,
                                                 const float* __restrict__ bin,
                                                 float* __restrict__ out) {
    __shared__ float xl[16 * 16];
    int tid = threadIdx.x;
    int row0 = blockIdx.x * 16;
    if (tid < 64) {
        int r = tid >> 2, k4 = tid & 3;
        int row = row0 + r;
        float4 v = make_float4(0.f, 0.f, 0.f, 0.f);
        if (row < N_NODES) v = *(const float4*)(x + row * 16 + k4 * 4);
        *(float4*)(xl + r * 16 + k4 * 4) = v;
    }
    float wv[16];
#pragma unroll
    for (int k = 0; k < 16; k++) wv[k] = Win[k * 128 + tid];
    float bias = bin[tid];
    __syncthreads();
    for (int r = 0; r < 16; r++) {
        float acc = bias;
#pragma unroll
        for (int k = 0; k < 16; k++) acc += xl[r * 16 + k] * wv[k];
        int row = row0 + r;
        if (row < N_NODES) out[row * 128 + tid] = acc;
    }
}

// ============ main GEMM: in[N,128] @ W[128,128] + b -> out[N,128] ============
__global__ __launch_bounds__(256) void gemm128_k(const float* __restrict__ in,
                                                 const float* __restrict__ W,
                                                 const float* __restrict__ b,
                                                 float* __restrict__ out) {
    __shared__ float At[64 * 128];
    int tid = threadIdx.x;
    int row0 = blockIdx.x * 64;
    for (int v = tid; v < (64 * 128) / 4; v += 256) {
        int r = v >> 5, kk = v & 31;
        int row = row0 + r;
        float4 val = make_float4(0.f, 0.f, 0.f, 0.f);
        if (row < N_NODES) val = *(const float4*)(in + row * 128 + kk * 4);
        *(float4*)(At + r * 128 + kk * 4) = val;
    }
    __syncthreads();

    int cp = tid & 63, rg = tid >> 6;
    int c0 = cp * 2;
    float acc0[16], acc1[16];
    float bx = b[c0], by = b[c0 + 1];
#pragma unroll
    for (int r = 0; r < 16; r++) { acc0[r] = bx; acc1[r] = by; }

    for (int kb = 0; kb < 128; kb += 4) {
        float wx[4], wy[4];
#pragma unroll
        for (int j = 0; j < 4; j++) {
            float2 w = *(const float2*)(W + (kb + j) * 128 + c0);
            wx[j] = w.x; wy[j] = w.y;
        }
#pragma unroll
        for (int r = 0; r < 16; r++) {
            float4 a = *(const float4*)(At + (rg * 16 + r) * 128 + kb);
            acc0[r] += a.x * wx[0] + a.y * wx[1] + a.z * wx[2] + a.w * wx[3];
            acc1[r] += a.x * wy[0] + a.y * wy[1] + a.z * wy[2] + a.w * wy[3];
        }
    }
#pragma unroll
    for (int r = 0; r < 16; r++) {
        int row = row0 + rg * 16 + r;
        if (row < N_NODES) {
            float2 o = make_float2(acc0[r], acc1[r]);
            *(float2*)(out + row * 128 + c0) = o;
        }
    }
}

// ============ aggregation (gather over dst-sorted edges) ============
template <int MODE>
__global__ __launch_bounds__(256) void agg_k(const float* __restrict__ lin,
                                             const int* __restrict__ offs,
                                             const ushort_t* __restrict__ srcS,
                                             const float* __restrict__ wS,
                                             const float* __restrict__ dinv,
                                             const float* __restrict__ sc,
                                             const float* __restrict__ sh,
                                             float* __restrict__ outF,
                                             float* __restrict__ zb,
                                             void* __restrict__ outp,
                                             const int* __restrict__ flags) {
    int tid = threadIdx.x;
    int n = blockIdx.x * 2 + (tid >> 7);
    int t = tid & 127;
    float dv = dinv[n];
    float acc = lin[n * 128 + t] * dv * dv;
    int e0 = offs[n], e1 = offs[n + 1];
    for (int e = e0; e < e1; e++) {
        acc += wS[e] * lin[(int)srcS[e] * 128 + t];
    }
    if (MODE == 0) {
        float o = acc * sc[t] + sh[t];
        outF[n * 128 + t] = fmaxf(o, 0.f);
    } else {
        int f32 = flags[0];
        if (t < 64) {
            zb[n * 64 + t] = acc;
            wout(outp, f32, OMU_OFF + n * 64 + t, acc);
        } else {
            wout(outp, f32, OLV_OFF + n * 64 + (t - 64), acc);
        }
    }
}

// ============ attention logits ============
__global__ __launch_bounds__(128) void att_k(const float* __restrict__ zb,
                                             const float* __restrict__ Wa1,
                                             const float* __restrict__ ba1,
                                             const float* __restrict__ Wa2,
                                             const float* __restrict__ ba2,
                                             float* __restrict__ logits) {
    __shared__ float Wl[64 * 128];
    __shared__ float zl[32 * 64];
    __shared__ float wa2s[128];
    __shared__ float red2[2];
    int tid = threadIdx.x;
    for (int i = tid; i < 64 * 128; i += 128) Wl[i] = Wa1[i];
    wa2s[tid] = Wa2[tid];
    int row0 = blockIdx.x * 32;
    for (int v = tid; v < 512; v += 128) {
        int r = v >> 4, kk = v & 15;
        int row = row0 + r;
        float4 val = make_float4(0.f, 0.f, 0.f, 0.f);
        if (row < N_NODES) val = *(const float4*)(zb + row * 64 + kk * 4);
        *(float4*)(zl + r * 64 + kk * 4) = val;
    }
    float ba1v = ba1[tid];
    float ba2v = ba2[0];
    __syncthreads();
    for (int r = 0; r < 32; r++) {
        float acc = ba1v;
#pragma unroll
        for (int k = 0; k < 64; k += 4) {
            float4 z4 = *(const float4*)(zl + r * 64 + k);
            acc += z4.x * Wl[(k + 0) * 128 + tid];
            acc += z4.y * Wl[(k + 1) * 128 + tid];
            acc += z4.z * Wl[(k + 2) * 128 + tid];
            acc += z4.w * Wl[(k + 3) * 128 + tid];
        }
        float v = tanhf(acc) * wa2s[tid];
        for (int off = 32; off > 0; off >>= 1) v += __shfl_down(v, off, 64);
        if ((tid & 63) == 0) red2[tid >> 6] = v;
        __syncthreads();
        if (tid == 0) {
            int row = row0 + r;
            if (row < N_NODES) logits[row] = red2[0] + red2[1] + ba2v;
        }
        __syncthreads();
    }
}

// ============ softmax reduction ============
__global__ __launch_bounds__(1024) void smax_k(const float* __restrict__ logits, float* red) {
    __shared__ float sm[1024];
    int tid = threadIdx.x;
    float m = -1e30f;
    for (int i = tid; i < N_NODES; i += 1024) m = fmaxf(m, logits[i]);
    sm[tid] = m;
    __syncthreads();
    for (int s = 512; s > 0; s >>= 1) {
        if (tid < s) sm[tid] = fmaxf(sm[tid], sm[tid + s]);
        __syncthreads();
    }
    float mm = sm[0];
    __syncthreads();
    float ssum = 0.f;
    for (int i = tid; i < N_NODES; i += 1024) ssum += expf(logits[i] - mm);
    sm[tid] = ssum;
    __syncthreads();
    for (int s = 512; s > 0; s >>= 1) {
        if (tid < s) sm[tid] += sm[tid + s];
        __syncthreads();
    }
    if (tid == 0) { red[0] = mm; red[1] = sm[0]; }
}

// ============ pooling ============
__global__ __launch_bounds__(64) void pool_k(const float* __restrict__ zb,
                                             const float* __restrict__ logits,
                                             const int* __restrict__ batch,
                                             const float* __restrict__ red,
                                             float* gpool, float* zsum, float* cnt,
                                             const int* __restrict__ flags) {
    int l = threadIdx.x;
    int i64 = flags[1];
    const int CHUNK = 128;
    int nstart = blockIdx.x * CHUNK;
    float m = red[0];
    float ag = 0.f, az = 0.f, c = 0.f;
    int cur = -1;
    for (int i = 0; i < CHUNK; i++) {
        int n = nstart + i;
        if (n >= N_NODES) break;
        int b = clampi(batch[i64 ? 2 * n : n], 0, NB - 1);
        if (b != cur) {
            if (cur >= 0) {
                atomicAdd(&gpool[cur * 64 + l], ag);
                atomicAdd(&zsum[cur * 64 + l], az);
                if (l == 0) atomicAdd(&cnt[cur], c);
            }
            cur = b; ag = 0.f; az = 0.f; c = 0.f;
        }
        float zv = zb[n * 64 + l];
        float p = expf(logits[n] - m);
        ag += p * zv; az += zv; c += 1.f;
    }
    if (cur >= 0) {
        atomicAdd(&gpool[cur * 64 + l], ag);
        atomicAdd(&zsum[cur * 64 + l], az);
        if (l == 0) atomicAdd(&cnt[cur], c);
    }
}

// ============ per-graph heads ============
__global__ __launch_bounds__(128) void head_k(const float* __restrict__ gpool,
                                              const float* __restrict__ zsum,
                                              const float* __restrict__ cnt,
                                              const float* __restrict__ red,
                                              const float* Wc1, const float* bc1,
                                              const float* Wc2, const float* bc2,
                                              const float* Wc3, const float* bc3,
                                              const float* Wn1, const float* bn1,
                                              const float* Wn2, const float* bn2,
                                              void* outp, const int* __restrict__ flags) {
    __shared__ float gsh[64], zm[64], p1[128], p2[64], n1[64];
    int b = blockIdx.x, t = threadIdx.x;
    float S = red[1];
    if (t < 64) {
        gsh[t] = gpool[b * 64 + t] / S;
        zm[t] = zsum[b * 64 + t] / fmaxf(cnt[b], 1.f);
    }
    __syncthreads();
    {
        float acc = bc1[t];
        for (int k = 0; k < 64; k++) acc += gsh[k] * Wc1[k * 128 + t];
        p1[t] = fmaxf(acc, 0.f);
    }
    __syncthreads();
    if (t < 64) {
        float acc = bc2[t];
        for (int k = 0; k < 128; k++) acc += p1[k] * Wc2[k * 64 + t];
        p2[t] = fmaxf(acc, 0.f);
    } else {
        int tt = t - 64;
        float acc = bn1[tt];
        for (int k = 0; k < 64; k++) acc += zm[k] * Wn1[k * 64 + tt];
        n1[tt] = fmaxf(acc, 0.f);
    }
    __syncthreads();
    int f32 = flags[0];
    if (t < NC) {
        float acc = bc3[t];
        for (int k = 0; k < 64; k++) acc += p2[k] * Wc3[k * 6 + t];
        wout(outp, f32, OPRED_OFF + b * 6 + t, acc);
    }
    if (t == 64) {
        float acc = bn2[0];
        for (int k = 0; k < 64; k++) acc += n1[k] * Wn2[k];
        float s = 1.f / (1.f + expf(-acc));
        wout(outp, f32, ONOI_OFF + b, s);
    }
}

extern "C" void kernel_launch(void* const* d_in, const int* in_sizes, int n_in,
                              void* d_out, int out_size, void* d_ws, size_t ws_size,
                              hipStream_t stream) {
    const int* ei    = (const int*)d_in[1];
    const int* batch = (const int*)d_in[3];

    // workspace layout
    char* ws = (char*)d_ws;
    size_t o = 0;
    auto alloc = [&](size_t bytes) { size_t r = o; o = (o + bytes + 511) & ~((size_t)511); return r; };
    int*   flags  = (int*)  (ws + alloc(16));
    float* cbuf   = (float*)(ws + alloc((size_t)CTOTAL * 4));
    float* deg    = (float*)(ws + alloc(N_NODES * 4));
    float* dinv   = (float*)(ws + alloc(N_NODES * 4));
    int*   offs   = (int*)  (ws + alloc((N_NODES + 1) * 4));
    int*   cursor = (int*)  (ws + alloc(N_NODES * 4));
    ushort_t* srcS= (ushort_t*)(ws + alloc(N_EDGES * 2));
    float* wS     = (float*)(ws + alloc(N_EDGES * 4));
    float* logits = (float*)(ws + alloc(N_NODES * 4));
    float* Wcat   = (float*)(ws + alloc(HF * HF * 4));
    float* bcat   = (float*)(ws + alloc(HF * 4));
    float* sc1    = (float*)(ws + alloc(HF * 4));
    float* sh1    = (float*)(ws + alloc(HF * 4));
    float* sc2    = (float*)(ws + alloc(HF * 4));
    float* sh2    = (float*)(ws + alloc(HF * 4));
    float* red    = (float*)(ws + alloc(16));
    float* gpool  = (float*)(ws + alloc(NB * LF * 4));
    float* zsum   = (float*)(ws + alloc(NB * LF * 4));
    float* cnt    = (float*)(ws + alloc(NB * 4));
    int*   bsums  = (int*)  (ws + alloc(64 * 4));
    float* bufA   = (float*)(ws + alloc((size_t)N_NODES * 128 * 4));
    float* bufB   = (float*)(ws + alloc((size_t)N_NODES * 128 * 4));
    float* zb     = bufA;
    (void)ws_size; (void)n_in; (void)in_sizes; (void)out_size;

    // converted fp32 views into cbuf
    static const int seg_din[NSEG] = {0, 2, 4, 5, 6, 7, 8, 9, 10, 11, 12, 13,
                                      14, 15, 16, 17, 18, 19, 20, 21,
                                      22, 23, 24, 25, 26, 27, 28, 29, 30, 31, 32, 33, 34, 35};
    static const int seg_cnt[NSEG] = {800000, 1600000, 2048, 128, 16384, 128, 16384, 128,
                                      8192, 64, 8192, 64,
                                      128, 128, 128, 128, 128, 128, 128, 128,
                                      8192, 128, 128, 1, 8192, 128, 8192, 64, 384, 6, 4096, 64, 64, 1};
    ConvArgs ca;
    int pre = 0;
    int off_tab[NSEG];
    for (int i = 0; i < NSEG; i++) {
        ca.src[i] = d_in[seg_din[i]];
        ca.pre[i] = pre;
        off_tab[i] = pre;
        pre += seg_cnt[i];
    }
    ca.pre[NSEG] = pre;  // == CTOTAL

    const float* cx   = cbuf + off_tab[0];
    const float* cew  = cbuf + off_tab[1];
    const float* cWin = cbuf + off_tab[2];
    const float* cbin = cbuf + off_tab[3];
    const float* cW1  = cbuf + off_tab[4];
    const float* cb1  = cbuf + off_tab[5];
    const float* cW2  = cbuf + off_tab[6];
    const float* cb2  = cbuf + off_tab[7];
    const float* cWmu = cbuf + off_tab[8];
    const float* cbmu = cbuf + off_tab[9];
    const float* cWlv = cbuf + off_tab[10];
    const float* cblv = cbuf + off_tab[11];
    const float* cg1  = cbuf + off_tab[12];
    const float* cbe1 = cbuf + off_tab[13];
    const float* crm1 = cbuf + off_tab[14];
    const float* crv1 = cbuf + off_tab[15];
    const float* cg2  = cbuf + off_tab[16];
    const float* cbe2 = cbuf + off_tab[17];
    const float* crm2 = cbuf + off_tab[18];
    const float* crv2 = cbuf + off_tab[19];
    const float* cWa1 = cbuf + off_tab[20];
    const float* cba1 = cbuf + off_tab[21];
    const float* cWa2 = cbuf + off_tab[22];
    const float* cba2 = cbuf + off_tab[23];
    const float* cWc1 = cbuf + off_tab[24];
    const float* cbc1 = cbuf + off_tab[25];
    const float* cWc2 = cbuf + off_tab[26];
    const float* cbc2 = cbuf + off_tab[27];
    const float* cWc3 = cbuf + off_tab[28];
    const float* cbc3 = cbuf + off_tab[29];
    const float* cWn1 = cbuf + off_tab[30];
    const float* cbn1 = cbuf + off_tab[31];
    const float* cWn2 = cbuf + off_tab[32];
    const float* cbn2 = cbuf + off_tab[33];

    const int GN = (N_NODES + 255) / 256;
    const int GE = (N_EDGES + 255) / 256;
    const int GS = (N_NODES + 1023) / 1024;
    const int GC = (CTOTAL + 255) / 256;

    hipLaunchKernelGGL(detect_k, dim3(1), dim3(256), 0, stream,
                       (const ushort_t*)d_in[4], (const int*)d_in[1], flags);
    hipLaunchKernelGGL(convert_all_k, dim3(GC), dim3(256), 0, stream, ca, cbuf, flags);

    hipLaunchKernelGGL(init_k, dim3(GN), dim3(256), 0, stream,
                       deg, cursor, gpool, zsum, cnt, Wcat, bcat, sc1, sh1, sc2, sh2,
                       cWmu, cbmu, cWlv, cblv, cg1, cbe1, crm1, crv1, cg2, cbe2, crm2, crv2);
    hipLaunchKernelGGL(scatter_deg_k, dim3(GE), dim3(256), 0, stream, ei, cew, deg, cursor, flags);
    hipLaunchKernelGGL(dinv_k, dim3(GN), dim3(256), 0, stream, deg, dinv);
    hipLaunchKernelGGL(scan_blocks_k, dim3(GS), dim3(1024), 0, stream, cursor, offs, bsums);
    hipLaunchKernelGGL(scan_sums_k, dim3(1), dim3(64), 0, stream, bsums, GS);
    hipLaunchKernelGGL(scan_fin_k, dim3(GS), dim3(1024), 0, stream, offs, cursor, bsums);
    hipLaunchKernelGGL(scatter_edges_k, dim3(GE), dim3(256), 0, stream, ei, cew, dinv, cursor, srcS, wS, flags);

    // encoder
    hipLaunchKernelGGL(gemm_in_k, dim3(N_NODES / 16), dim3(128), 0, stream, cx, cWin, cbin, bufA);
    const int GG = (N_NODES + 63) / 64;
    hipLaunchKernelGGL(gemm128_k, dim3(GG), dim3(256), 0, stream, bufA, cW1, cb1, bufB);
    hipLaunchKernelGGL((agg_k<0>), dim3(N_NODES / 2), dim3(256), 0, stream,
                       bufB, offs, srcS, wS, dinv, sc1, sh1, bufA, (float*)nullptr,
                       (void*)nullptr, flags);
    hipLaunchKernelGGL(gemm128_k, dim3(GG), dim3(256), 0, stream, bufA, cW2, cb2, bufB);
    hipLaunchKernelGGL((agg_k<0>), dim3(N_NODES / 2), dim3(256), 0, stream,
                       bufB, offs, srcS, wS, dinv, sc2, sh2, bufA, (float*)nullptr,
                       (void*)nullptr, flags);
    hipLaunchKernelGGL(gemm128_k, dim3(GG), dim3(256), 0, stream, bufA, Wcat, bcat, bufB);
    hipLaunchKernelGGL((agg_k<1>), dim3(N_NODES / 2), dim3(256), 0, stream,
                       bufB, offs, srcS, wS, dinv, (const float*)nullptr, (const float*)nullptr,
                       (float*)nullptr, zb, d_out, flags);

    // attention + pooling + heads
    hipLaunchKernelGGL(att_k, dim3((N_NODES + 31) / 32), dim3(128), 0, stream,
                       zb, cWa1, cba1, cWa2, cba2, logits);
    hipLaunchKernelGGL(smax_k, dim3(1), dim3(1024), 0, stream, logits, red);
    hipLaunchKernelGGL(pool_k, dim3((N_NODES + 127) / 128), dim3(64), 0, stream,
                       zb, logits, batch, red, gpool, zsum, cnt, flags);
    hipLaunchKernelGGL(head_k, dim3(NB), dim3(128), 0, stream,
                       gpool, zsum, cnt, red, cWc1, cbc1, cWc2, cbc2, cWc3, cbc3,
                       cWn1, cbn1, cWn2, cbn2, d_out, flags);
}

// Round 4
// 774.720 us; speedup vs baseline: 1.9308x; 1.9308x over previous
//
#include <hip/hip_runtime.h>
#include <hip/hip_fp16.h>

typedef unsigned short ushort_t;

#define N_NODES 50000
#define N_EDGES 1600000
#define NB      64
#define HF      128
#define LF      64
#define NC      6
#define EPSBN   1e-5f

// output element offsets (fp32 out confirmed in round 3)
#define OPRED_OFF 0
#define OMU_OFF   384
#define OLV_OFF   3200384
#define ONOI_OFF  6400384

__device__ __forceinline__ int clampi(int v, int lo, int hi) {
    return v < lo ? lo : (v > hi ? hi : v);
}

// ============ int-width detection (flags[1] = 1 if int64) ============
__global__ void detect_k(const int* ei_raw, int* flags) {
    __shared__ int c1s;
    if (threadIdx.x == 0) c1s = 0;
    __syncthreads();
    if (ei_raw[2 * threadIdx.x + 1] != 0) atomicAdd(&c1s, 1);
    __syncthreads();
    if (threadIdx.x == 0) flags[1] = (c1s == 0) ? 1 : 0;
}

// ============ init: zero hist/pools/red, fold BN, build Wcat ============
__global__ void init_k(int* hist, float* gpool, float* zsum, float* cnt, float* red,
                       float* Wcat, float* bcat, float* sc1, float* sh1, float* sc2, float* sh2,
                       const float* Wmu, const float* bmu, const float* Wlv, const float* blv,
                       const float* g1, const float* be1, const float* rm1, const float* rv1,
                       const float* g2, const float* be2, const float* rm2, const float* rv2) {
    int i = blockIdx.x * 256 + threadIdx.x;
    if (i < N_NODES) hist[i] = 0;
    if (i < NB * LF) { gpool[i] = 0.f; zsum[i] = 0.f; }
    if (i < NB) cnt[i] = 0.f;
    if (i < 4) red[i] = 0.f;
    if (i < HF * HF) {
        int k = i >> 7, c = i & 127;
        Wcat[i] = (c < 64) ? Wmu[k * 64 + c] : Wlv[k * 64 + (c - 64)];
    }
    if (i < HF) {
        bcat[i] = (i < 64) ? bmu[i] : blv[i - 64];
        float s1 = g1[i] * rsqrtf(rv1[i] + EPSBN);
        sc1[i] = s1; sh1[i] = be1[i] - rm1[i] * s1;
        float s2 = g2[i] * rsqrtf(rv2[i] + EPSBN);
        sc2[i] = s2; sh2[i] = be2[i] - rm2[i] * s2;
    }
}

// ============ dst histogram (int atomics only) ============
__global__ void hist_k(const int* ei, int* hist, const int* flags) {
    int e = blockIdx.x * 256 + threadIdx.x;
    if (e >= N_EDGES) return;
    int i64 = flags[1];
    int di = N_EDGES + e;
    int d = clampi(ei[i64 ? 2 * di : di], 0, N_NODES - 1);
    atomicAdd(&hist[d], 1);
}

// ============ scan (counting sort by dst) ============
__global__ void scan_blocks_k(const int* hist, int* offs, int* bsums) {
    __shared__ int sh[1024];
    int tid = threadIdx.x;
    int i = blockIdx.x * 1024 + tid;
    int v = (i < N_NODES) ? hist[i] : 0;
    sh[tid] = v;
    __syncthreads();
    for (int d = 1; d < 1024; d <<= 1) {
        int t = (tid >= d) ? sh[tid - d] : 0;
        __syncthreads();
        sh[tid] += t;
        __syncthreads();
    }
    int incl = sh[tid];
    if (i < N_NODES) offs[i] = incl - v;
    if (tid == 1023) bsums[blockIdx.x] = incl;
}

__global__ void scan_sums_k(int* bsums, int nb) {
    if (threadIdx.x == 0 && blockIdx.x == 0) {
        int acc = 0;
        for (int b = 0; b < nb; b++) { int v = bsums[b]; bsums[b] = acc; acc += v; }
    }
}

__global__ void scan_fin_k(int* offs, int* cursor, const int* bsums) {
    int i = blockIdx.x * 1024 + threadIdx.x;
    if (i < N_NODES) {
        int v = offs[i] + bsums[i >> 10];
        offs[i] = v; cursor[i] = v;
    }
    if (i == 0) offs[N_NODES] = N_EDGES;
}

// ============ scatter edges into dst-sorted order ============
__global__ void scatter_edges_k(const int* ei, const float* ew,
                                int* cursor, ushort_t* srcS, ushort_t* dstS, float* ewS,
                                const int* flags) {
    int e = blockIdx.x * 256 + threadIdx.x;
    if (e >= N_EDGES) return;
    int i64 = flags[1];
    int di = N_EDGES + e;
    int s = clampi(ei[i64 ? 2 * e : e], 0, N_NODES - 1);
    int d = clampi(ei[i64 ? 2 * di : di], 0, N_NODES - 1);
    int p = atomicAdd(&cursor[d], 1);
    srcS[p] = (ushort_t)s;
    dstS[p] = (ushort_t)d;
    ewS[p] = ew[e];
}

// ============ degree (segmented sum, no atomics) -> dinv ============
__global__ void deginv_k(const int* offs, const float* ewS, float* dinv) {
    int n = blockIdx.x * 256 + threadIdx.x;
    if (n >= N_NODES) return;
    float s = 1.0f;
    int e1 = offs[n + 1];
    for (int e = offs[n]; e < e1; e++) s += ewS[e];
    dinv[n] = rsqrtf(s);
}

// ============ edge weights ============
__global__ void ws_k(const ushort_t* srcS, const ushort_t* dstS, const float* ewS,
                     const float* dinv, float* wS) {
    int e = blockIdx.x * 256 + threadIdx.x;
    if (e >= N_EDGES) return;
    wS[e] = ewS[e] * dinv[(int)srcS[e]] * dinv[(int)dstS[e]];
}

// ============ input GEMM: x[N,16] @ W_in[16,128] + b -> h0 (fp16) ============
__global__ __launch_bounds__(128) void gemm_in_k(const float* __restrict__ x,
                                                 const float* __restrict__ Win,
                                                 const float* __restrict__ bin,
                                                 __half* __restrict__ out) {
    __shared__ float xl[16 * 16];
    int tid = threadIdx.x;
    int row0 = blockIdx.x * 16;
    if (tid < 64) {
        int r = tid >> 2, k4 = tid & 3;
        int row = row0 + r;
        float4 v = make_float4(0.f, 0.f, 0.f, 0.f);
        if (row < N_NODES) v = *(const float4*)(x + row * 16 + k4 * 4);
        *(float4*)(xl + r * 16 + k4 * 4) = v;
    }
    float wv[16];
#pragma unroll
    for (int k = 0; k < 16; k++) wv[k] = Win[k * 128 + tid];
    float bias = bin[tid];
    __syncthreads();
    for (int r = 0; r < 16; r++) {
        float acc = bias;
#pragma unroll
        for (int k = 0; k < 16; k++) acc += xl[r * 16 + k] * wv[k];
        int row = row0 + r;
        if (row < N_NODES) out[row * 128 + tid] = __float2half(acc);
    }
}

// ============ main GEMM: in(fp16)[N,128] @ W(fp32)[128,128] + b -> out(fp16) ============
__global__ __launch_bounds__(256) void gemm128_k(const __half* __restrict__ in,
                                                 const float* __restrict__ W,
                                                 const float* __restrict__ b,
                                                 __half* __restrict__ out) {
    __shared__ float At[64 * 128];
    int tid = threadIdx.x;
    int row0 = blockIdx.x * 64;
    union HU { unsigned u; __half2 h; };
    for (int v = tid; v < 1024; v += 256) {     // 64 rows x 16 uint4 (8 halves each)
        int r = v >> 4, c8 = (v & 15) * 8;
        int row = row0 + r;
        uint4 raw = make_uint4(0u, 0u, 0u, 0u);
        if (row < N_NODES) raw = *(const uint4*)(in + row * 128 + c8);
        HU u0, u1, u2, u3;
        u0.u = raw.x; u1.u = raw.y; u2.u = raw.z; u3.u = raw.w;
        float2 f0 = __half22float2(u0.h), f1 = __half22float2(u1.h);
        float2 f2 = __half22float2(u2.h), f3 = __half22float2(u3.h);
        *(float4*)(At + r * 128 + c8)     = make_float4(f0.x, f0.y, f1.x, f1.y);
        *(float4*)(At + r * 128 + c8 + 4) = make_float4(f2.x, f2.y, f3.x, f3.y);
    }
    __syncthreads();

    int cp = tid & 63, rg = tid >> 6;
    int c0 = cp * 2;
    float acc0[16], acc1[16];
    float bx = b[c0], by = b[c0 + 1];
#pragma unroll
    for (int r = 0; r < 16; r++) { acc0[r] = bx; acc1[r] = by; }

    for (int kb = 0; kb < 128; kb += 4) {
        float wx[4], wy[4];
#pragma unroll
        for (int j = 0; j < 4; j++) {
            float2 w = *(const float2*)(W + (kb + j) * 128 + c0);
            wx[j] = w.x; wy[j] = w.y;
        }
#pragma unroll
        for (int r = 0; r < 16; r++) {
            float4 a = *(const float4*)(At + (rg * 16 + r) * 128 + kb);
            acc0[r] += a.x * wx[0] + a.y * wx[1] + a.z * wx[2] + a.w * wx[3];
            acc1[r] += a.x * wy[0] + a.y * wy[1] + a.z * wy[2] + a.w * wy[3];
        }
    }
#pragma unroll
    for (int r = 0; r < 16; r++) {
        int row = row0 + rg * 16 + r;
        if (row < N_NODES) {
            *(__half2*)(out + row * 128 + c0) = __floats2half2_rn(acc0[r], acc1[r]);
        }
    }
}

// ============ aggregation: 1 wave per node, half2 lanes, 8x-unrolled gather ============
// MODE 0: BN+ReLU -> outH (fp16).  MODE 1: mu/logvar -> zb (fp32) + fp32 outputs.
template <int MODE>
__global__ __launch_bounds__(256) void agg_k(const __half* __restrict__ lin,
                                             const int* __restrict__ offs,
                                             const ushort_t* __restrict__ srcS,
                                             const float* __restrict__ wS,
                                             const float* __restrict__ dinv,
                                             const float* __restrict__ sc,
                                             const float* __restrict__ sh,
                                             __half* __restrict__ outH,
                                             float* __restrict__ zb,
                                             float* __restrict__ outp) {
    int tid = threadIdx.x;
    int n = blockIdx.x * 4 + (tid >> 6);
    int t = tid & 63;                       // features 2t, 2t+1
    const __half2* linv = (const __half2*)lin;
    float dv = dinv[n];
    float2 self = __half22float2(linv[n * 64 + t]);
    float ax = self.x * dv * dv, ay = self.y * dv * dv;
    int e0 = offs[n], e1 = offs[n + 1];
    int e = e0;
    for (; e + 8 <= e1; e += 8) {
        int s[8]; float w[8]; __half2 h[8];
#pragma unroll
        for (int j = 0; j < 8; j++) { s[j] = srcS[e + j]; w[j] = wS[e + j]; }
#pragma unroll
        for (int j = 0; j < 8; j++) h[j] = linv[s[j] * 64 + t];
#pragma unroll
        for (int j = 0; j < 8; j++) {
            float2 f = __half22float2(h[j]);
            ax += w[j] * f.x; ay += w[j] * f.y;
        }
    }
    for (; e < e1; e++) {
        float2 f = __half22float2(linv[(int)srcS[e] * 64 + t]);
        float w = wS[e];
        ax += w * f.x; ay += w * f.y;
    }
    if (MODE == 0) {
        float2 s2 = *(const float2*)(sc + 2 * t);
        float2 h2 = *(const float2*)(sh + 2 * t);
        float o0 = fmaxf(ax * s2.x + h2.x, 0.f);
        float o1 = fmaxf(ay * s2.y + h2.y, 0.f);
        *(__half2*)(outH + n * 128 + 2 * t) = __floats2half2_rn(o0, o1);
    } else {
        if (t < 32) {
            *(float2*)(zb + n * 64 + 2 * t) = make_float2(ax, ay);
            *(float2*)(outp + OMU_OFF + n * 64 + 2 * t) = make_float2(ax, ay);
        } else {
            int c = 2 * t - 64;
            *(float2*)(outp + OLV_OFF + n * 64 + c) = make_float2(ax, ay);
        }
    }
}

// ============ attention: p[n] = exp(tanh(z Wa1 + ba1) Wa2 + ba2); sum into red[1] ============
__global__ __launch_bounds__(256) void att_k(const float* __restrict__ zb,
                                             const float* __restrict__ Wa1,
                                             const float* __restrict__ ba1,
                                             const float* __restrict__ Wa2,
                                             const float* __restrict__ ba2,
                                             float* __restrict__ p, float* __restrict__ red) {
    __shared__ float Wl[64 * 128];   // 32 KB
    __shared__ float zl[64 * 64];    // 16 KB
    int tid = threadIdx.x;
    for (int v = tid; v < 2048; v += 256) *(float4*)(Wl + v * 4) = *(const float4*)(Wa1 + v * 4);
    int row0 = blockIdx.x * 64;
    for (int v = tid; v < 1024; v += 256) {
        int r = v >> 4, k4 = (v & 15) * 4;
        int row = row0 + r;
        float4 val = make_float4(0.f, 0.f, 0.f, 0.f);
        if (row < N_NODES) val = *(const float4*)(zb + row * 64 + k4);
        *(float4*)(zl + r * 64 + k4) = val;
    }
    int w = tid >> 6, lam = tid & 63;
    float b0 = ba1[lam], b1 = ba1[lam + 64];
    float a0 = Wa2[lam], a1 = Wa2[lam + 64];
    float ba2v = ba2[0];
    __syncthreads();
    float wsum = 0.f;
    for (int i = 0; i < 16; i++) {
        int r = w * 16 + i;
        int row = row0 + r;
        float acc0 = b0, acc1 = b1;
        const float* zr = zl + r * 64;
#pragma unroll 4
        for (int k = 0; k < 64; k++) {
            float zv = zr[k];
            acc0 += zv * Wl[k * 128 + lam];
            acc1 += zv * Wl[k * 128 + lam + 64];
        }
        float y = tanhf(acc0) * a0 + tanhf(acc1) * a1;
#pragma unroll
        for (int off = 32; off > 0; off >>= 1) y += __shfl_down(y, off, 64);
        if (lam == 0 && row < N_NODES) {
            float pe = expf(y + ba2v);
            p[row] = pe;
            wsum += pe;
        }
    }
    if (lam == 0) atomicAdd(&red[1], wsum);
}

// ============ pooling (4 groups of 64 per block) ============
__global__ __launch_bounds__(256) void pool_k(const float* __restrict__ zb,
                                              const float* __restrict__ p,
                                              const int* __restrict__ batch,
                                              float* gpool, float* zsum, float* cnt,
                                              const int* __restrict__ flags) {
    int l = threadIdx.x & 63, g = threadIdx.x >> 6;
    int i64 = flags[1];
    int nstart = blockIdx.x * 256 + g * 64;
    float ag = 0.f, az = 0.f, c = 0.f;
    int cur = -1;
    for (int i = 0; i < 64; i++) {
        int n = nstart + i;
        if (n >= N_NODES) break;
        int b = clampi(batch[i64 ? 2 * n : n], 0, NB - 1);
        if (b != cur) {
            if (cur >= 0) {
                atomicAdd(&gpool[cur * 64 + l], ag);
                atomicAdd(&zsum[cur * 64 + l], az);
                if (l == 0) atomicAdd(&cnt[cur], c);
            }
            cur = b; ag = 0.f; az = 0.f; c = 0.f;
        }
        float pe = p[n];
        float zv = zb[n * 64 + l];
        ag += pe * zv; az += zv; c += 1.f;
    }
    if (cur >= 0) {
        atomicAdd(&gpool[cur * 64 + l], ag);
        atomicAdd(&zsum[cur * 64 + l], az);
        if (l == 0) atomicAdd(&cnt[cur], c);
    }
}

// ============ per-graph heads ============
__global__ __launch_bounds__(128) void head_k(const float* __restrict__ gpool,
                                              const float* __restrict__ zsum,
                                              const float* __restrict__ cnt,
                                              const float* __restrict__ red,
                                              const float* Wc1, const float* bc1,
                                              const float* Wc2, const float* bc2,
                                              const float* Wc3, const float* bc3,
                                              const float* Wn1, const float* bn1,
                                              const float* Wn2, const float* bn2,
                                              float* __restrict__ outp) {
    __shared__ float gsh[64], zm[64], p1[128], p2[64], n1[64];
    int b = blockIdx.x, t = threadIdx.x;
    float S = red[1];
    if (t < 64) {
        gsh[t] = gpool[b * 64 + t] / S;
        zm[t] = zsum[b * 64 + t] / fmaxf(cnt[b], 1.f);
    }
    __syncthreads();
    {
        float acc = bc1[t];
        for (int k = 0; k < 64; k++) acc += gsh[k] * Wc1[k * 128 + t];
        p1[t] = fmaxf(acc, 0.f);
    }
    __syncthreads();
    if (t < 64) {
        float acc = bc2[t];
        for (int k = 0; k < 128; k++) acc += p1[k] * Wc2[k * 64 + t];
        p2[t] = fmaxf(acc, 0.f);
    } else {
        int tt = t - 64;
        float acc = bn1[tt];
        for (int k = 0; k < 64; k++) acc += zm[k] * Wn1[k * 64 + tt];
        n1[tt] = fmaxf(acc, 0.f);
    }
    __syncthreads();
    if (t < NC) {
        float acc = bc3[t];
        for (int k = 0; k < 64; k++) acc += p2[k] * Wc3[k * 6 + t];
        outp[OPRED_OFF + b * 6 + t] = acc;
    }
    if (t == 64) {
        float acc = bn2[0];
        for (int k = 0; k < 64; k++) acc += n1[k] * Wn2[k];
        outp[ONOI_OFF + b] = 1.f / (1.f + expf(-acc));
    }
}

extern "C" void kernel_launch(void* const* d_in, const int* in_sizes, int n_in,
                              void* d_out, int out_size, void* d_ws, size_t ws_size,
                              hipStream_t stream) {
    const int*   ei    = (const int*)d_in[1];
    const int*   batch = (const int*)d_in[3];
    const float* x     = (const float*)d_in[0];
    const float* ew    = (const float*)d_in[2];
    const float* Win   = (const float*)d_in[4];
    const float* bin   = (const float*)d_in[5];
    const float* W1    = (const float*)d_in[6];
    const float* b1    = (const float*)d_in[7];
    const float* W2    = (const float*)d_in[8];
    const float* b2    = (const float*)d_in[9];
    const float* Wmu   = (const float*)d_in[10];
    const float* bmu   = (const float*)d_in[11];
    const float* Wlv   = (const float*)d_in[12];
    const float* blv   = (const float*)d_in[13];
    const float* g1    = (const float*)d_in[14];
    const float* be1   = (const float*)d_in[15];
    const float* rm1   = (const float*)d_in[16];
    const float* rv1   = (const float*)d_in[17];
    const float* g2    = (const float*)d_in[18];
    const float* be2   = (const float*)d_in[19];
    const float* rm2   = (const float*)d_in[20];
    const float* rv2   = (const float*)d_in[21];
    const float* Wa1   = (const float*)d_in[22];
    const float* ba1   = (const float*)d_in[23];
    const float* Wa2   = (const float*)d_in[24];
    const float* ba2   = (const float*)d_in[25];
    const float* Wc1   = (const float*)d_in[26];
    const float* bc1   = (const float*)d_in[27];
    const float* Wc2   = (const float*)d_in[28];
    const float* bc2   = (const float*)d_in[29];
    const float* Wc3   = (const float*)d_in[30];
    const float* bc3   = (const float*)d_in[31];
    const float* Wn1   = (const float*)d_in[32];
    const float* bn1   = (const float*)d_in[33];
    const float* Wn2   = (const float*)d_in[34];
    const float* bn2   = (const float*)d_in[35];

    float* outp = (float*)d_out;

    // workspace layout
    char* ws = (char*)d_ws;
    size_t o = 0;
    auto alloc = [&](size_t bytes) { size_t r = o; o = (o + bytes + 511) & ~((size_t)511); return r; };
    int*      flags  = (int*)     (ws + alloc(16));
    float*    dinv   = (float*)   (ws + alloc(N_NODES * 4));
    int*      offs   = (int*)     (ws + alloc((N_NODES + 1) * 4));
    int*      cursor = (int*)     (ws + alloc(N_NODES * 4));   // doubles as hist
    ushort_t* srcS   = (ushort_t*)(ws + alloc(N_EDGES * 2));
    ushort_t* dstS   = (ushort_t*)(ws + alloc(N_EDGES * 2));
    float*    ewS    = (float*)   (ws + alloc(N_EDGES * 4));
    float*    wS     = (float*)   (ws + alloc(N_EDGES * 4));
    float*    pexp   = (float*)   (ws + alloc(N_NODES * 4));
    float*    Wcat   = (float*)   (ws + alloc(HF * HF * 4));
    float*    bcat   = (float*)   (ws + alloc(HF * 4));
    float*    sc1    = (float*)   (ws + alloc(HF * 4));
    float*    sh1    = (float*)   (ws + alloc(HF * 4));
    float*    sc2    = (float*)   (ws + alloc(HF * 4));
    float*    sh2    = (float*)   (ws + alloc(HF * 4));
    float*    red    = (float*)   (ws + alloc(16));
    float*    gpool  = (float*)   (ws + alloc(NB * LF * 4));
    float*    zsum   = (float*)   (ws + alloc(NB * LF * 4));
    float*    cnt    = (float*)   (ws + alloc(NB * 4));
    int*      bsums  = (int*)     (ws + alloc(64 * 4));
    __half*   bufA   = (__half*)  (ws + alloc((size_t)N_NODES * 128 * 2));
    __half*   bufB   = (__half*)  (ws + alloc((size_t)N_NODES * 128 * 2));
    float*    zb     = (float*)   (ws + alloc((size_t)N_NODES * 64 * 4));
    (void)ws_size; (void)n_in; (void)in_sizes; (void)out_size;

    const int GN = (N_NODES + 255) / 256;     // 196
    const int GE = (N_EDGES + 255) / 256;     // 6250
    const int GS = (N_NODES + 1023) / 1024;   // 49

    hipLaunchKernelGGL(detect_k, dim3(1), dim3(256), 0, stream, ei, flags);
    hipLaunchKernelGGL(init_k, dim3(GN), dim3(256), 0, stream,
                       cursor, gpool, zsum, cnt, red, Wcat, bcat, sc1, sh1, sc2, sh2,
                       Wmu, bmu, Wlv, blv, g1, be1, rm1, rv1, g2, be2, rm2, rv2);
    hipLaunchKernelGGL(hist_k, dim3(GE), dim3(256), 0, stream, ei, cursor, flags);
    hipLaunchKernelGGL(scan_blocks_k, dim3(GS), dim3(1024), 0, stream, cursor, offs, bsums);
    hipLaunchKernelGGL(scan_sums_k, dim3(1), dim3(64), 0, stream, bsums, GS);
    hipLaunchKernelGGL(scan_fin_k, dim3(GS), dim3(1024), 0, stream, offs, cursor, bsums);
    hipLaunchKernelGGL(scatter_edges_k, dim3(GE), dim3(256), 0, stream,
                       ei, ew, cursor, srcS, dstS, ewS, flags);
    hipLaunchKernelGGL(deginv_k, dim3(GN), dim3(256), 0, stream, offs, ewS, dinv);
    hipLaunchKernelGGL(ws_k, dim3(GE), dim3(256), 0, stream, srcS, dstS, ewS, dinv, wS);

    // encoder
    hipLaunchKernelGGL(gemm_in_k, dim3(N_NODES / 16), dim3(128), 0, stream, x, Win, bin, bufA);
    const int GG = (N_NODES + 63) / 64;       // 782
    const int GA = N_NODES / 4;               // 12500
    hipLaunchKernelGGL(gemm128_k, dim3(GG), dim3(256), 0, stream, bufA, W1, b1, bufB);
    hipLaunchKernelGGL((agg_k<0>), dim3(GA), dim3(256), 0, stream,
                       bufB, offs, srcS, wS, dinv, sc1, sh1, bufA, (float*)nullptr, (float*)nullptr);
    hipLaunchKernelGGL(gemm128_k, dim3(GG), dim3(256), 0, stream, bufA, W2, b2, bufB);
    hipLaunchKernelGGL((agg_k<0>), dim3(GA), dim3(256), 0, stream,
                       bufB, offs, srcS, wS, dinv, sc2, sh2, bufA, (float*)nullptr, (float*)nullptr);
    hipLaunchKernelGGL(gemm128_k, dim3(GG), dim3(256), 0, stream, bufA, Wcat, bcat, bufB);
    hipLaunchKernelGGL((agg_k<1>), dim3(GA), dim3(256), 0, stream,
                       bufB, offs, srcS, wS, dinv, (const float*)nullptr, (const float*)nullptr,
                       (__half*)nullptr, zb, outp);

    // attention + pooling + heads
    hipLaunchKernelGGL(att_k, dim3(GG), dim3(256), 0, stream, zb, Wa1, ba1, Wa2, ba2, pexp, red);
    hipLaunchKernelGGL(pool_k, dim3(GN), dim3(256), 0, stream, zb, pexp, batch, gpool, zsum, cnt, flags);
    hipLaunchKernelGGL(head_k, dim3(NB), dim3(128), 0, stream,
                       gpool, zsum, cnt, red, Wc1, bc1, Wc2, bc2, Wc3, bc3,
                       Wn1, bn1, Wn2, bn2, outp);
}

// Round 5
// 770.042 us; speedup vs baseline: 1.9425x; 1.0061x over previous
//
#include <hip/hip_runtime.h>
#include <hip/hip_fp16.h>

typedef unsigned short ushort_t;

#define N_NODES 50000
#define N_EDGES 1600000
#define NB      64
#define HF      128
#define LF      64
#define NC      6
#define EPSBN   1e-5f

// output element offsets (fp32 out confirmed in round 3)
#define OPRED_OFF 0
#define OMU_OFF   384
#define OLV_OFF   3200384
#define ONOI_OFF  6400384

__device__ __forceinline__ int clampi(int v, int lo, int hi) {
    return v < lo ? lo : (v > hi ? hi : v);
}

// ============ int-width detection (flags[1] = 1 if int64) ============
__global__ void detect_k(const int* ei_raw, int* flags) {
    __shared__ int c1s;
    if (threadIdx.x == 0) c1s = 0;
    __syncthreads();
    if (ei_raw[2 * threadIdx.x + 1] != 0) atomicAdd(&c1s, 1);
    __syncthreads();
    if (threadIdx.x == 0) flags[1] = (c1s == 0) ? 1 : 0;
}

// ============ init: zero hist/pools/red, fold BN, build Wcat ============
__global__ void init_k(int* hist, float* gpool, float* zsum, float* cnt, float* red,
                       float* Wcat, float* bcat, float* sc1, float* sh1, float* sc2, float* sh2,
                       const float* Wmu, const float* bmu, const float* Wlv, const float* blv,
                       const float* g1, const float* be1, const float* rm1, const float* rv1,
                       const float* g2, const float* be2, const float* rm2, const float* rv2) {
    int i = blockIdx.x * 256 + threadIdx.x;
    if (i < N_NODES) hist[i] = 0;
    if (i < NB * LF) { gpool[i] = 0.f; zsum[i] = 0.f; }
    if (i < NB) cnt[i] = 0.f;
    if (i < 4) red[i] = 0.f;
    if (i < HF * HF) {
        int k = i >> 7, c = i & 127;
        Wcat[i] = (c < 64) ? Wmu[k * 64 + c] : Wlv[k * 64 + (c - 64)];
    }
    if (i < HF) {
        bcat[i] = (i < 64) ? bmu[i] : blv[i - 64];
        float s1 = g1[i] * rsqrtf(rv1[i] + EPSBN);
        sc1[i] = s1; sh1[i] = be1[i] - rm1[i] * s1;
        float s2 = g2[i] * rsqrtf(rv2[i] + EPSBN);
        sc2[i] = s2; sh2[i] = be2[i] - rm2[i] * s2;
    }
}

// ============ dst histogram (int atomics only) ============
__global__ void hist_k(const int* ei, int* hist, const int* flags) {
    int e = blockIdx.x * 256 + threadIdx.x;
    if (e >= N_EDGES) return;
    int i64 = flags[1];
    int di = N_EDGES + e;
    int d = clampi(ei[i64 ? 2 * di : di], 0, N_NODES - 1);
    atomicAdd(&hist[d], 1);
}

// ============ scan (counting sort by dst) ============
__global__ void scan_blocks_k(const int* hist, int* offs, int* bsums) {
    __shared__ int sh[1024];
    int tid = threadIdx.x;
    int i = blockIdx.x * 1024 + tid;
    int v = (i < N_NODES) ? hist[i] : 0;
    sh[tid] = v;
    __syncthreads();
    for (int d = 1; d < 1024; d <<= 1) {
        int t = (tid >= d) ? sh[tid - d] : 0;
        __syncthreads();
        sh[tid] += t;
        __syncthreads();
    }
    int incl = sh[tid];
    if (i < N_NODES) offs[i] = incl - v;
    if (tid == 1023) bsums[blockIdx.x] = incl;
}

__global__ void scan_sums_k(int* bsums, int nb) {
    if (threadIdx.x == 0 && blockIdx.x == 0) {
        int acc = 0;
        for (int b = 0; b < nb; b++) { int v = bsums[b]; bsums[b] = acc; acc += v; }
    }
}

__global__ void scan_fin_k(int* offs, int* cursor, const int* bsums) {
    int i = blockIdx.x * 1024 + threadIdx.x;
    if (i < N_NODES) {
        int v = offs[i] + bsums[i >> 10];
        offs[i] = v; cursor[i] = v;
    }
    if (i == 0) offs[N_NODES] = N_EDGES;
}

// ============ scatter edges: ONE packed 8B record per edge ============
__global__ void scatter_edges_k(const int* ei, const float* ew,
                                int* cursor, uint2* rec, const int* flags) {
    int e = blockIdx.x * 256 + threadIdx.x;
    if (e >= N_EDGES) return;
    int i64 = flags[1];
    int di = N_EDGES + e;
    int s = clampi(ei[i64 ? 2 * e : e], 0, N_NODES - 1);
    int d = clampi(ei[i64 ? 2 * di : di], 0, N_NODES - 1);
    int p = atomicAdd(&cursor[d], 1);
    rec[p] = make_uint2((unsigned)s | ((unsigned)d << 16), __float_as_uint(ew[e]));
}

// ============ degree (segmented sum over packed recs) -> dinv ============
__global__ void deginv_k(const int* offs, const uint2* rec, float* dinv) {
    int n = blockIdx.x * 256 + threadIdx.x;
    if (n >= N_NODES) return;
    float s = 1.0f;
    int e1 = offs[n + 1];
    for (int e = offs[n]; e < e1; e++) s += __uint_as_float(rec[e].y);
    dinv[n] = rsqrtf(s);
}

// ============ unpack recs -> srcS + normalized edge weights (coalesced) ============
__global__ void ws_k(const uint2* rec, const float* dinv, ushort_t* srcS, float* wS) {
    int e = blockIdx.x * 256 + threadIdx.x;
    if (e >= N_EDGES) return;
    uint2 r = rec[e];
    int s = (int)(r.x & 0xFFFFu), d = (int)(r.x >> 16);
    srcS[e] = (ushort_t)s;
    wS[e] = __uint_as_float(r.y) * dinv[s] * dinv[d];
}

// ============ input GEMM: x[N,16] @ W_in[16,128] + b -> h0 (fp16) ============
__global__ __launch_bounds__(128) void gemm_in_k(const float* __restrict__ x,
                                                 const float* __restrict__ Win,
                                                 const float* __restrict__ bin,
                                                 __half* __restrict__ out) {
    __shared__ float xl[16 * 16];
    int tid = threadIdx.x;
    int row0 = blockIdx.x * 16;
    if (tid < 64) {
        int r = tid >> 2, k4 = tid & 3;
        int row = row0 + r;
        float4 v = make_float4(0.f, 0.f, 0.f, 0.f);
        if (row < N_NODES) v = *(const float4*)(x + row * 16 + k4 * 4);
        *(float4*)(xl + r * 16 + k4 * 4) = v;
    }
    float wv[16];
#pragma unroll
    for (int k = 0; k < 16; k++) wv[k] = Win[k * 128 + tid];
    float bias = bin[tid];
    __syncthreads();
    for (int r = 0; r < 16; r++) {
        float acc = bias;
#pragma unroll
        for (int k = 0; k < 16; k++) acc += xl[r * 16 + k] * wv[k];
        int row = row0 + r;
        if (row < N_NODES) out[row * 128 + tid] = __float2half(acc);
    }
}

// ============ main GEMM: in(fp16)[N,128] @ W(fp32)[128,128] + b -> out(fp16) ============
__global__ __launch_bounds__(256) void gemm128_k(const __half* __restrict__ in,
                                                 const float* __restrict__ W,
                                                 const float* __restrict__ b,
                                                 __half* __restrict__ out) {
    __shared__ float At[64 * 128];
    int tid = threadIdx.x;
    int row0 = blockIdx.x * 64;
    union HU { unsigned u; __half2 h; };
    for (int v = tid; v < 1024; v += 256) {
        int r = v >> 4, c8 = (v & 15) * 8;
        int row = row0 + r;
        uint4 raw = make_uint4(0u, 0u, 0u, 0u);
        if (row < N_NODES) raw = *(const uint4*)(in + row * 128 + c8);
        HU u0, u1, u2, u3;
        u0.u = raw.x; u1.u = raw.y; u2.u = raw.z; u3.u = raw.w;
        float2 f0 = __half22float2(u0.h), f1 = __half22float2(u1.h);
        float2 f2 = __half22float2(u2.h), f3 = __half22float2(u3.h);
        *(float4*)(At + r * 128 + c8)     = make_float4(f0.x, f0.y, f1.x, f1.y);
        *(float4*)(At + r * 128 + c8 + 4) = make_float4(f2.x, f2.y, f3.x, f3.y);
    }
    __syncthreads();

    int cp = tid & 63, rg = tid >> 6;
    int c0 = cp * 2;
    float acc0[16], acc1[16];
    float bx = b[c0], by = b[c0 + 1];
#pragma unroll
    for (int r = 0; r < 16; r++) { acc0[r] = bx; acc1[r] = by; }

    for (int kb = 0; kb < 128; kb += 4) {
        float wx[4], wy[4];
#pragma unroll
        for (int j = 0; j < 4; j++) {
            float2 w = *(const float2*)(W + (kb + j) * 128 + c0);
            wx[j] = w.x; wy[j] = w.y;
        }
#pragma unroll
        for (int r = 0; r < 16; r++) {
            float4 a = *(const float4*)(At + (rg * 16 + r) * 128 + kb);
            acc0[r] += a.x * wx[0] + a.y * wx[1] + a.z * wx[2] + a.w * wx[3];
            acc1[r] += a.x * wy[0] + a.y * wy[1] + a.z * wy[2] + a.w * wy[3];
        }
    }
#pragma unroll
    for (int r = 0; r < 16; r++) {
        int row = row0 + rg * 16 + r;
        if (row < N_NODES) {
            *(__half2*)(out + row * 128 + c0) = __floats2half2_rn(acc0[r], acc1[r]);
        }
    }
}

// ============ aggregation: 1 wave per node, half2 lanes, 8x-unrolled gather ============
template <int MODE>
__global__ __launch_bounds__(256) void agg_k(const __half* __restrict__ lin,
                                             const int* __restrict__ offs,
                                             const ushort_t* __restrict__ srcS,
                                             const float* __restrict__ wS,
                                             const float* __restrict__ dinv,
                                             const float* __restrict__ sc,
                                             const float* __restrict__ sh,
                                             __half* __restrict__ outH,
                                             float* __restrict__ zb,
                                             float* __restrict__ outp) {
    int tid = threadIdx.x;
    int n = blockIdx.x * 4 + (tid >> 6);
    int t = tid & 63;
    const __half2* linv = (const __half2*)lin;
    float dv = dinv[n];
    float2 self = __half22float2(linv[n * 64 + t]);
    float ax = self.x * dv * dv, ay = self.y * dv * dv;
    int e0 = offs[n], e1 = offs[n + 1];
    int e = e0;
    for (; e + 8 <= e1; e += 8) {
        int s[8]; float w[8]; __half2 h[8];
#pragma unroll
        for (int j = 0; j < 8; j++) { s[j] = srcS[e + j]; w[j] = wS[e + j]; }
#pragma unroll
        for (int j = 0; j < 8; j++) h[j] = linv[s[j] * 64 + t];
#pragma unroll
        for (int j = 0; j < 8; j++) {
            float2 f = __half22float2(h[j]);
            ax += w[j] * f.x; ay += w[j] * f.y;
        }
    }
    for (; e < e1; e++) {
        float2 f = __half22float2(linv[(int)srcS[e] * 64 + t]);
        float w = wS[e];
        ax += w * f.x; ay += w * f.y;
    }
    if (MODE == 0) {
        float2 s2 = *(const float2*)(sc + 2 * t);
        float2 h2 = *(const float2*)(sh + 2 * t);
        float o0 = fmaxf(ax * s2.x + h2.x, 0.f);
        float o1 = fmaxf(ay * s2.y + h2.y, 0.f);
        *(__half2*)(outH + n * 128 + 2 * t) = __floats2half2_rn(o0, o1);
    } else {
        if (t < 32) {
            *(float2*)(zb + n * 64 + 2 * t) = make_float2(ax, ay);
            *(float2*)(outp + OMU_OFF + n * 64 + 2 * t) = make_float2(ax, ay);
        } else {
            int c = 2 * t - 64;
            *(float2*)(outp + OLV_OFF + n * 64 + c) = make_float2(ax, ay);
        }
    }
}

// ============ attention (gemm-style): p[n] = exp(tanh(z Wa1 + ba1) Wa2 + ba2) ============
__global__ __launch_bounds__(256) void att_k(const float* __restrict__ zb,
                                             const float* __restrict__ Wa1,
                                             const float* __restrict__ ba1,
                                             const float* __restrict__ Wa2,
                                             const float* __restrict__ ba2,
                                             float* __restrict__ p, float* __restrict__ red) {
    __shared__ float zl[64 * 64];    // 16 KB
    int tid = threadIdx.x;
    int row0 = blockIdx.x * 64;
    for (int v = tid; v < 1024; v += 256) {
        int r = v >> 4, k4 = (v & 15) * 4;
        int row = row0 + r;
        float4 val = make_float4(0.f, 0.f, 0.f, 0.f);
        if (row < N_NODES) val = *(const float4*)(zb + row * 64 + k4);
        *(float4*)(zl + r * 64 + k4) = val;
    }
    int cp = tid & 63, rg = tid >> 6;
    int c0 = cp * 2;
    float acc0[16], acc1[16];
    float b0 = ba1[c0], b1 = ba1[c0 + 1];
#pragma unroll
    for (int r = 0; r < 16; r++) { acc0[r] = b0; acc1[r] = b1; }
    float a0 = Wa2[c0], a1 = Wa2[c0 + 1];
    float ba2v = ba2[0];
    __syncthreads();
    for (int kb = 0; kb < 64; kb += 4) {
        float wx[4], wy[4];
#pragma unroll
        for (int j = 0; j < 4; j++) {
            float2 w = *(const float2*)(Wa1 + (kb + j) * 128 + c0);
            wx[j] = w.x; wy[j] = w.y;
        }
#pragma unroll
        for (int r = 0; r < 16; r++) {
            float4 a = *(const float4*)(zl + (rg * 16 + r) * 64 + kb);
            acc0[r] += a.x * wx[0] + a.y * wx[1] + a.z * wx[2] + a.w * wx[3];
            acc1[r] += a.x * wy[0] + a.y * wy[1] + a.z * wy[2] + a.w * wy[3];
        }
    }
    float wsum = 0.f;
#pragma unroll
    for (int r = 0; r < 16; r++) {
        float y = tanhf(acc0[r]) * a0 + tanhf(acc1[r]) * a1;
#pragma unroll
        for (int off = 32; off > 0; off >>= 1) y += __shfl_down(y, off, 64);
        if (cp == 0) {
            int row = row0 + rg * 16 + r;
            if (row < N_NODES) {
                float pe = expf(y + ba2v);
                p[row] = pe;
                wsum += pe;
            }
        }
    }
    if (cp == 0) atomicAdd(&red[1], wsum);
}

// ============ pooling (4 groups of 64 per block) ============
__global__ __launch_bounds__(256) void pool_k(const float* __restrict__ zb,
                                              const float* __restrict__ p,
                                              const int* __restrict__ batch,
                                              float* gpool, float* zsum, float* cnt,
                                              const int* __restrict__ flags) {
    int l = threadIdx.x & 63, g = threadIdx.x >> 6;
    int i64 = flags[1];
    int nstart = blockIdx.x * 256 + g * 64;
    float ag = 0.f, az = 0.f, c = 0.f;
    int cur = -1;
    for (int i = 0; i < 64; i++) {
        int n = nstart + i;
        if (n >= N_NODES) break;
        int b = clampi(batch[i64 ? 2 * n : n], 0, NB - 1);
        if (b != cur) {
            if (cur >= 0) {
                atomicAdd(&gpool[cur * 64 + l], ag);
                atomicAdd(&zsum[cur * 64 + l], az);
                if (l == 0) atomicAdd(&cnt[cur], c);
            }
            cur = b; ag = 0.f; az = 0.f; c = 0.f;
        }
        float pe = p[n];
        float zv = zb[n * 64 + l];
        ag += pe * zv; az += zv; c += 1.f;
    }
    if (cur >= 0) {
        atomicAdd(&gpool[cur * 64 + l], ag);
        atomicAdd(&zsum[cur * 64 + l], az);
        if (l == 0) atomicAdd(&cnt[cur], c);
    }
}

// ============ per-graph heads ============
__global__ __launch_bounds__(128) void head_k(const float* __restrict__ gpool,
                                              const float* __restrict__ zsum,
                                              const float* __restrict__ cnt,
                                              const float* __restrict__ red,
                                              const float* Wc1, const float* bc1,
                                              const float* Wc2, const float* bc2,
                                              const float* Wc3, const float* bc3,
                                              const float* Wn1, const float* bn1,
                                              const float* Wn2, const float* bn2,
                                              float* __restrict__ outp) {
    __shared__ float gsh[64], zm[64], p1[128], p2[64], n1[64];
    int b = blockIdx.x, t = threadIdx.x;
    float S = red[1];
    if (t < 64) {
        gsh[t] = gpool[b * 64 + t] / S;
        zm[t] = zsum[b * 64 + t] / fmaxf(cnt[b], 1.f);
    }
    __syncthreads();
    {
        float acc = bc1[t];
        for (int k = 0; k < 64; k++) acc += gsh[k] * Wc1[k * 128 + t];
        p1[t] = fmaxf(acc, 0.f);
    }
    __syncthreads();
    if (t < 64) {
        float acc = bc2[t];
        for (int k = 0; k < 128; k++) acc += p1[k] * Wc2[k * 64 + t];
        p2[t] = fmaxf(acc, 0.f);
    } else {
        int tt = t - 64;
        float acc = bn1[tt];
        for (int k = 0; k < 64; k++) acc += zm[k] * Wn1[k * 64 + tt];
        n1[tt] = fmaxf(acc, 0.f);
    }
    __syncthreads();
    if (t < NC) {
        float acc = bc3[t];
        for (int k = 0; k < 64; k++) acc += p2[k] * Wc3[k * 6 + t];
        outp[OPRED_OFF + b * 6 + t] = acc;
    }
    if (t == 64) {
        float acc = bn2[0];
        for (int k = 0; k < 64; k++) acc += n1[k] * Wn2[k];
        outp[ONOI_OFF + b] = 1.f / (1.f + expf(-acc));
    }
}

extern "C" void kernel_launch(void* const* d_in, const int* in_sizes, int n_in,
                              void* d_out, int out_size, void* d_ws, size_t ws_size,
                              hipStream_t stream) {
    const int*   ei    = (const int*)d_in[1];
    const int*   batch = (const int*)d_in[3];
    const float* x     = (const float*)d_in[0];
    const float* ew    = (const float*)d_in[2];
    const float* Win   = (const float*)d_in[4];
    const float* bin   = (const float*)d_in[5];
    const float* W1    = (const float*)d_in[6];
    const float* b1    = (const float*)d_in[7];
    const float* W2    = (const float*)d_in[8];
    const float* b2    = (const float*)d_in[9];
    const float* Wmu   = (const float*)d_in[10];
    const float* bmu   = (const float*)d_in[11];
    const float* Wlv   = (const float*)d_in[12];
    const float* blv   = (const float*)d_in[13];
    const float* g1    = (const float*)d_in[14];
    const float* be1   = (const float*)d_in[15];
    const float* rm1   = (const float*)d_in[16];
    const float* rv1   = (const float*)d_in[17];
    const float* g2    = (const float*)d_in[18];
    const float* be2   = (const float*)d_in[19];
    const float* rm2   = (const float*)d_in[20];
    const float* rv2   = (const float*)d_in[21];
    const float* Wa1   = (const float*)d_in[22];
    const float* ba1   = (const float*)d_in[23];
    const float* Wa2   = (const float*)d_in[24];
    const float* ba2   = (const float*)d_in[25];
    const float* Wc1   = (const float*)d_in[26];
    const float* bc1   = (const float*)d_in[27];
    const float* Wc2   = (const float*)d_in[28];
    const float* bc2   = (const float*)d_in[29];
    const float* Wc3   = (const float*)d_in[30];
    const float* bc3   = (const float*)d_in[31];
    const float* Wn1   = (const float*)d_in[32];
    const float* bn1   = (const float*)d_in[33];
    const float* Wn2   = (const float*)d_in[34];
    const float* bn2   = (const float*)d_in[35];

    float* outp = (float*)d_out;

    // workspace layout
    char* ws = (char*)d_ws;
    size_t o = 0;
    auto alloc = [&](size_t bytes) { size_t r = o; o = (o + bytes + 511) & ~((size_t)511); return r; };
    int*      flags  = (int*)     (ws + alloc(16));
    float*    dinv   = (float*)   (ws + alloc(N_NODES * 4));
    int*      offs   = (int*)     (ws + alloc((N_NODES + 1) * 4));
    int*      cursor = (int*)     (ws + alloc(N_NODES * 4));   // doubles as hist
    uint2*    rec    = (uint2*)   (ws + alloc((size_t)N_EDGES * 8));
    ushort_t* srcS   = (ushort_t*)(ws + alloc(N_EDGES * 2));
    float*    wS     = (float*)   (ws + alloc(N_EDGES * 4));
    float*    pexp   = (float*)   (ws + alloc(N_NODES * 4));
    float*    Wcat   = (float*)   (ws + alloc(HF * HF * 4));
    float*    bcat   = (float*)   (ws + alloc(HF * 4));
    float*    sc1    = (float*)   (ws + alloc(HF * 4));
    float*    sh1    = (float*)   (ws + alloc(HF * 4));
    float*    sc2    = (float*)   (ws + alloc(HF * 4));
    float*    sh2    = (float*)   (ws + alloc(HF * 4));
    float*    red    = (float*)   (ws + alloc(16));
    float*    gpool  = (float*)   (ws + alloc(NB * LF * 4));
    float*    zsum   = (float*)   (ws + alloc(NB * LF * 4));
    float*    cnt    = (float*)   (ws + alloc(NB * 4));
    int*      bsums  = (int*)     (ws + alloc(64 * 4));
    __half*   bufA   = (__half*)  (ws + alloc((size_t)N_NODES * 128 * 2));
    __half*   bufB   = (__half*)  (ws + alloc((size_t)N_NODES * 128 * 2));
    float*    zb     = (float*)   (ws + alloc((size_t)N_NODES * 64 * 4));
    (void)ws_size; (void)n_in; (void)in_sizes; (void)out_size;

    const int GN = (N_NODES + 255) / 256;     // 196
    const int GE = (N_EDGES + 255) / 256;     // 6250
    const int GS = (N_NODES + 1023) / 1024;   // 49

    hipLaunchKernelGGL(detect_k, dim3(1), dim3(256), 0, stream, ei, flags);
    hipLaunchKernelGGL(init_k, dim3(GN), dim3(256), 0, stream,
                       cursor, gpool, zsum, cnt, red, Wcat, bcat, sc1, sh1, sc2, sh2,
                       Wmu, bmu, Wlv, blv, g1, be1, rm1, rv1, g2, be2, rm2, rv2);
    hipLaunchKernelGGL(hist_k, dim3(GE), dim3(256), 0, stream, ei, cursor, flags);
    hipLaunchKernelGGL(scan_blocks_k, dim3(GS), dim3(1024), 0, stream, cursor, offs, bsums);
    hipLaunchKernelGGL(scan_sums_k, dim3(1), dim3(64), 0, stream, bsums, GS);
    hipLaunchKernelGGL(scan_fin_k, dim3(GS), dim3(1024), 0, stream, offs, cursor, bsums);
    hipLaunchKernelGGL(scatter_edges_k, dim3(GE), dim3(256), 0, stream, ei, ew, cursor, rec, flags);
    hipLaunchKernelGGL(deginv_k, dim3(GN), dim3(256), 0, stream, offs, rec, dinv);
    hipLaunchKernelGGL(ws_k, dim3(GE), dim3(256), 0, stream, rec, dinv, srcS, wS);

    // encoder
    hipLaunchKernelGGL(gemm_in_k, dim3(N_NODES / 16), dim3(128), 0, stream, x, Win, bin, bufA);
    const int GG = (N_NODES + 63) / 64;       // 782
    const int GA = N_NODES / 4;               // 12500
    hipLaunchKernelGGL(gemm128_k, dim3(GG), dim3(256), 0, stream, bufA, W1, b1, bufB);
    hipLaunchKernelGGL((agg_k<0>), dim3(GA), dim3(256), 0, stream,
                       bufB, offs, srcS, wS, dinv, sc1, sh1, bufA, (float*)nullptr, (float*)nullptr);
    hipLaunchKernelGGL(gemm128_k, dim3(GG), dim3(256), 0, stream, bufA, W2, b2, bufB);
    hipLaunchKernelGGL((agg_k<0>), dim3(GA), dim3(256), 0, stream,
                       bufB, offs, srcS, wS, dinv, sc2, sh2, bufA, (float*)nullptr, (float*)nullptr);
    hipLaunchKernelGGL(gemm128_k, dim3(GG), dim3(256), 0, stream, bufA, Wcat, bcat, bufB);
    hipLaunchKernelGGL((agg_k<1>), dim3(GA), dim3(256), 0, stream,
                       bufB, offs, srcS, wS, dinv, (const float*)nullptr, (const float*)nullptr,
                       (__half*)nullptr, zb, outp);

    // attention + pooling + heads
    hipLaunchKernelGGL(att_k, dim3(GG), dim3(256), 0, stream, zb, Wa1, ba1, Wa2, ba2, pexp, red);
    hipLaunchKernelGGL(pool_k, dim3(GN), dim3(256), 0, stream, zb, pexp, batch, gpool, zsum, cnt, flags);
    hipLaunchKernelGGL(head_k, dim3(NB), dim3(128), 0, stream,
                       gpool, zsum, cnt, red, Wc1, bc1, Wc2, bc2, Wc3, bc3,
                       Wn1, bn1, Wn2, bn2, outp);
}

// Round 6
// 727.752 us; speedup vs baseline: 2.0554x; 1.0581x over previous
//
#include <hip/hip_runtime.h>
#include <hip/hip_fp16.h>

typedef unsigned short ushort_t;

#define N_NODES 50000
#define N_EDGES 1600000
#define NB      64
#define HF      128
#define LF      64
#define NC      6
#define EPSBN   1e-5f
#define NBUCK   196          // dst buckets of 256 nodes: 196*256 = 50176 >= 50000
#define NSEGS   (NBUCK * 8)  // 8 sub-partitions (≈XCD) per bucket
#define CPAD    16           // one 64B line per counter

// output element offsets (fp32 out confirmed in round 3)
#define OPRED_OFF 0
#define OMU_OFF   384
#define OLV_OFF   3200384
#define ONOI_OFF  6400384

__device__ __forceinline__ int clampi(int v, int lo, int hi) {
    return v < lo ? lo : (v > hi ? hi : v);
}

// ============ int-width detection (flags[1] = 1 if int64) ============
__global__ void detect_k(const int* ei_raw, int* flags) {
    __shared__ int c1s;
    if (threadIdx.x == 0) c1s = 0;
    __syncthreads();
    if (ei_raw[2 * threadIdx.x + 1] != 0) atomicAdd(&c1s, 1);
    __syncthreads();
    if (threadIdx.x == 0) flags[1] = (c1s == 0) ? 1 : 0;
}

// ============ init: zero seg counters/pools/red, fold BN, build Wcat ============
__global__ void init_k(int* gcnt, float* gpool, float* zsum, float* cnt, float* red,
                       float* Wcat, float* bcat, float* sc1, float* sh1, float* sc2, float* sh2,
                       const float* Wmu, const float* bmu, const float* Wlv, const float* blv,
                       const float* g1, const float* be1, const float* rm1, const float* rv1,
                       const float* g2, const float* be2, const float* rm2, const float* rv2) {
    int i = blockIdx.x * 256 + threadIdx.x;
    if (i < NSEGS) gcnt[i * CPAD] = 0;
    if (i < NB * LF) { gpool[i] = 0.f; zsum[i] = 0.f; }
    if (i < NB) cnt[i] = 0.f;
    if (i < 4) red[i] = 0.f;
    if (i < HF * HF) {
        int k = i >> 7, c = i & 127;
        Wcat[i] = (c < 64) ? Wmu[k * 64 + c] : Wlv[k * 64 + (c - 64)];
    }
    if (i < HF) {
        bcat[i] = (i < 64) ? bmu[i] : blv[i - 64];
        float s1 = g1[i] * rsqrtf(rv1[i] + EPSBN);
        sc1[i] = s1; sh1[i] = be1[i] - rm1[i] * s1;
        float s2 = g2[i] * rsqrtf(rv2[i] + EPSBN);
        sc2[i] = s2; sh2[i] = be2[i] - rm2[i] * s2;
    }
}

// ============ pass 0: per-block LDS bucket histogram -> global seg counts ============
__global__ __launch_bounds__(256) void precount_k(const int* ei, int* gcnt, const int* flags) {
    __shared__ int lh[NBUCK];
    int tid = threadIdx.x;
    for (int i = tid; i < NBUCK; i += 256) lh[i] = 0;
    __syncthreads();
    int e = blockIdx.x * 256 + tid;
    int sub = blockIdx.x & 7;
    if (e < N_EDGES) {
        int i64 = flags[1];
        int di = N_EDGES + e;
        int d = clampi(ei[i64 ? 2 * di : di], 0, N_NODES - 1);
        atomicAdd(&lh[d >> 8], 1);
    }
    __syncthreads();
    for (int i = tid; i < NBUCK; i += 256)
        if (lh[i] > 0) atomicAdd(&gcnt[(i * 8 + sub) * CPAD], lh[i]);
}

// ============ scan 1568 segment counts -> cursors + read-only bases ============
__global__ __launch_bounds__(256) void segscan_k(const int* gcnt, int* gcur, int* gbase) {
    __shared__ int sh[NSEGS];
    int tid = threadIdx.x;
    for (int i = tid; i < NSEGS; i += 256) sh[i] = gcnt[i * CPAD];
    __syncthreads();
    if (tid == 0) {
        int acc = 0;
        for (int i = 0; i < NSEGS; i++) { int v = sh[i]; sh[i] = acc; acc += v; }
    }
    __syncthreads();
    for (int i = tid; i < NSEGS; i += 256) { gcur[i * CPAD] = sh[i]; gbase[i] = sh[i]; }
    if (tid == 0) gbase[NSEGS] = N_EDGES;
}

// ============ pass 1: append edges into (bucket, sub) segments ============
__global__ __launch_bounds__(256) void pass1_k(const int* ei, const float* ew,
                                               int* gcur, uint2* rec, const int* flags) {
    int e = blockIdx.x * 256 + threadIdx.x;
    if (e >= N_EDGES) return;
    int i64 = flags[1];
    int di = N_EDGES + e;
    int s = clampi(ei[i64 ? 2 * e : e], 0, N_NODES - 1);
    int d = clampi(ei[i64 ? 2 * di : di], 0, N_NODES - 1);
    int sub = blockIdx.x & 7;
    int p = atomicAdd(&gcur[((d >> 8) * 8 + sub) * CPAD], 1);
    rec[p] = make_uint2((unsigned)s | ((unsigned)d << 16), __float_as_uint(ew[e]));
}

// ============ pass 2: per-bucket LDS sort -> offs, dinv, dst-sorted rec2 ============
__global__ __launch_bounds__(256) void pass2_k(const uint2* __restrict__ rec,
                                               const int* __restrict__ gbase,
                                               uint2* __restrict__ rec2,
                                               int* __restrict__ offs,
                                               float* __restrict__ dinv) {
    __shared__ int cnt[256];
    __shared__ float degs[256];
    __shared__ int off[256];
    int b = blockIdx.x, t = threadIdx.x;
    cnt[t] = 0; degs[t] = 0.f;
    __syncthreads();
    int B0 = gbase[b * 8], B8 = gbase[b * 8 + 8];
    for (int e = B0 + t; e < B8; e += 256) {
        uint2 r = rec[e];
        int dl = (r.x >> 16) & 255;
        atomicAdd(&cnt[dl], 1);
        atomicAdd(&degs[dl], __uint_as_float(r.y));
    }
    __syncthreads();
    int v = cnt[t];
    off[t] = v;
    __syncthreads();
    for (int dth = 1; dth < 256; dth <<= 1) {
        int x = (t >= dth) ? off[t - dth] : 0;
        __syncthreads();
        off[t] += x;
        __syncthreads();
    }
    int excl = off[t] - v;
    int n = (b << 8) + t;
    if (n < N_NODES) {
        offs[n] = B0 + excl;
        dinv[n] = rsqrtf(1.f + degs[t]);
    }
    if (b == NBUCK - 1 && t == 0) offs[N_NODES] = N_EDGES;
    __syncthreads();
    cnt[t] = B0 + excl;   // reuse as cursor
    __syncthreads();
    for (int e = B0 + t; e < B8; e += 256) {
        uint2 r = rec[e];
        int dl = (r.x >> 16) & 255;
        int p = atomicAdd(&cnt[dl], 1);
        rec2[p] = r;
    }
}

// ============ unpack recs -> srcS + normalized edge weights (coalesced) ============
__global__ void ws_k(const uint2* rec, const float* dinv, ushort_t* srcS, float* wS) {
    int e = blockIdx.x * 256 + threadIdx.x;
    if (e >= N_EDGES) return;
    uint2 r = rec[e];
    int s = (int)(r.x & 0xFFFFu), d = (int)(r.x >> 16);
    srcS[e] = (ushort_t)s;
    wS[e] = __uint_as_float(r.y) * dinv[s] * dinv[d];
}

// ============ input GEMM: x[N,16] @ W_in[16,128] + b -> h0 (fp16) ============
__global__ __launch_bounds__(128) void gemm_in_k(const float* __restrict__ x,
                                                 const float* __restrict__ Win,
                                                 const float* __restrict__ bin,
                                                 __half* __restrict__ out) {
    __shared__ float xl[16 * 16];
    int tid = threadIdx.x;
    int row0 = blockIdx.x * 16;
    if (tid < 64) {
        int r = tid >> 2, k4 = tid & 3;
        int row = row0 + r;
        float4 v = make_float4(0.f, 0.f, 0.f, 0.f);
        if (row < N_NODES) v = *(const float4*)(x + row * 16 + k4 * 4);
        *(float4*)(xl + r * 16 + k4 * 4) = v;
    }
    float wv[16];
#pragma unroll
    for (int k = 0; k < 16; k++) wv[k] = Win[k * 128 + tid];
    float bias = bin[tid];
    __syncthreads();
    for (int r = 0; r < 16; r++) {
        float acc = bias;
#pragma unroll
        for (int k = 0; k < 16; k++) acc += xl[r * 16 + k] * wv[k];
        int row = row0 + r;
        if (row < N_NODES) out[row * 128 + tid] = __float2half(acc);
    }
}

// ============ main GEMM: in(fp16)[N,128] @ W(fp32)[128,128] + b -> out(fp16) ============
__global__ __launch_bounds__(256) void gemm128_k(const __half* __restrict__ in,
                                                 const float* __restrict__ W,
                                                 const float* __restrict__ b,
                                                 __half* __restrict__ out) {
    __shared__ float At[64 * 128];
    int tid = threadIdx.x;
    int row0 = blockIdx.x * 64;
    union HU { unsigned u; __half2 h; };
    for (int v = tid; v < 1024; v += 256) {
        int r = v >> 4, c8 = (v & 15) * 8;
        int row = row0 + r;
        uint4 raw = make_uint4(0u, 0u, 0u, 0u);
        if (row < N_NODES) raw = *(const uint4*)(in + row * 128 + c8);
        HU u0, u1, u2, u3;
        u0.u = raw.x; u1.u = raw.y; u2.u = raw.z; u3.u = raw.w;
        float2 f0 = __half22float2(u0.h), f1 = __half22float2(u1.h);
        float2 f2 = __half22float2(u2.h), f3 = __half22float2(u3.h);
        *(float4*)(At + r * 128 + c8)     = make_float4(f0.x, f0.y, f1.x, f1.y);
        *(float4*)(At + r * 128 + c8 + 4) = make_float4(f2.x, f2.y, f3.x, f3.y);
    }
    __syncthreads();

    int cp = tid & 63, rg = tid >> 6;
    int c0 = cp * 2;
    float acc0[16], acc1[16];
    float bx = b[c0], by = b[c0 + 1];
#pragma unroll
    for (int r = 0; r < 16; r++) { acc0[r] = bx; acc1[r] = by; }

    for (int kb = 0; kb < 128; kb += 4) {
        float wx[4], wy[4];
#pragma unroll
        for (int j = 0; j < 4; j++) {
            float2 w = *(const float2*)(W + (kb + j) * 128 + c0);
            wx[j] = w.x; wy[j] = w.y;
        }
#pragma unroll
        for (int r = 0; r < 16; r++) {
            float4 a = *(const float4*)(At + (rg * 16 + r) * 128 + kb);
            acc0[r] += a.x * wx[0] + a.y * wx[1] + a.z * wx[2] + a.w * wx[3];
            acc1[r] += a.x * wy[0] + a.y * wy[1] + a.z * wy[2] + a.w * wy[3];
        }
    }
#pragma unroll
    for (int r = 0; r < 16; r++) {
        int row = row0 + rg * 16 + r;
        if (row < N_NODES) {
            *(__half2*)(out + row * 128 + c0) = __floats2half2_rn(acc0[r], acc1[r]);
        }
    }
}

// ============ aggregation: 1 wave per node, half2 lanes, 8x-unrolled gather ============
template <int MODE>
__global__ __launch_bounds__(256) void agg_k(const __half* __restrict__ lin,
                                             const int* __restrict__ offs,
                                             const ushort_t* __restrict__ srcS,
                                             const float* __restrict__ wS,
                                             const float* __restrict__ dinv,
                                             const float* __restrict__ sc,
                                             const float* __restrict__ sh,
                                             __half* __restrict__ outH,
                                             float* __restrict__ zb,
                                             float* __restrict__ outp) {
    int tid = threadIdx.x;
    int n = blockIdx.x * 4 + (tid >> 6);
    int t = tid & 63;
    const __half2* linv = (const __half2*)lin;
    float dv = dinv[n];
    float2 self = __half22float2(linv[n * 64 + t]);
    float ax = self.x * dv * dv, ay = self.y * dv * dv;
    int e0 = offs[n], e1 = offs[n + 1];
    int e = e0;
    for (; e + 8 <= e1; e += 8) {
        int s[8]; float w[8]; __half2 h[8];
#pragma unroll
        for (int j = 0; j < 8; j++) { s[j] = srcS[e + j]; w[j] = wS[e + j]; }
#pragma unroll
        for (int j = 0; j < 8; j++) h[j] = linv[s[j] * 64 + t];
#pragma unroll
        for (int j = 0; j < 8; j++) {
            float2 f = __half22float2(h[j]);
            ax += w[j] * f.x; ay += w[j] * f.y;
        }
    }
    for (; e < e1; e++) {
        float2 f = __half22float2(linv[(int)srcS[e] * 64 + t]);
        float w = wS[e];
        ax += w * f.x; ay += w * f.y;
    }
    if (MODE == 0) {
        float2 s2 = *(const float2*)(sc + 2 * t);
        float2 h2 = *(const float2*)(sh + 2 * t);
        float o0 = fmaxf(ax * s2.x + h2.x, 0.f);
        float o1 = fmaxf(ay * s2.y + h2.y, 0.f);
        *(__half2*)(outH + n * 128 + 2 * t) = __floats2half2_rn(o0, o1);
    } else {
        if (t < 32) {
            *(float2*)(zb + n * 64 + 2 * t) = make_float2(ax, ay);
            *(float2*)(outp + OMU_OFF + n * 64 + 2 * t) = make_float2(ax, ay);
        } else {
            int c = 2 * t - 64;
            *(float2*)(outp + OLV_OFF + n * 64 + c) = make_float2(ax, ay);
        }
    }
}

// ============ attention (gemm-style): p[n] = exp(tanh(z Wa1 + ba1) Wa2 + ba2) ============
__global__ __launch_bounds__(256) void att_k(const float* __restrict__ zb,
                                             const float* __restrict__ Wa1,
                                             const float* __restrict__ ba1,
                                             const float* __restrict__ Wa2,
                                             const float* __restrict__ ba2,
                                             float* __restrict__ p, float* __restrict__ red) {
    __shared__ float zl[64 * 64];    // 16 KB
    int tid = threadIdx.x;
    int row0 = blockIdx.x * 64;
    for (int v = tid; v < 1024; v += 256) {
        int r = v >> 4, k4 = (v & 15) * 4;
        int row = row0 + r;
        float4 val = make_float4(0.f, 0.f, 0.f, 0.f);
        if (row < N_NODES) val = *(const float4*)(zb + row * 64 + k4);
        *(float4*)(zl + r * 64 + k4) = val;
    }
    int cp = tid & 63, rg = tid >> 6;
    int c0 = cp * 2;
    float acc0[16], acc1[16];
    float b0 = ba1[c0], b1 = ba1[c0 + 1];
#pragma unroll
    for (int r = 0; r < 16; r++) { acc0[r] = b0; acc1[r] = b1; }
    float a0 = Wa2[c0], a1 = Wa2[c0 + 1];
    float ba2v = ba2[0];
    __syncthreads();
    for (int kb = 0; kb < 64; kb += 4) {
        float wx[4], wy[4];
#pragma unroll
        for (int j = 0; j < 4; j++) {
            float2 w = *(const float2*)(Wa1 + (kb + j) * 128 + c0);
            wx[j] = w.x; wy[j] = w.y;
        }
#pragma unroll
        for (int r = 0; r < 16; r++) {
            float4 a = *(const float4*)(zl + (rg * 16 + r) * 64 + kb);
            acc0[r] += a.x * wx[0] + a.y * wx[1] + a.z * wx[2] + a.w * wx[3];
            acc1[r] += a.x * wy[0] + a.y * wy[1] + a.z * wy[2] + a.w * wy[3];
        }
    }
    float wsum = 0.f;
#pragma unroll
    for (int r = 0; r < 16; r++) {
        float y = tanhf(acc0[r]) * a0 + tanhf(acc1[r]) * a1;
#pragma unroll
        for (int off = 32; off > 0; off >>= 1) y += __shfl_down(y, off, 64);
        if (cp == 0) {
            int row = row0 + rg * 16 + r;
            if (row < N_NODES) {
                float pe = expf(y + ba2v);
                p[row] = pe;
                wsum += pe;
            }
        }
    }
    if (cp == 0) atomicAdd(&red[1], wsum);
}

// ============ pooling (4 groups of 64 per block) ============
__global__ __launch_bounds__(256) void pool_k(const float* __restrict__ zb,
                                              const float* __restrict__ p,
                                              const int* __restrict__ batch,
                                              float* gpool, float* zsum, float* cnt,
                                              const int* __restrict__ flags) {
    int l = threadIdx.x & 63, g = threadIdx.x >> 6;
    int i64 = flags[1];
    int nstart = blockIdx.x * 256 + g * 64;
    float ag = 0.f, az = 0.f, c = 0.f;
    int cur = -1;
    for (int i = 0; i < 64; i++) {
        int n = nstart + i;
        if (n >= N_NODES) break;
        int b = clampi(batch[i64 ? 2 * n : n], 0, NB - 1);
        if (b != cur) {
            if (cur >= 0) {
                atomicAdd(&gpool[cur * 64 + l], ag);
                atomicAdd(&zsum[cur * 64 + l], az);
                if (l == 0) atomicAdd(&cnt[cur], c);
            }
            cur = b; ag = 0.f; az = 0.f; c = 0.f;
        }
        float pe = p[n];
        float zv = zb[n * 64 + l];
        ag += pe * zv; az += zv; c += 1.f;
    }
    if (cur >= 0) {
        atomicAdd(&gpool[cur * 64 + l], ag);
        atomicAdd(&zsum[cur * 64 + l], az);
        if (l == 0) atomicAdd(&cnt[cur], c);
    }
}

// ============ per-graph heads ============
__global__ __launch_bounds__(128) void head_k(const float* __restrict__ gpool,
                                              const float* __restrict__ zsum,
                                              const float* __restrict__ cnt,
                                              const float* __restrict__ red,
                                              const float* Wc1, const float* bc1,
                                              const float* Wc2, const float* bc2,
                                              const float* Wc3, const float* bc3,
                                              const float* Wn1, const float* bn1,
                                              const float* Wn2, const float* bn2,
                                              float* __restrict__ outp) {
    __shared__ float gsh[64], zm[64], p1[128], p2[64], n1[64];
    int b = blockIdx.x, t = threadIdx.x;
    float S = red[1];
    if (t < 64) {
        gsh[t] = gpool[b * 64 + t] / S;
        zm[t] = zsum[b * 64 + t] / fmaxf(cnt[b], 1.f);
    }
    __syncthreads();
    {
        float acc = bc1[t];
        for (int k = 0; k < 64; k++) acc += gsh[k] * Wc1[k * 128 + t];
        p1[t] = fmaxf(acc, 0.f);
    }
    __syncthreads();
    if (t < 64) {
        float acc = bc2[t];
        for (int k = 0; k < 128; k++) acc += p1[k] * Wc2[k * 64 + t];
        p2[t] = fmaxf(acc, 0.f);
    } else {
        int tt = t - 64;
        float acc = bn1[tt];
        for (int k = 0; k < 64; k++) acc += zm[k] * Wn1[k * 64 + tt];
        n1[tt] = fmaxf(acc, 0.f);
    }
    __syncthreads();
    if (t < NC) {
        float acc = bc3[t];
        for (int k = 0; k < 64; k++) acc += p2[k] * Wc3[k * 6 + t];
        outp[OPRED_OFF + b * 6 + t] = acc;
    }
    if (t == 64) {
        float acc = bn2[0];
        for (int k = 0; k < 64; k++) acc += n1[k] * Wn2[k];
        outp[ONOI_OFF + b] = 1.f / (1.f + expf(-acc));
    }
}

extern "C" void kernel_launch(void* const* d_in, const int* in_sizes, int n_in,
                              void* d_out, int out_size, void* d_ws, size_t ws_size,
                              hipStream_t stream) {
    const int*   ei    = (const int*)d_in[1];
    const int*   batch = (const int*)d_in[3];
    const float* x     = (const float*)d_in[0];
    const float* ew    = (const float*)d_in[2];
    const float* Win   = (const float*)d_in[4];
    const float* bin   = (const float*)d_in[5];
    const float* W1    = (const float*)d_in[6];
    const float* b1    = (const float*)d_in[7];
    const float* W2    = (const float*)d_in[8];
    const float* b2    = (const float*)d_in[9];
    const float* Wmu   = (const float*)d_in[10];
    const float* bmu   = (const float*)d_in[11];
    const float* Wlv   = (const float*)d_in[12];
    const float* blv   = (const float*)d_in[13];
    const float* g1    = (const float*)d_in[14];
    const float* be1   = (const float*)d_in[15];
    const float* rm1   = (const float*)d_in[16];
    const float* rv1   = (const float*)d_in[17];
    const float* g2    = (const float*)d_in[18];
    const float* be2   = (const float*)d_in[19];
    const float* rm2   = (const float*)d_in[20];
    const float* rv2   = (const float*)d_in[21];
    const float* Wa1   = (const float*)d_in[22];
    const float* ba1   = (const float*)d_in[23];
    const float* Wa2   = (const float*)d_in[24];
    const float* ba2   = (const float*)d_in[25];
    const float* Wc1   = (const float*)d_in[26];
    const float* bc1   = (const float*)d_in[27];
    const float* Wc2   = (const float*)d_in[28];
    const float* bc2   = (const float*)d_in[29];
    const float* Wc3   = (const float*)d_in[30];
    const float* bc3   = (const float*)d_in[31];
    const float* Wn1   = (const float*)d_in[32];
    const float* bn1   = (const float*)d_in[33];
    const float* Wn2   = (const float*)d_in[34];
    const float* bn2   = (const float*)d_in[35];

    float* outp = (float*)d_out;

    // workspace layout
    char* ws = (char*)d_ws;
    size_t o = 0;
    auto alloc = [&](size_t bytes) { size_t r = o; o = (o + bytes + 511) & ~((size_t)511); return r; };
    int*      flags  = (int*)     (ws + alloc(16));
    float*    dinv   = (float*)   (ws + alloc(N_NODES * 4));
    int*      offs   = (int*)     (ws + alloc((N_NODES + 1) * 4));
    int*      gcnt   = (int*)     (ws + alloc(NSEGS * CPAD * 4));
    int*      gcur   = (int*)     (ws + alloc(NSEGS * CPAD * 4));
    int*      gbase  = (int*)     (ws + alloc((NSEGS + 1) * 4));
    uint2*    rec    = (uint2*)   (ws + alloc((size_t)N_EDGES * 8));
    uint2*    rec2   = (uint2*)   (ws + alloc((size_t)N_EDGES * 8));
    ushort_t* srcS   = (ushort_t*)(ws + alloc(N_EDGES * 2));
    float*    wS     = (float*)   (ws + alloc(N_EDGES * 4));
    float*    pexp   = (float*)   (ws + alloc(N_NODES * 4));
    float*    Wcat   = (float*)   (ws + alloc(HF * HF * 4));
    float*    bcat   = (float*)   (ws + alloc(HF * 4));
    float*    sc1    = (float*)   (ws + alloc(HF * 4));
    float*    sh1    = (float*)   (ws + alloc(HF * 4));
    float*    sc2    = (float*)   (ws + alloc(HF * 4));
    float*    sh2    = (float*)   (ws + alloc(HF * 4));
    float*    red    = (float*)   (ws + alloc(16));
    float*    gpool  = (float*)   (ws + alloc(NB * LF * 4));
    float*    zsum   = (float*)   (ws + alloc(NB * LF * 4));
    float*    cnt    = (float*)   (ws + alloc(NB * 4));
    __half*   bufA   = (__half*)  (ws + alloc((size_t)N_NODES * 128 * 2));
    __half*   bufB   = (__half*)  (ws + alloc((size_t)N_NODES * 128 * 2));
    float*    zb     = (float*)   (ws + alloc((size_t)N_NODES * 64 * 4));
    (void)ws_size; (void)n_in; (void)in_sizes; (void)out_size;

    const int GN = (N_NODES + 255) / 256;     // 196
    const int GE = (N_EDGES + 255) / 256;     // 6250

    hipLaunchKernelGGL(detect_k, dim3(1), dim3(256), 0, stream, ei, flags);
    hipLaunchKernelGGL(init_k, dim3(GN), dim3(256), 0, stream,
                       gcnt, gpool, zsum, cnt, red, Wcat, bcat, sc1, sh1, sc2, sh2,
                       Wmu, bmu, Wlv, blv, g1, be1, rm1, rv1, g2, be2, rm2, rv2);
    hipLaunchKernelGGL(precount_k, dim3(GE), dim3(256), 0, stream, ei, gcnt, flags);
    hipLaunchKernelGGL(segscan_k, dim3(1), dim3(256), 0, stream, gcnt, gcur, gbase);
    hipLaunchKernelGGL(pass1_k, dim3(GE), dim3(256), 0, stream, ei, ew, gcur, rec, flags);
    hipLaunchKernelGGL(pass2_k, dim3(NBUCK), dim3(256), 0, stream, rec, gbase, rec2, offs, dinv);
    hipLaunchKernelGGL(ws_k, dim3(GE), dim3(256), 0, stream, rec2, dinv, srcS, wS);

    // encoder
    hipLaunchKernelGGL(gemm_in_k, dim3(N_NODES / 16), dim3(128), 0, stream, x, Win, bin, bufA);
    const int GG = (N_NODES + 63) / 64;       // 782
    const int GA = N_NODES / 4;               // 12500
    hipLaunchKernelGGL(gemm128_k, dim3(GG), dim3(256), 0, stream, bufA, W1, b1, bufB);
    hipLaunchKernelGGL((agg_k<0>), dim3(GA), dim3(256), 0, stream,
                       bufB, offs, srcS, wS, dinv, sc1, sh1, bufA, (float*)nullptr, (float*)nullptr);
    hipLaunchKernelGGL(gemm128_k, dim3(GG), dim3(256), 0, stream, bufA, W2, b2, bufB);
    hipLaunchKernelGGL((agg_k<0>), dim3(GA), dim3(256), 0, stream,
                       bufB, offs, srcS, wS, dinv, sc2, sh2, bufA, (float*)nullptr, (float*)nullptr);
    hipLaunchKernelGGL(gemm128_k, dim3(GG), dim3(256), 0, stream, bufA, Wcat, bcat, bufB);
    hipLaunchKernelGGL((agg_k<1>), dim3(GA), dim3(256), 0, stream,
                       bufB, offs, srcS, wS, dinv, (const float*)nullptr, (const float*)nullptr,
                       (__half*)nullptr, zb, outp);

    // attention + pooling + heads
    hipLaunchKernelGGL(att_k, dim3(GG), dim3(256), 0, stream, zb, Wa1, ba1, Wa2, ba2, pexp, red);
    hipLaunchKernelGGL(pool_k, dim3(GN), dim3(256), 0, stream, zb, pexp, batch, gpool, zsum, cnt, flags);
    hipLaunchKernelGGL(head_k, dim3(NB), dim3(128), 0, stream,
                       gpool, zsum, cnt, red, Wc1, bc1, Wc2, bc2, Wc3, bc3,
                       Wn1, bn1, Wn2, bn2, outp);
}

// Round 7
// 598.610 us; speedup vs baseline: 2.4988x; 1.2157x over previous
//
#include <hip/hip_runtime.h>
#include <hip/hip_fp16.h>

typedef unsigned short ushort_t;

#define N_NODES 50000
#define N_EDGES 1600000
#define NB      64
#define HF      128
#define LF      64
#define NC      6
#define EPSBN   1e-5f
#define NBUCK   196          // dst buckets of 256 nodes: 196*256 = 50176 >= 50000
#define CAPB    9216         // per-bucket padded capacity (mean 8163, sigma ~90)
#define EPB     2048         // edges per pass1 block

// output element offsets (fp32 out confirmed in round 3)
#define OPRED_OFF 0
#define OMU_OFF   384
#define OLV_OFF   3200384
#define ONOI_OFF  6400384

__device__ __forceinline__ int clampi(int v, int lo, int hi) {
    return v < lo ? lo : (v > hi ? hi : v);
}

// ============ int-width detection (flags[1] = 1 if int64) ============
__global__ void detect_k(const int* ei_raw, int* flags) {
    __shared__ int c1s;
    if (threadIdx.x == 0) c1s = 0;
    __syncthreads();
    if (ei_raw[2 * threadIdx.x + 1] != 0) atomicAdd(&c1s, 1);
    __syncthreads();
    if (threadIdx.x == 0) flags[1] = (c1s == 0) ? 1 : 0;
}

// ============ init: zero bucket counters/pools/red, fold BN, build Wcat ============
__global__ void init_k(int* bcnt, float* gpool, float* zsum, float* cnt, float* red,
                       float* Wcat, float* bcat, float* sc1, float* sh1, float* sc2, float* sh2,
                       const float* Wmu, const float* bmu, const float* Wlv, const float* blv,
                       const float* g1, const float* be1, const float* rm1, const float* rv1,
                       const float* g2, const float* be2, const float* rm2, const float* rv2) {
    int i = blockIdx.x * 256 + threadIdx.x;
    if (i < NBUCK) bcnt[i] = 0;
    if (i < NB * LF) { gpool[i] = 0.f; zsum[i] = 0.f; }
    if (i < NB) cnt[i] = 0.f;
    if (i < 4) red[i] = 0.f;
    if (i < HF * HF) {
        int k = i >> 7, c = i & 127;
        Wcat[i] = (c < 64) ? Wmu[k * 64 + c] : Wlv[k * 64 + (c - 64)];
    }
    if (i < HF) {
        bcat[i] = (i < 64) ? bmu[i] : blv[i - 64];
        float s1 = g1[i] * rsqrtf(rv1[i] + EPSBN);
        sc1[i] = s1; sh1[i] = be1[i] - rm1[i] * s1;
        float s2 = g2[i] * rsqrtf(rv2[i] + EPSBN);
        sc2[i] = s2; sh2[i] = be2[i] - rm2[i] * s2;
    }
}

// ============ pass 1: block-local LDS counting sort + run-append to padded buckets ============
__global__ __launch_bounds__(256) void pass1_k(const int* __restrict__ ei,
                                               const float* __restrict__ ew,
                                               int* __restrict__ bcnt,
                                               uint2* __restrict__ recP,
                                               const int* __restrict__ flags) {
    __shared__ uint2 stg[EPB];       // 16 KB staging, bucket-sorted
    __shared__ int lh[NBUCK];        // per-bucket count
    __shared__ int lcur[NBUCK];      // scatter cursor
    __shared__ int gb[NBUCK];        // global run base (within bucket region)
    __shared__ int loff[256];        // inclusive scan
    int tid = threadIdx.x;
    for (int i = tid; i < NBUCK; i += 256) lh[i] = 0;
    __syncthreads();
    int e0 = blockIdx.x * EPB;
    int i64 = flags[1];
    uint2 myrec[8]; int myb[8];
#pragma unroll
    for (int j = 0; j < 8; j++) {
        int e = e0 + j * 256 + tid;
        if (e < N_EDGES) {
            int di = N_EDGES + e;
            int s = clampi(ei[i64 ? 2 * e : e], 0, N_NODES - 1);
            int d = clampi(ei[i64 ? 2 * di : di], 0, N_NODES - 1);
            myrec[j] = make_uint2((unsigned)s | ((unsigned)d << 16), __float_as_uint(ew[e]));
            myb[j] = d >> 8;
            atomicAdd(&lh[myb[j]], 1);
        } else myb[j] = -1;
    }
    __syncthreads();
    loff[tid] = (tid < NBUCK) ? lh[tid] : 0;
    __syncthreads();
    for (int dth = 1; dth < 256; dth <<= 1) {
        int x = (tid >= dth) ? loff[tid - dth] : 0;
        __syncthreads();
        loff[tid] += x;
        __syncthreads();
    }
    if (tid < NBUCK) lcur[tid] = loff[tid] - lh[tid];   // exclusive start
    __syncthreads();
#pragma unroll
    for (int j = 0; j < 8; j++) {
        if (myb[j] >= 0) {
            int p = atomicAdd(&lcur[myb[j]], 1);
            stg[p] = myrec[j];
        }
    }
    if (tid < NBUCK) {
        int c = lh[tid];
        gb[tid] = (c > 0) ? atomicAdd(&bcnt[tid], c) : 0;
    }
    __syncthreads();
    int total = N_EDGES - e0; if (total > EPB) total = EPB;
    for (int idx = tid; idx < total; idx += 256) {
        uint2 r = stg[idx];
        int b = (int)(r.x >> 24);                 // dst >> 8
        int within = idx - (loff[b] - lh[b]);
        int pos = gb[b] + within;
        if (pos < CAPB) recP[b * CAPB + pos] = r; // overflow guard (never expected)
    }
}

// ============ scan 196 bucket counts -> global compact bases ============
__global__ __launch_bounds__(256) void bscan_k(const int* bcnt, int* gbase) {
    __shared__ int sh[256];
    int t = threadIdx.x;
    int c = (t < NBUCK) ? bcnt[t] : 0;
    if (c > CAPB) c = CAPB;
    sh[t] = c;
    __syncthreads();
    for (int dth = 1; dth < 256; dth <<= 1) {
        int x = (t >= dth) ? sh[t - dth] : 0;
        __syncthreads();
        sh[t] += x;
        __syncthreads();
    }
    if (t < NBUCK) gbase[t] = sh[t] - c;
    if (t == NBUCK - 1) gbase[NBUCK] = sh[t];
}

// ============ pass 2a: per-bucket hist + degree -> offs, dinv ============
__global__ __launch_bounds__(256) void pass2a_k(const uint2* __restrict__ recP,
                                                const int* __restrict__ gbase,
                                                int* __restrict__ offs,
                                                float* __restrict__ dinv) {
    __shared__ int cnt[256];
    __shared__ float degs[256];
    __shared__ int off[256];
    int b = blockIdx.x, t = threadIdx.x;
    cnt[t] = 0; degs[t] = 0.f;
    __syncthreads();
    int n0 = b * CAPB;
    int m = gbase[b + 1] - gbase[b];
    for (int i = t; i < m; i += 256) {
        uint2 r = recP[n0 + i];
        int dl = (r.x >> 16) & 255;
        atomicAdd(&cnt[dl], 1);
        atomicAdd(&degs[dl], __uint_as_float(r.y));
    }
    __syncthreads();
    int v = cnt[t];
    off[t] = v;
    __syncthreads();
    for (int dth = 1; dth < 256; dth <<= 1) {
        int x = (t >= dth) ? off[t - dth] : 0;
        __syncthreads();
        off[t] += x;
        __syncthreads();
    }
    int excl = off[t] - v;
    int n = (b << 8) + t;
    if (n < N_NODES) {
        offs[n] = gbase[b] + excl;
        dinv[n] = rsqrtf(1.f + degs[t]);
    }
    if (b == NBUCK - 1 && t == 0) offs[N_NODES] = gbase[NBUCK];
}

// ============ pass 2b: scatter to compact dst-sorted srcS + normalized wS ============
__global__ __launch_bounds__(256) void pass2b_k(const uint2* __restrict__ recP,
                                                const int* __restrict__ gbase,
                                                const int* __restrict__ offs,
                                                const float* __restrict__ dinv,
                                                ushort_t* __restrict__ srcS,
                                                float* __restrict__ wS) {
    __shared__ int cur[256];
    __shared__ float dloc[256];
    int b = blockIdx.x, t = threadIdx.x;
    int n = (b << 8) + t;
    cur[t] = (n < N_NODES) ? offs[n] : 0;
    dloc[t] = (n < N_NODES) ? dinv[n] : 0.f;
    __syncthreads();
    int n0 = b * CAPB;
    int m = gbase[b + 1] - gbase[b];
    for (int i = t; i < m; i += 256) {
        uint2 r = recP[n0 + i];
        int s = (int)(r.x & 0xFFFFu);
        int dl = (r.x >> 16) & 255;
        int p = atomicAdd(&cur[dl], 1);
        srcS[p] = (ushort_t)s;
        wS[p] = __uint_as_float(r.y) * dinv[s] * dloc[dl];
    }
}

// ============ input GEMM: x[N,16] @ W_in[16,128] + b -> h0 (fp16) ============
__global__ __launch_bounds__(128) void gemm_in_k(const float* __restrict__ x,
                                                 const float* __restrict__ Win,
                                                 const float* __restrict__ bin,
                                                 __half* __restrict__ out) {
    __shared__ float xl[16 * 16];
    int tid = threadIdx.x;
    int row0 = blockIdx.x * 16;
    if (tid < 64) {
        int r = tid >> 2, k4 = tid & 3;
        int row = row0 + r;
        float4 v = make_float4(0.f, 0.f, 0.f, 0.f);
        if (row < N_NODES) v = *(const float4*)(x + row * 16 + k4 * 4);
        *(float4*)(xl + r * 16 + k4 * 4) = v;
    }
    float wv[16];
#pragma unroll
    for (int k = 0; k < 16; k++) wv[k] = Win[k * 128 + tid];
    float bias = bin[tid];
    __syncthreads();
    for (int r = 0; r < 16; r++) {
        float acc = bias;
#pragma unroll
        for (int k = 0; k < 16; k++) acc += xl[r * 16 + k] * wv[k];
        int row = row0 + r;
        if (row < N_NODES) out[row * 128 + tid] = __float2half(acc);
    }
}

// ============ main GEMM: in(fp16)[N,128] @ W(fp32)[128,128] + b -> out(fp16) ============
__global__ __launch_bounds__(256) void gemm128_k(const __half* __restrict__ in,
                                                 const float* __restrict__ W,
                                                 const float* __restrict__ b,
                                                 __half* __restrict__ out) {
    __shared__ float At[64 * 128];
    int tid = threadIdx.x;
    int row0 = blockIdx.x * 64;
    union HU { unsigned u; __half2 h; };
    for (int v = tid; v < 1024; v += 256) {
        int r = v >> 4, c8 = (v & 15) * 8;
        int row = row0 + r;
        uint4 raw = make_uint4(0u, 0u, 0u, 0u);
        if (row < N_NODES) raw = *(const uint4*)(in + row * 128 + c8);
        HU u0, u1, u2, u3;
        u0.u = raw.x; u1.u = raw.y; u2.u = raw.z; u3.u = raw.w;
        float2 f0 = __half22float2(u0.h), f1 = __half22float2(u1.h);
        float2 f2 = __half22float2(u2.h), f3 = __half22float2(u3.h);
        *(float4*)(At + r * 128 + c8)     = make_float4(f0.x, f0.y, f1.x, f1.y);
        *(float4*)(At + r * 128 + c8 + 4) = make_float4(f2.x, f2.y, f3.x, f3.y);
    }
    __syncthreads();

    int cp = tid & 63, rg = tid >> 6;
    int c0 = cp * 2;
    float acc0[16], acc1[16];
    float bx = b[c0], by = b[c0 + 1];
#pragma unroll
    for (int r = 0; r < 16; r++) { acc0[r] = bx; acc1[r] = by; }

    for (int kb = 0; kb < 128; kb += 4) {
        float wx[4], wy[4];
#pragma unroll
        for (int j = 0; j < 4; j++) {
            float2 w = *(const float2*)(W + (kb + j) * 128 + c0);
            wx[j] = w.x; wy[j] = w.y;
        }
#pragma unroll
        for (int r = 0; r < 16; r++) {
            float4 a = *(const float4*)(At + (rg * 16 + r) * 128 + kb);
            acc0[r] += a.x * wx[0] + a.y * wx[1] + a.z * wx[2] + a.w * wx[3];
            acc1[r] += a.x * wy[0] + a.y * wy[1] + a.z * wy[2] + a.w * wy[3];
        }
    }
#pragma unroll
    for (int r = 0; r < 16; r++) {
        int row = row0 + rg * 16 + r;
        if (row < N_NODES) {
            *(__half2*)(out + row * 128 + c0) = __floats2half2_rn(acc0[r], acc1[r]);
        }
    }
}

// ============ aggregation: 1 wave per node, half2 lanes, 8x-unrolled gather ============
template <int MODE>
__global__ __launch_bounds__(256) void agg_k(const __half* __restrict__ lin,
                                             const int* __restrict__ offs,
                                             const ushort_t* __restrict__ srcS,
                                             const float* __restrict__ wS,
                                             const float* __restrict__ dinv,
                                             const float* __restrict__ sc,
                                             const float* __restrict__ sh,
                                             __half* __restrict__ outH,
                                             float* __restrict__ zb,
                                             float* __restrict__ outp) {
    int tid = threadIdx.x;
    int n = blockIdx.x * 4 + (tid >> 6);
    int t = tid & 63;
    const __half2* linv = (const __half2*)lin;
    float dv = dinv[n];
    float2 self = __half22float2(linv[n * 64 + t]);
    float ax = self.x * dv * dv, ay = self.y * dv * dv;
    int e0 = offs[n], e1 = offs[n + 1];
    int e = e0;
    for (; e + 8 <= e1; e += 8) {
        int s[8]; float w[8]; __half2 h[8];
#pragma unroll
        for (int j = 0; j < 8; j++) { s[j] = srcS[e + j]; w[j] = wS[e + j]; }
#pragma unroll
        for (int j = 0; j < 8; j++) h[j] = linv[s[j] * 64 + t];
#pragma unroll
        for (int j = 0; j < 8; j++) {
            float2 f = __half22float2(h[j]);
            ax += w[j] * f.x; ay += w[j] * f.y;
        }
    }
    for (; e < e1; e++) {
        float2 f = __half22float2(linv[(int)srcS[e] * 64 + t]);
        float w = wS[e];
        ax += w * f.x; ay += w * f.y;
    }
    if (MODE == 0) {
        float2 s2 = *(const float2*)(sc + 2 * t);
        float2 h2 = *(const float2*)(sh + 2 * t);
        float o0 = fmaxf(ax * s2.x + h2.x, 0.f);
        float o1 = fmaxf(ay * s2.y + h2.y, 0.f);
        *(__half2*)(outH + n * 128 + 2 * t) = __floats2half2_rn(o0, o1);
    } else {
        if (t < 32) {
            *(float2*)(zb + n * 64 + 2 * t) = make_float2(ax, ay);
            *(float2*)(outp + OMU_OFF + n * 64 + 2 * t) = make_float2(ax, ay);
        } else {
            int c = 2 * t - 64;
            *(float2*)(outp + OLV_OFF + n * 64 + c) = make_float2(ax, ay);
        }
    }
}

// ============ attention (gemm-style): p[n] = exp(tanh(z Wa1 + ba1) Wa2 + ba2) ============
__global__ __launch_bounds__(256) void att_k(const float* __restrict__ zb,
                                             const float* __restrict__ Wa1,
                                             const float* __restrict__ ba1,
                                             const float* __restrict__ Wa2,
                                             const float* __restrict__ ba2,
                                             float* __restrict__ p, float* __restrict__ red) {
    __shared__ float zl[64 * 64];    // 16 KB
    int tid = threadIdx.x;
    int row0 = blockIdx.x * 64;
    for (int v = tid; v < 1024; v += 256) {
        int r = v >> 4, k4 = (v & 15) * 4;
        int row = row0 + r;
        float4 val = make_float4(0.f, 0.f, 0.f, 0.f);
        if (row < N_NODES) val = *(const float4*)(zb + row * 64 + k4);
        *(float4*)(zl + r * 64 + k4) = val;
    }
    int cp = tid & 63, rg = tid >> 6;
    int c0 = cp * 2;
    float acc0[16], acc1[16];
    float b0 = ba1[c0], b1 = ba1[c0 + 1];
#pragma unroll
    for (int r = 0; r < 16; r++) { acc0[r] = b0; acc1[r] = b1; }
    float a0 = Wa2[c0], a1 = Wa2[c0 + 1];
    float ba2v = ba2[0];
    __syncthreads();
    for (int kb = 0; kb < 64; kb += 4) {
        float wx[4], wy[4];
#pragma unroll
        for (int j = 0; j < 4; j++) {
            float2 w = *(const float2*)(Wa1 + (kb + j) * 128 + c0);
            wx[j] = w.x; wy[j] = w.y;
        }
#pragma unroll
        for (int r = 0; r < 16; r++) {
            float4 a = *(const float4*)(zl + (rg * 16 + r) * 64 + kb);
            acc0[r] += a.x * wx[0] + a.y * wx[1] + a.z * wx[2] + a.w * wx[3];
            acc1[r] += a.x * wy[0] + a.y * wy[1] + a.z * wy[2] + a.w * wy[3];
        }
    }
    float wsum = 0.f;
#pragma unroll
    for (int r = 0; r < 16; r++) {
        float y = tanhf(acc0[r]) * a0 + tanhf(acc1[r]) * a1;
#pragma unroll
        for (int off = 32; off > 0; off >>= 1) y += __shfl_down(y, off, 64);
        if (cp == 0) {
            int row = row0 + rg * 16 + r;
            if (row < N_NODES) {
                float pe = expf(y + ba2v);
                p[row] = pe;
                wsum += pe;
            }
        }
    }
    if (cp == 0) atomicAdd(&red[1], wsum);
}

// ============ pooling (4 groups of 64 per block) ============
__global__ __launch_bounds__(256) void pool_k(const float* __restrict__ zb,
                                              const float* __restrict__ p,
                                              const int* __restrict__ batch,
                                              float* gpool, float* zsum, float* cnt,
                                              const int* __restrict__ flags) {
    int l = threadIdx.x & 63, g = threadIdx.x >> 6;
    int i64 = flags[1];
    int nstart = blockIdx.x * 256 + g * 64;
    float ag = 0.f, az = 0.f, c = 0.f;
    int cur = -1;
    for (int i = 0; i < 64; i++) {
        int n = nstart + i;
        if (n >= N_NODES) break;
        int b = clampi(batch[i64 ? 2 * n : n], 0, NB - 1);
        if (b != cur) {
            if (cur >= 0) {
                atomicAdd(&gpool[cur * 64 + l], ag);
                atomicAdd(&zsum[cur * 64 + l], az);
                if (l == 0) atomicAdd(&cnt[cur], c);
            }
            cur = b; ag = 0.f; az = 0.f; c = 0.f;
        }
        float pe = p[n];
        float zv = zb[n * 64 + l];
        ag += pe * zv; az += zv; c += 1.f;
    }
    if (cur >= 0) {
        atomicAdd(&gpool[cur * 64 + l], ag);
        atomicAdd(&zsum[cur * 64 + l], az);
        if (l == 0) atomicAdd(&cnt[cur], c);
    }
}

// ============ per-graph heads ============
__global__ __launch_bounds__(128) void head_k(const float* __restrict__ gpool,
                                              const float* __restrict__ zsum,
                                              const float* __restrict__ cnt,
                                              const float* __restrict__ red,
                                              const float* Wc1, const float* bc1,
                                              const float* Wc2, const float* bc2,
                                              const float* Wc3, const float* bc3,
                                              const float* Wn1, const float* bn1,
                                              const float* Wn2, const float* bn2,
                                              float* __restrict__ outp) {
    __shared__ float gsh[64], zm[64], p1[128], p2[64], n1[64];
    int b = blockIdx.x, t = threadIdx.x;
    float S = red[1];
    if (t < 64) {
        gsh[t] = gpool[b * 64 + t] / S;
        zm[t] = zsum[b * 64 + t] / fmaxf(cnt[b], 1.f);
    }
    __syncthreads();
    {
        float acc = bc1[t];
        for (int k = 0; k < 64; k++) acc += gsh[k] * Wc1[k * 128 + t];
        p1[t] = fmaxf(acc, 0.f);
    }
    __syncthreads();
    if (t < 64) {
        float acc = bc2[t];
        for (int k = 0; k < 128; k++) acc += p1[k] * Wc2[k * 64 + t];
        p2[t] = fmaxf(acc, 0.f);
    } else {
        int tt = t - 64;
        float acc = bn1[tt];
        for (int k = 0; k < 64; k++) acc += zm[k] * Wn1[k * 64 + tt];
        n1[tt] = fmaxf(acc, 0.f);
    }
    __syncthreads();
    if (t < NC) {
        float acc = bc3[t];
        for (int k = 0; k < 64; k++) acc += p2[k] * Wc3[k * 6 + t];
        outp[OPRED_OFF + b * 6 + t] = acc;
    }
    if (t == 64) {
        float acc = bn2[0];
        for (int k = 0; k < 64; k++) acc += n1[k] * Wn2[k];
        outp[ONOI_OFF + b] = 1.f / (1.f + expf(-acc));
    }
}

extern "C" void kernel_launch(void* const* d_in, const int* in_sizes, int n_in,
                              void* d_out, int out_size, void* d_ws, size_t ws_size,
                              hipStream_t stream) {
    const int*   ei    = (const int*)d_in[1];
    const int*   batch = (const int*)d_in[3];
    const float* x     = (const float*)d_in[0];
    const float* ew    = (const float*)d_in[2];
    const float* Win   = (const float*)d_in[4];
    const float* bin   = (const float*)d_in[5];
    const float* W1    = (const float*)d_in[6];
    const float* b1    = (const float*)d_in[7];
    const float* W2    = (const float*)d_in[8];
    const float* b2    = (const float*)d_in[9];
    const float* Wmu   = (const float*)d_in[10];
    const float* bmu   = (const float*)d_in[11];
    const float* Wlv   = (const float*)d_in[12];
    const float* blv   = (const float*)d_in[13];
    const float* g1    = (const float*)d_in[14];
    const float* be1   = (const float*)d_in[15];
    const float* rm1   = (const float*)d_in[16];
    const float* rv1   = (const float*)d_in[17];
    const float* g2    = (const float*)d_in[18];
    const float* be2   = (const float*)d_in[19];
    const float* rm2   = (const float*)d_in[20];
    const float* rv2   = (const float*)d_in[21];
    const float* Wa1   = (const float*)d_in[22];
    const float* ba1   = (const float*)d_in[23];
    const float* Wa2   = (const float*)d_in[24];
    const float* ba2   = (const float*)d_in[25];
    const float* Wc1   = (const float*)d_in[26];
    const float* bc1   = (const float*)d_in[27];
    const float* Wc2   = (const float*)d_in[28];
    const float* bc2   = (const float*)d_in[29];
    const float* Wc3   = (const float*)d_in[30];
    const float* bc3   = (const float*)d_in[31];
    const float* Wn1   = (const float*)d_in[32];
    const float* bn1   = (const float*)d_in[33];
    const float* Wn2   = (const float*)d_in[34];
    const float* bn2   = (const float*)d_in[35];

    float* outp = (float*)d_out;

    // workspace layout
    char* ws = (char*)d_ws;
    size_t o = 0;
    auto alloc = [&](size_t bytes) { size_t r = o; o = (o + bytes + 511) & ~((size_t)511); return r; };
    int*      flags  = (int*)     (ws + alloc(16));
    float*    dinv   = (float*)   (ws + alloc(N_NODES * 4));
    int*      offs   = (int*)     (ws + alloc((N_NODES + 1) * 4));
    int*      bcnt   = (int*)     (ws + alloc(NBUCK * 4));
    int*      gbase  = (int*)     (ws + alloc((NBUCK + 1) * 4));
    uint2*    recP   = (uint2*)   (ws + alloc((size_t)NBUCK * CAPB * 8));   // 14.5 MB
    ushort_t* srcS   = (ushort_t*)(ws + alloc(N_EDGES * 2));
    float*    wS     = (float*)   (ws + alloc(N_EDGES * 4));
    float*    pexp   = (float*)   (ws + alloc(N_NODES * 4));
    float*    Wcat   = (float*)   (ws + alloc(HF * HF * 4));
    float*    bcat   = (float*)   (ws + alloc(HF * 4));
    float*    sc1    = (float*)   (ws + alloc(HF * 4));
    float*    sh1    = (float*)   (ws + alloc(HF * 4));
    float*    sc2    = (float*)   (ws + alloc(HF * 4));
    float*    sh2    = (float*)   (ws + alloc(HF * 4));
    float*    red    = (float*)   (ws + alloc(16));
    float*    gpool  = (float*)   (ws + alloc(NB * LF * 4));
    float*    zsum   = (float*)   (ws + alloc(NB * LF * 4));
    float*    cnt    = (float*)   (ws + alloc(NB * 4));
    __half*   bufA   = (__half*)  (ws + alloc((size_t)N_NODES * 128 * 2));
    __half*   bufB   = (__half*)  (ws + alloc((size_t)N_NODES * 128 * 2));
    float*    zb     = (float*)   (ws + alloc((size_t)N_NODES * 64 * 4));
    (void)ws_size; (void)n_in; (void)in_sizes; (void)out_size;

    const int GN = (N_NODES + 255) / 256;     // 196
    const int GP = (N_EDGES + EPB - 1) / EPB; // 782

    hipLaunchKernelGGL(detect_k, dim3(1), dim3(256), 0, stream, ei, flags);
    hipLaunchKernelGGL(init_k, dim3(GN), dim3(256), 0, stream,
                       bcnt, gpool, zsum, cnt, red, Wcat, bcat, sc1, sh1, sc2, sh2,
                       Wmu, bmu, Wlv, blv, g1, be1, rm1, rv1, g2, be2, rm2, rv2);
    hipLaunchKernelGGL(pass1_k, dim3(GP), dim3(256), 0, stream, ei, ew, bcnt, recP, flags);
    hipLaunchKernelGGL(bscan_k, dim3(1), dim3(256), 0, stream, bcnt, gbase);
    hipLaunchKernelGGL(pass2a_k, dim3(NBUCK), dim3(256), 0, stream, recP, gbase, offs, dinv);
    hipLaunchKernelGGL(pass2b_k, dim3(NBUCK), dim3(256), 0, stream, recP, gbase, offs, dinv, srcS, wS);

    // encoder
    hipLaunchKernelGGL(gemm_in_k, dim3(N_NODES / 16), dim3(128), 0, stream, x, Win, bin, bufA);
    const int GG = (N_NODES + 63) / 64;       // 782
    const int GA = N_NODES / 4;               // 12500
    hipLaunchKernelGGL(gemm128_k, dim3(GG), dim3(256), 0, stream, bufA, W1, b1, bufB);
    hipLaunchKernelGGL((agg_k<0>), dim3(GA), dim3(256), 0, stream,
                       bufB, offs, srcS, wS, dinv, sc1, sh1, bufA, (float*)nullptr, (float*)nullptr);
    hipLaunchKernelGGL(gemm128_k, dim3(GG), dim3(256), 0, stream, bufA, W2, b2, bufB);
    hipLaunchKernelGGL((agg_k<0>), dim3(GA), dim3(256), 0, stream,
                       bufB, offs, srcS, wS, dinv, sc2, sh2, bufA, (float*)nullptr, (float*)nullptr);
    hipLaunchKernelGGL(gemm128_k, dim3(GG), dim3(256), 0, stream, bufA, Wcat, bcat, bufB);
    hipLaunchKernelGGL((agg_k<1>), dim3(GA), dim3(256), 0, stream,
                       bufB, offs, srcS, wS, dinv, (const float*)nullptr, (const float*)nullptr,
                       (__half*)nullptr, zb, outp);

    // attention + pooling + heads
    hipLaunchKernelGGL(att_k, dim3(GG), dim3(256), 0, stream, zb, Wa1, ba1, Wa2, ba2, pexp, red);
    hipLaunchKernelGGL(pool_k, dim3(GN), dim3(256), 0, stream, zb, pexp, batch, gpool, zsum, cnt, flags);
    hipLaunchKernelGGL(head_k, dim3(NB), dim3(128), 0, stream,
                       gpool, zsum, cnt, red, Wc1, bc1, Wc2, bc2, Wc3, bc3,
                       Wn1, bn1, Wn2, bn2, outp);
}

// Round 8
// 499.798 us; speedup vs baseline: 2.9929x; 1.1977x over previous
//
#include <hip/hip_runtime.h>
#include <hip/hip_fp16.h>

typedef unsigned short ushort_t;
typedef _Float16 h8v __attribute__((ext_vector_type(8)));
typedef float f4v __attribute__((ext_vector_type(4)));

#define N_NODES 50000
#define N_EDGES 1600000
#define NB      64
#define HF      128
#define LF      64
#define NC      6
#define EPSBN   1e-5f
#define NBUCK   196          // dst buckets of 256 nodes
#define CAPB    9216         // per-bucket padded capacity
#define EPB     2048         // edges per pass1 block

// output element offsets (fp32 out confirmed in round 3)
#define OPRED_OFF 0
#define OMU_OFF   384
#define OLV_OFF   3200384
#define ONOI_OFF  6400384

__device__ __forceinline__ int clampi(int v, int lo, int hi) {
    return v < lo ? lo : (v > hi ? hi : v);
}

// ============ int-width detection (flags[1] = 1 if int64) ============
__global__ void detect_k(const int* ei_raw, int* flags) {
    __shared__ int c1s;
    if (threadIdx.x == 0) c1s = 0;
    __syncthreads();
    if (ei_raw[2 * threadIdx.x + 1] != 0) atomicAdd(&c1s, 1);
    __syncthreads();
    if (threadIdx.x == 0) flags[1] = (c1s == 0) ? 1 : 0;
}

// ============ init: zero counters/pools, fold BN, build fp16-swizzled weights ============
// swizzle: Wsw[((k>>5)*128 + c)*32 + (k&31)] = W[k][c]  (B-frag = contiguous 16B per lane)
__global__ void init_k(int* bcnt, float* gpool, float* zsum, float* cnt, float* red,
                       _Float16* W1sw, _Float16* W2sw, _Float16* Wcsw, _Float16* Wasw,
                       float* bcat, float* sc1, float* sh1, float* sc2, float* sh2,
                       const float* W1, const float* W2,
                       const float* Wmu, const float* bmu, const float* Wlv, const float* blv,
                       const float* Wa1,
                       const float* g1, const float* be1, const float* rm1, const float* rv1,
                       const float* g2, const float* be2, const float* rm2, const float* rv2) {
    int i = blockIdx.x * 256 + threadIdx.x;
    if (i < NBUCK) bcnt[i] = 0;
    if (i < NB * LF) { gpool[i] = 0.f; zsum[i] = 0.f; }
    if (i < NB) cnt[i] = 0.f;
    if (i < 4) red[i] = 0.f;
    if (i < HF * HF) {
        int k = i >> 7, c = i & 127;
        int idx = ((k >> 5) * 128 + c) * 32 + (k & 31);
        W1sw[idx] = (_Float16)W1[i];
        W2sw[idx] = (_Float16)W2[i];
        float wc = (c < 64) ? Wmu[k * 64 + c] : Wlv[k * 64 + (c - 64)];
        Wcsw[idx] = (_Float16)wc;
    }
    if (i < LF * HF) {   // Wa1: 64x128
        int k = i >> 7, c = i & 127;
        int idx = ((k >> 5) * 128 + c) * 32 + (k & 31);
        Wasw[idx] = (_Float16)Wa1[i];
    }
    if (i < HF) {
        bcat[i] = (i < 64) ? bmu[i] : blv[i - 64];
        float s1 = g1[i] * rsqrtf(rv1[i] + EPSBN);
        sc1[i] = s1; sh1[i] = be1[i] - rm1[i] * s1;
        float s2 = g2[i] * rsqrtf(rv2[i] + EPSBN);
        sc2[i] = s2; sh2[i] = be2[i] - rm2[i] * s2;
    }
}

// ============ pass 1: block-local LDS counting sort + run-append to padded buckets ============
__global__ __launch_bounds__(256) void pass1_k(const int* __restrict__ ei,
                                               const float* __restrict__ ew,
                                               int* __restrict__ bcnt,
                                               uint2* __restrict__ recP,
                                               const int* __restrict__ flags) {
    __shared__ uint2 stg[EPB];
    __shared__ int lh[NBUCK];
    __shared__ int lcur[NBUCK];
    __shared__ int gb[NBUCK];
    __shared__ int loff[256];
    int tid = threadIdx.x;
    for (int i = tid; i < NBUCK; i += 256) lh[i] = 0;
    __syncthreads();
    int e0 = blockIdx.x * EPB;
    int i64 = flags[1];
    uint2 myrec[8]; int myb[8];
#pragma unroll
    for (int j = 0; j < 8; j++) {
        int e = e0 + j * 256 + tid;
        if (e < N_EDGES) {
            int di = N_EDGES + e;
            int s = clampi(ei[i64 ? 2 * e : e], 0, N_NODES - 1);
            int d = clampi(ei[i64 ? 2 * di : di], 0, N_NODES - 1);
            myrec[j] = make_uint2((unsigned)s | ((unsigned)d << 16), __float_as_uint(ew[e]));
            myb[j] = d >> 8;
            atomicAdd(&lh[myb[j]], 1);
        } else myb[j] = -1;
    }
    __syncthreads();
    loff[tid] = (tid < NBUCK) ? lh[tid] : 0;
    __syncthreads();
    for (int dth = 1; dth < 256; dth <<= 1) {
        int x = (tid >= dth) ? loff[tid - dth] : 0;
        __syncthreads();
        loff[tid] += x;
        __syncthreads();
    }
    if (tid < NBUCK) lcur[tid] = loff[tid] - lh[tid];
    __syncthreads();
#pragma unroll
    for (int j = 0; j < 8; j++) {
        if (myb[j] >= 0) {
            int p = atomicAdd(&lcur[myb[j]], 1);
            stg[p] = myrec[j];
        }
    }
    if (tid < NBUCK) {
        int c = lh[tid];
        gb[tid] = (c > 0) ? atomicAdd(&bcnt[tid], c) : 0;
    }
    __syncthreads();
    int total = N_EDGES - e0; if (total > EPB) total = EPB;
    for (int idx = tid; idx < total; idx += 256) {
        uint2 r = stg[idx];
        int b = (int)(r.x >> 24);
        int within = idx - (loff[b] - lh[b]);
        int pos = gb[b] + within;
        if (pos < CAPB) recP[b * CAPB + pos] = r;
    }
}

// ============ scan 196 bucket counts -> global compact bases ============
__global__ __launch_bounds__(256) void bscan_k(const int* bcnt, int* gbase) {
    __shared__ int sh[256];
    int t = threadIdx.x;
    int c = (t < NBUCK) ? bcnt[t] : 0;
    if (c > CAPB) c = CAPB;
    sh[t] = c;
    __syncthreads();
    for (int dth = 1; dth < 256; dth <<= 1) {
        int x = (t >= dth) ? sh[t - dth] : 0;
        __syncthreads();
        sh[t] += x;
        __syncthreads();
    }
    if (t < NBUCK) gbase[t] = sh[t] - c;
    if (t == NBUCK - 1) gbase[NBUCK] = sh[t];
}

// ============ pass 2a: per-bucket hist + degree -> offs, dinv ============
__global__ __launch_bounds__(256) void pass2a_k(const uint2* __restrict__ recP,
                                                const int* __restrict__ gbase,
                                                int* __restrict__ offs,
                                                float* __restrict__ dinv) {
    __shared__ int cnt[256];
    __shared__ float degs[256];
    __shared__ int off[256];
    int b = blockIdx.x, t = threadIdx.x;
    cnt[t] = 0; degs[t] = 0.f;
    __syncthreads();
    int n0 = b * CAPB;
    int m = gbase[b + 1] - gbase[b];
    for (int i = t; i < m; i += 256) {
        uint2 r = recP[n0 + i];
        int dl = (r.x >> 16) & 255;
        atomicAdd(&cnt[dl], 1);
        atomicAdd(&degs[dl], __uint_as_float(r.y));
    }
    __syncthreads();
    int v = cnt[t];
    off[t] = v;
    __syncthreads();
    for (int dth = 1; dth < 256; dth <<= 1) {
        int x = (t >= dth) ? off[t - dth] : 0;
        __syncthreads();
        off[t] += x;
        __syncthreads();
    }
    int excl = off[t] - v;
    int n = (b << 8) + t;
    if (n < N_NODES) {
        offs[n] = gbase[b] + excl;
        dinv[n] = rsqrtf(1.f + degs[t]);
    }
    if (b == NBUCK - 1 && t == 0) offs[N_NODES] = gbase[NBUCK];
}

// ============ pass 2b: scatter to compact dst-sorted srcS + normalized wS ============
__global__ __launch_bounds__(256) void pass2b_k(const uint2* __restrict__ recP,
                                                const int* __restrict__ gbase,
                                                const int* __restrict__ offs,
                                                const float* __restrict__ dinv,
                                                ushort_t* __restrict__ srcS,
                                                float* __restrict__ wS) {
    __shared__ int cur[256];
    __shared__ float dloc[256];
    int b = blockIdx.x, t = threadIdx.x;
    int n = (b << 8) + t;
    cur[t] = (n < N_NODES) ? offs[n] : 0;
    dloc[t] = (n < N_NODES) ? dinv[n] : 0.f;
    __syncthreads();
    int n0 = b * CAPB;
    int m = gbase[b + 1] - gbase[b];
    for (int i = t; i < m; i += 256) {
        uint2 r = recP[n0 + i];
        int s = (int)(r.x & 0xFFFFu);
        int dl = (r.x >> 16) & 255;
        int p = atomicAdd(&cur[dl], 1);
        srcS[p] = (ushort_t)s;
        wS[p] = __uint_as_float(r.y) * dinv[s] * dloc[dl];
    }
}

// ============ input GEMM: x[N,16] @ W_in[16,128] + b -> h0 (fp16) ============
__global__ __launch_bounds__(128) void gemm_in_k(const float* __restrict__ x,
                                                 const float* __restrict__ Win,
                                                 const float* __restrict__ bin,
                                                 __half* __restrict__ out) {
    __shared__ float xl[16 * 16];
    int tid = threadIdx.x;
    int row0 = blockIdx.x * 16;
    if (tid < 64) {
        int r = tid >> 2, k4 = tid & 3;
        int row = row0 + r;
        float4 v = make_float4(0.f, 0.f, 0.f, 0.f);
        if (row < N_NODES) v = *(const float4*)(x + row * 16 + k4 * 4);
        *(float4*)(xl + r * 16 + k4 * 4) = v;
    }
    float wv[16];
#pragma unroll
    for (int k = 0; k < 16; k++) wv[k] = Win[k * 128 + tid];
    float bias = bin[tid];
    __syncthreads();
    for (int r = 0; r < 16; r++) {
        float acc = bias;
#pragma unroll
        for (int k = 0; k < 16; k++) acc += xl[r * 16 + k] * wv[k];
        int row = row0 + r;
        if (row < N_NODES) out[row * 128 + tid] = __float2half(acc);
    }
}

// ============ MFMA GEMM: in(fp16)[N,128] @ Wsw(fp16,swizzled)[128,128] + b -> out(fp16) ============
// wave = 16 rows x 128 cols; block = 64 rows. A[m=l&15][k=q*8+j]; B[k=q*8+j][n=l&15];
// D: col=l&15, row=q*4+r.
__global__ __launch_bounds__(256) void gemm128_k(const __half* __restrict__ in,
                                                 const _Float16* __restrict__ Wsw,
                                                 const float* __restrict__ b,
                                                 __half* __restrict__ out) {
    int l = threadIdx.x & 63, w = threadIdx.x >> 6;
    int row0 = blockIdx.x * 64 + w * 16;
    int m = l & 15, q = l >> 4;
    int row = row0 + m;
    bool rok = row < N_NODES;
    const h8v* inp = (const h8v*)in;
    const h8v* wp = (const h8v*)Wsw;
    h8v az = {0, 0, 0, 0, 0, 0, 0, 0};
    h8v a[4];
#pragma unroll
    for (int kb = 0; kb < 4; kb++)
        a[kb] = rok ? inp[(row * 128 + kb * 32 + q * 8) >> 3] : az;
#pragma unroll
    for (int ct = 0; ct < 8; ct++) {
        f4v acc = {0.f, 0.f, 0.f, 0.f};
#pragma unroll
        for (int kb = 0; kb < 4; kb++) {
            h8v bf = wp[((kb * 128 + ct * 16 + m) * 32 + q * 8) >> 3];
            acc = __builtin_amdgcn_mfma_f32_16x16x32_f16(a[kb], bf, acc, 0, 0, 0);
        }
        int col = ct * 16 + m;
        float bias = b[col];
#pragma unroll
        for (int r = 0; r < 4; r++) {
            int orow = row0 + q * 4 + r;
            if (orow < N_NODES) out[orow * 128 + col] = __float2half(acc[r] + bias);
        }
    }
}

// ============ aggregation: 1 wave per node, half2 lanes, 8x-unrolled gather ============
template <int MODE>
__global__ __launch_bounds__(256) void agg_k(const __half* __restrict__ lin,
                                             const int* __restrict__ offs,
                                             const ushort_t* __restrict__ srcS,
                                             const float* __restrict__ wS,
                                             const float* __restrict__ dinv,
                                             const float* __restrict__ sc,
                                             const float* __restrict__ sh,
                                             __half* __restrict__ outH,
                                             __half* __restrict__ zh,
                                             float* __restrict__ outp) {
    int tid = threadIdx.x;
    int n = blockIdx.x * 4 + (tid >> 6);
    int t = tid & 63;
    const __half2* linv = (const __half2*)lin;
    float dv = dinv[n];
    float2 self = __half22float2(linv[n * 64 + t]);
    float ax = self.x * dv * dv, ay = self.y * dv * dv;
    int e0 = offs[n], e1 = offs[n + 1];
    int e = e0;
    for (; e + 8 <= e1; e += 8) {
        int s[8]; float w[8]; __half2 h[8];
#pragma unroll
        for (int j = 0; j < 8; j++) { s[j] = srcS[e + j]; w[j] = wS[e + j]; }
#pragma unroll
        for (int j = 0; j < 8; j++) h[j] = linv[s[j] * 64 + t];
#pragma unroll
        for (int j = 0; j < 8; j++) {
            float2 f = __half22float2(h[j]);
            ax += w[j] * f.x; ay += w[j] * f.y;
        }
    }
    for (; e < e1; e++) {
        float2 f = __half22float2(linv[(int)srcS[e] * 64 + t]);
        float w = wS[e];
        ax += w * f.x; ay += w * f.y;
    }
    if (MODE == 0) {
        float2 s2 = *(const float2*)(sc + 2 * t);
        float2 h2 = *(const float2*)(sh + 2 * t);
        float o0 = fmaxf(ax * s2.x + h2.x, 0.f);
        float o1 = fmaxf(ay * s2.y + h2.y, 0.f);
        *(__half2*)(outH + n * 128 + 2 * t) = __floats2half2_rn(o0, o1);
    } else {
        if (t < 32) {
            *(float2*)(outp + OMU_OFF + n * 64 + 2 * t) = make_float2(ax, ay);
            ((__half2*)zh)[n * 32 + t] = __floats2half2_rn(ax, ay);
        } else {
            *(float2*)(outp + OLV_OFF + n * 64 + (2 * t - 64)) = make_float2(ax, ay);
        }
    }
}

// ============ attention via MFMA: p = exp(tanh(zh @ Wa1 + ba1) @ Wa2 + ba2) ============
__global__ __launch_bounds__(256) void att_k(const __half* __restrict__ zh,
                                             const _Float16* __restrict__ Wasw,
                                             const float* __restrict__ ba1,
                                             const float* __restrict__ Wa2,
                                             const float* __restrict__ ba2,
                                             float* __restrict__ p, float* __restrict__ red) {
    __shared__ float rsum[4];
    int l = threadIdx.x & 63, w = threadIdx.x >> 6;
    int row0 = blockIdx.x * 64 + w * 16;
    int m = l & 15, q = l >> 4;
    int row = row0 + m;
    bool rok = row < N_NODES;
    const h8v* zp = (const h8v*)zh;
    const h8v* wp = (const h8v*)Wasw;
    h8v az = {0, 0, 0, 0, 0, 0, 0, 0};
    h8v a[2];
#pragma unroll
    for (int kb = 0; kb < 2; kb++)
        a[kb] = rok ? zp[(row * 64 + kb * 32 + q * 8) >> 3] : az;
    float ysum[4] = {0.f, 0.f, 0.f, 0.f};
#pragma unroll
    for (int ct = 0; ct < 8; ct++) {
        f4v acc = {0.f, 0.f, 0.f, 0.f};
#pragma unroll
        for (int kb = 0; kb < 2; kb++) {
            h8v bf = wp[((kb * 128 + ct * 16 + m) * 32 + q * 8) >> 3];
            acc = __builtin_amdgcn_mfma_f32_16x16x32_f16(a[kb], bf, acc, 0, 0, 0);
        }
        int col = ct * 16 + m;
        float bb = ba1[col], wa2 = Wa2[col];
#pragma unroll
        for (int r = 0; r < 4; r++) ysum[r] += tanhf(acc[r] + bb) * wa2;
    }
    // reduce over the 16 lanes of each quad (m dimension)
#pragma unroll
    for (int off = 1; off < 16; off <<= 1) {
#pragma unroll
        for (int r = 0; r < 4; r++) ysum[r] += __shfl_xor(ysum[r], off, 64);
    }
    float wsum = 0.f;
    if (m == 0) {
        float ba2v = ba2[0];
#pragma unroll
        for (int r = 0; r < 4; r++) {
            int orow = row0 + q * 4 + r;
            if (orow < N_NODES) {
                float pe = expf(ysum[r] + ba2v);
                p[orow] = pe;
                wsum += pe;
            }
        }
    }
    // combine quads within wave, then block, then 1 atomic
    wsum += __shfl_xor(wsum, 16, 64);
    wsum += __shfl_xor(wsum, 32, 64);
    if (l == 0) rsum[w] = wsum;
    __syncthreads();
    if (threadIdx.x == 0)
        atomicAdd(&red[1], rsum[0] + rsum[1] + rsum[2] + rsum[3]);
}

// ============ pooling (4 groups of 64 per block) ============
__global__ __launch_bounds__(256) void pool_k(const __half* __restrict__ zh,
                                              const float* __restrict__ p,
                                              const int* __restrict__ batch,
                                              float* gpool, float* zsum, float* cnt,
                                              const int* __restrict__ flags) {
    int l = threadIdx.x & 63, g = threadIdx.x >> 6;
    int i64 = flags[1];
    int nstart = blockIdx.x * 256 + g * 64;
    float ag = 0.f, az = 0.f, c = 0.f;
    int cur = -1;
    for (int i = 0; i < 64; i++) {
        int n = nstart + i;
        if (n >= N_NODES) break;
        int b = clampi(batch[i64 ? 2 * n : n], 0, NB - 1);
        if (b != cur) {
            if (cur >= 0) {
                atomicAdd(&gpool[cur * 64 + l], ag);
                atomicAdd(&zsum[cur * 64 + l], az);
                if (l == 0) atomicAdd(&cnt[cur], c);
            }
            cur = b; ag = 0.f; az = 0.f; c = 0.f;
        }
        float pe = p[n];
        float zv = __half2float(zh[n * 64 + l]);
        ag += pe * zv; az += zv; c += 1.f;
    }
    if (cur >= 0) {
        atomicAdd(&gpool[cur * 64 + l], ag);
        atomicAdd(&zsum[cur * 64 + l], az);
        if (l == 0) atomicAdd(&cnt[cur], c);
    }
}

// ============ per-graph heads ============
__global__ __launch_bounds__(128) void head_k(const float* __restrict__ gpool,
                                              const float* __restrict__ zsum,
                                              const float* __restrict__ cnt,
                                              const float* __restrict__ red,
                                              const float* Wc1, const float* bc1,
                                              const float* Wc2, const float* bc2,
                                              const float* Wc3, const float* bc3,
                                              const float* Wn1, const float* bn1,
                                              const float* Wn2, const float* bn2,
                                              float* __restrict__ outp) {
    __shared__ float gsh[64], zm[64], p1[128], p2[64], n1[64];
    int b = blockIdx.x, t = threadIdx.x;
    float S = red[1];
    if (t < 64) {
        gsh[t] = gpool[b * 64 + t] / S;
        zm[t] = zsum[b * 64 + t] / fmaxf(cnt[b], 1.f);
    }
    __syncthreads();
    {
        float acc = bc1[t];
        for (int k = 0; k < 64; k++) acc += gsh[k] * Wc1[k * 128 + t];
        p1[t] = fmaxf(acc, 0.f);
    }
    __syncthreads();
    if (t < 64) {
        float acc = bc2[t];
        for (int k = 0; k < 128; k++) acc += p1[k] * Wc2[k * 64 + t];
        p2[t] = fmaxf(acc, 0.f);
    } else {
        int tt = t - 64;
        float acc = bn1[tt];
        for (int k = 0; k < 64; k++) acc += zm[k] * Wn1[k * 64 + tt];
        n1[tt] = fmaxf(acc, 0.f);
    }
    __syncthreads();
    if (t < NC) {
        float acc = bc3[t];
        for (int k = 0; k < 64; k++) acc += p2[k] * Wc3[k * 6 + t];
        outp[OPRED_OFF + b * 6 + t] = acc;
    }
    if (t == 64) {
        float acc = bn2[0];
        for (int k = 0; k < 64; k++) acc += n1[k] * Wn2[k];
        outp[ONOI_OFF + b] = 1.f / (1.f + expf(-acc));
    }
}

extern "C" void kernel_launch(void* const* d_in, const int* in_sizes, int n_in,
                              void* d_out, int out_size, void* d_ws, size_t ws_size,
                              hipStream_t stream) {
    const int*   ei    = (const int*)d_in[1];
    const int*   batch = (const int*)d_in[3];
    const float* x     = (const float*)d_in[0];
    const float* ew    = (const float*)d_in[2];
    const float* Win   = (const float*)d_in[4];
    const float* bin   = (const float*)d_in[5];
    const float* W1    = (const float*)d_in[6];
    const float* b1    = (const float*)d_in[7];
    const float* W2    = (const float*)d_in[8];
    const float* b2    = (const float*)d_in[9];
    const float* Wmu   = (const float*)d_in[10];
    const float* bmu   = (const float*)d_in[11];
    const float* Wlv   = (const float*)d_in[12];
    const float* blv   = (const float*)d_in[13];
    const float* g1    = (const float*)d_in[14];
    const float* be1   = (const float*)d_in[15];
    const float* rm1   = (const float*)d_in[16];
    const float* rv1   = (const float*)d_in[17];
    const float* g2    = (const float*)d_in[18];
    const float* be2   = (const float*)d_in[19];
    const float* rm2   = (const float*)d_in[20];
    const float* rv2   = (const float*)d_in[21];
    const float* Wa1   = (const float*)d_in[22];
    const float* ba1   = (const float*)d_in[23];
    const float* Wa2   = (const float*)d_in[24];
    const float* ba2   = (const float*)d_in[25];
    const float* Wc1   = (const float*)d_in[26];
    const float* bc1   = (const float*)d_in[27];
    const float* Wc2   = (const float*)d_in[28];
    const float* bc2   = (const float*)d_in[29];
    const float* Wc3   = (const float*)d_in[30];
    const float* bc3   = (const float*)d_in[31];
    const float* Wn1   = (const float*)d_in[32];
    const float* bn1   = (const float*)d_in[33];
    const float* Wn2   = (const float*)d_in[34];
    const float* bn2   = (const float*)d_in[35];

    float* outp = (float*)d_out;

    // workspace layout
    char* ws = (char*)d_ws;
    size_t o = 0;
    auto alloc = [&](size_t bytes) { size_t r = o; o = (o + bytes + 511) & ~((size_t)511); return r; };
    int*      flags  = (int*)     (ws + alloc(16));
    float*    dinv   = (float*)   (ws + alloc(N_NODES * 4));
    int*      offs   = (int*)     (ws + alloc((N_NODES + 1) * 4));
    int*      bcnt   = (int*)     (ws + alloc(NBUCK * 4));
    int*      gbase  = (int*)     (ws + alloc((NBUCK + 1) * 4));
    uint2*    recP   = (uint2*)   (ws + alloc((size_t)NBUCK * CAPB * 8));   // 14.5 MB
    ushort_t* srcS   = (ushort_t*)(ws + alloc(N_EDGES * 2));
    float*    wS     = (float*)   (ws + alloc(N_EDGES * 4));
    float*    pexp   = (float*)   (ws + alloc(N_NODES * 4));
    _Float16* W1sw   = (_Float16*)(ws + alloc(HF * HF * 2));
    _Float16* W2sw   = (_Float16*)(ws + alloc(HF * HF * 2));
    _Float16* Wcsw   = (_Float16*)(ws + alloc(HF * HF * 2));
    _Float16* Wasw   = (_Float16*)(ws + alloc(LF * HF * 2));
    float*    bcat   = (float*)   (ws + alloc(HF * 4));
    float*    sc1    = (float*)   (ws + alloc(HF * 4));
    float*    sh1    = (float*)   (ws + alloc(HF * 4));
    float*    sc2    = (float*)   (ws + alloc(HF * 4));
    float*    sh2    = (float*)   (ws + alloc(HF * 4));
    float*    red    = (float*)   (ws + alloc(16));
    float*    gpool  = (float*)   (ws + alloc(NB * LF * 4));
    float*    zsum   = (float*)   (ws + alloc(NB * LF * 4));
    float*    cnt    = (float*)   (ws + alloc(NB * 4));
    __half*   bufA   = (__half*)  (ws + alloc((size_t)50048 * 128 * 2));
    __half*   bufB   = (__half*)  (ws + alloc((size_t)50048 * 128 * 2));
    __half*   zh     = (__half*)  (ws + alloc((size_t)50048 * 64 * 2));
    (void)ws_size; (void)n_in; (void)in_sizes; (void)out_size;

    const int GN = (N_NODES + 255) / 256;     // 196
    const int GP = (N_EDGES + EPB - 1) / EPB; // 782

    hipLaunchKernelGGL(detect_k, dim3(1), dim3(256), 0, stream, ei, flags);
    hipLaunchKernelGGL(init_k, dim3(GN), dim3(256), 0, stream,
                       bcnt, gpool, zsum, cnt, red,
                       W1sw, W2sw, Wcsw, Wasw, bcat, sc1, sh1, sc2, sh2,
                       W1, W2, Wmu, bmu, Wlv, blv, Wa1,
                       g1, be1, rm1, rv1, g2, be2, rm2, rv2);
    hipLaunchKernelGGL(pass1_k, dim3(GP), dim3(256), 0, stream, ei, ew, bcnt, recP, flags);
    hipLaunchKernelGGL(bscan_k, dim3(1), dim3(256), 0, stream, bcnt, gbase);
    hipLaunchKernelGGL(pass2a_k, dim3(NBUCK), dim3(256), 0, stream, recP, gbase, offs, dinv);
    hipLaunchKernelGGL(pass2b_k, dim3(NBUCK), dim3(256), 0, stream, recP, gbase, offs, dinv, srcS, wS);

    // encoder
    hipLaunchKernelGGL(gemm_in_k, dim3(N_NODES / 16), dim3(128), 0, stream, x, Win, bin, bufA);
    const int GM = (N_NODES + 63) / 64;       // 782 (64 rows per block)
    const int GA = N_NODES / 4;               // 12500
    hipLaunchKernelGGL(gemm128_k, dim3(GM), dim3(256), 0, stream, bufA, W1sw, b1, bufB);
    hipLaunchKernelGGL((agg_k<0>), dim3(GA), dim3(256), 0, stream,
                       bufB, offs, srcS, wS, dinv, sc1, sh1, bufA, (__half*)nullptr, (float*)nullptr);
    hipLaunchKernelGGL(gemm128_k, dim3(GM), dim3(256), 0, stream, bufA, W2sw, b2, bufB);
    hipLaunchKernelGGL((agg_k<0>), dim3(GA), dim3(256), 0, stream,
                       bufB, offs, srcS, wS, dinv, sc2, sh2, bufA, (__half*)nullptr, (float*)nullptr);
    hipLaunchKernelGGL(gemm128_k, dim3(GM), dim3(256), 0, stream, bufA, Wcsw, bcat, bufB);
    hipLaunchKernelGGL((agg_k<1>), dim3(GA), dim3(256), 0, stream,
                       bufB, offs, srcS, wS, dinv, (const float*)nullptr, (const float*)nullptr,
                       (__half*)nullptr, zh, outp);

    // attention + pooling + heads
    hipLaunchKernelGGL(att_k, dim3(GM), dim3(256), 0, stream, zh, Wasw, ba1, Wa2, ba2, pexp, red);
    hipLaunchKernelGGL(pool_k, dim3(GN), dim3(256), 0, stream, zh, pexp, batch, gpool, zsum, cnt, flags);
    hipLaunchKernelGGL(head_k, dim3(NB), dim3(128), 0, stream,
                       gpool, zsum, cnt, red, Wc1, bc1, Wc2, bc2, Wc3, bc3,
                       Wn1, bn1, Wn2, bn2, outp);
}

// Round 9
// 487.220 us; speedup vs baseline: 3.0701x; 1.0258x over previous
//
#include <hip/hip_runtime.h>
#include <hip/hip_fp16.h>

typedef unsigned short ushort_t;
typedef _Float16 h8v __attribute__((ext_vector_type(8)));
typedef float f4v __attribute__((ext_vector_type(4)));

#define N_NODES 50000
#define N_EDGES 1600000
#define NB      64
#define HF      128
#define LF      64
#define NC      6
#define EPSBN   1e-5f
#define NBUCK   196          // dst buckets of 256 nodes
#define CAPB    9216         // per-bucket padded capacity
#define EPB     2048         // edges per pass1 block

// output element offsets (fp32 out confirmed in round 3)
#define OPRED_OFF 0
#define OMU_OFF   384
#define OLV_OFF   3200384
#define ONOI_OFF  6400384

__device__ __forceinline__ int clampi(int v, int lo, int hi) {
    return v < lo ? lo : (v > hi ? hi : v);
}

// ============ init: detect int width, zero counters/pools, fold BN, swizzle weights ============
// swizzle: Wsw[((k>>5)*128 + c)*32 + (k&31)] = W[k][c]
__global__ void init_k(const int* ei_raw, int* flags,
                       int* bcnt, float* gpool, float* zsum, float* cnt, float* red,
                       _Float16* W1sw, _Float16* W2sw, _Float16* Wcsw, _Float16* Wasw,
                       float* bcat, float* sc1, float* sh1, float* sc2, float* sh2,
                       const float* W1, const float* W2,
                       const float* Wmu, const float* bmu, const float* Wlv, const float* blv,
                       const float* Wa1,
                       const float* g1, const float* be1, const float* rm1, const float* rv1,
                       const float* g2, const float* be2, const float* rm2, const float* rv2) {
    int i = blockIdx.x * 256 + threadIdx.x;
    if (blockIdx.x == 0) {
        __shared__ int c1s;
        if (threadIdx.x == 0) c1s = 0;
        __syncthreads();
        if (ei_raw[2 * threadIdx.x + 1] != 0) atomicAdd(&c1s, 1);
        __syncthreads();
        if (threadIdx.x == 0) flags[1] = (c1s == 0) ? 1 : 0;
    }
    if (i < NBUCK) bcnt[i] = 0;
    if (i < NB * LF) { gpool[i] = 0.f; zsum[i] = 0.f; }
    if (i < NB) cnt[i] = 0.f;
    if (i < 4) red[i] = 0.f;
    if (i < HF * HF) {
        int k = i >> 7, c = i & 127;
        int idx = ((k >> 5) * 128 + c) * 32 + (k & 31);
        W1sw[idx] = (_Float16)W1[i];
        W2sw[idx] = (_Float16)W2[i];
        float wc = (c < 64) ? Wmu[k * 64 + c] : Wlv[k * 64 + (c - 64)];
        Wcsw[idx] = (_Float16)wc;
    }
    if (i < LF * HF) {
        int k = i >> 7, c = i & 127;
        int idx = ((k >> 5) * 128 + c) * 32 + (k & 31);
        Wasw[idx] = (_Float16)Wa1[i];
    }
    if (i < HF) {
        bcat[i] = (i < 64) ? bmu[i] : blv[i - 64];
        float s1 = g1[i] * rsqrtf(rv1[i] + EPSBN);
        sc1[i] = s1; sh1[i] = be1[i] - rm1[i] * s1;
        float s2 = g2[i] * rsqrtf(rv2[i] + EPSBN);
        sc2[i] = s2; sh2[i] = be2[i] - rm2[i] * s2;
    }
}

// ============ fold input layer into GCN-1 linear: Weff = Win@W1, beff = bin@W1 + b1 ============
__global__ __launch_bounds__(256) void weff_k(const float* __restrict__ Win,
                                              const float* __restrict__ bin,
                                              const float* __restrict__ W1,
                                              const float* __restrict__ b1,
                                              float* __restrict__ Weff,
                                              float* __restrict__ beff) {
    int i = blockIdx.x * 256 + threadIdx.x;
    if (i < 16 * 128) {
        int k = i >> 7, c = i & 127;
        float acc = 0.f;
        for (int j = 0; j < 128; j++) acc += Win[k * 128 + j] * W1[j * 128 + c];
        Weff[i] = acc;
    }
    if (i < 128) {
        float acc = b1[i];
        for (int j = 0; j < 128; j++) acc += bin[j] * W1[j * 128 + i];
        beff[i] = acc;
    }
}

// ============ pass 1: block-local LDS counting sort + run-append to padded buckets ============
__global__ __launch_bounds__(256) void pass1_k(const int* __restrict__ ei,
                                               const float* __restrict__ ew,
                                               int* __restrict__ bcnt,
                                               uint2* __restrict__ recP,
                                               const int* __restrict__ flags) {
    __shared__ uint2 stg[EPB];
    __shared__ int lh[NBUCK];
    __shared__ int lcur[NBUCK];
    __shared__ int gb[NBUCK];
    __shared__ int loff[256];
    int tid = threadIdx.x;
    for (int i = tid; i < NBUCK; i += 256) lh[i] = 0;
    __syncthreads();
    int e0 = blockIdx.x * EPB;
    int i64 = flags[1];
    uint2 myrec[8]; int myb[8];
#pragma unroll
    for (int j = 0; j < 8; j++) {
        int e = e0 + j * 256 + tid;
        if (e < N_EDGES) {
            int di = N_EDGES + e;
            int s = clampi(ei[i64 ? 2 * e : e], 0, N_NODES - 1);
            int d = clampi(ei[i64 ? 2 * di : di], 0, N_NODES - 1);
            myrec[j] = make_uint2((unsigned)s | ((unsigned)d << 16), __float_as_uint(ew[e]));
            myb[j] = d >> 8;
            atomicAdd(&lh[myb[j]], 1);
        } else myb[j] = -1;
    }
    __syncthreads();
    loff[tid] = (tid < NBUCK) ? lh[tid] : 0;
    __syncthreads();
    for (int dth = 1; dth < 256; dth <<= 1) {
        int x = (tid >= dth) ? loff[tid - dth] : 0;
        __syncthreads();
        loff[tid] += x;
        __syncthreads();
    }
    if (tid < NBUCK) lcur[tid] = loff[tid] - lh[tid];
    __syncthreads();
#pragma unroll
    for (int j = 0; j < 8; j++) {
        if (myb[j] >= 0) {
            int p = atomicAdd(&lcur[myb[j]], 1);
            stg[p] = myrec[j];
        }
    }
    if (tid < NBUCK) {
        int c = lh[tid];
        gb[tid] = (c > 0) ? atomicAdd(&bcnt[tid], c) : 0;
    }
    __syncthreads();
    int total = N_EDGES - e0; if (total > EPB) total = EPB;
    for (int idx = tid; idx < total; idx += 256) {
        uint2 r = stg[idx];
        int b = (int)(r.x >> 24);
        int within = idx - (loff[b] - lh[b]);
        int pos = gb[b] + within;
        if (pos < CAPB) recP[b * CAPB + pos] = r;
    }
}

// ============ pass 2a: inline bucket scan + per-bucket hist + degree -> offs, dinv ============
__global__ __launch_bounds__(256) void pass2a_k(const uint2* __restrict__ recP,
                                                const int* __restrict__ bcnt,
                                                int* __restrict__ offs,
                                                float* __restrict__ dinv) {
    __shared__ int sb[256];
    __shared__ int cnt[256];
    __shared__ float degs[256];
    __shared__ int off[256];
    int b = blockIdx.x, t = threadIdx.x;
    int ct = (t < NBUCK) ? bcnt[t] : 0;
    if (ct > CAPB) ct = CAPB;
    sb[t] = ct;
    cnt[t] = 0; degs[t] = 0.f;
    __syncthreads();
    for (int dth = 1; dth < 256; dth <<= 1) {
        int x = (t >= dth) ? sb[t - dth] : 0;
        __syncthreads();
        sb[t] += x;
        __syncthreads();
    }
    int cb = bcnt[b]; if (cb > CAPB) cb = CAPB;
    int gb0 = sb[b] - cb;
    int n0 = b * CAPB;
    for (int i = t; i < cb; i += 256) {
        uint2 r = recP[n0 + i];
        int dl = (r.x >> 16) & 255;
        atomicAdd(&cnt[dl], 1);
        atomicAdd(&degs[dl], __uint_as_float(r.y));
    }
    __syncthreads();
    int v = cnt[t];
    off[t] = v;
    __syncthreads();
    for (int dth = 1; dth < 256; dth <<= 1) {
        int x = (t >= dth) ? off[t - dth] : 0;
        __syncthreads();
        off[t] += x;
        __syncthreads();
    }
    int excl = off[t] - v;
    int n = (b << 8) + t;
    if (n < N_NODES) {
        offs[n] = gb0 + excl;
        dinv[n] = rsqrtf(1.f + degs[t]);
    }
    if (b == NBUCK - 1 && t == 0) offs[N_NODES] = sb[NBUCK - 1];
}

// ============ pass 2b: scatter to compact dst-sorted srcS + normalized wS ============
__global__ __launch_bounds__(256) void pass2b_k(const uint2* __restrict__ recP,
                                                const int* __restrict__ bcnt,
                                                const int* __restrict__ offs,
                                                const float* __restrict__ dinv,
                                                ushort_t* __restrict__ srcS,
                                                float* __restrict__ wS) {
    __shared__ int cur[256];
    __shared__ float dloc[256];
    int b = blockIdx.x, t = threadIdx.x;
    int n = (b << 8) + t;
    cur[t] = (n < N_NODES) ? offs[n] : 0;
    dloc[t] = (n < N_NODES) ? dinv[n] : 0.f;
    __syncthreads();
    int cb = bcnt[b]; if (cb > CAPB) cb = CAPB;
    int n0 = b * CAPB;
    for (int i = t; i < cb; i += 256) {
        uint2 r = recP[n0 + i];
        int s = (int)(r.x & 0xFFFFu);
        int dl = (r.x >> 16) & 255;
        int p = atomicAdd(&cur[dl], 1);
        srcS[p] = (ushort_t)s;
        wS[p] = __uint_as_float(r.y) * dinv[s] * dloc[dl];
    }
}

// ============ fused input GEMM: x[N,16] @ Weff[16,128] + beff -> lin1 (fp16) ============
__global__ __launch_bounds__(128) void gemm_in_k(const float* __restrict__ x,
                                                 const float* __restrict__ Weff,
                                                 const float* __restrict__ beff,
                                                 __half* __restrict__ out) {
    __shared__ float xl[16 * 16];
    int tid = threadIdx.x;
    int row0 = blockIdx.x * 16;
    if (tid < 64) {
        int r = tid >> 2, k4 = tid & 3;
        int row = row0 + r;
        float4 v = make_float4(0.f, 0.f, 0.f, 0.f);
        if (row < N_NODES) v = *(const float4*)(x + row * 16 + k4 * 4);
        *(float4*)(xl + r * 16 + k4 * 4) = v;
    }
    float wv[16];
#pragma unroll
    for (int k = 0; k < 16; k++) wv[k] = Weff[k * 128 + tid];
    float bias = beff[tid];
    __syncthreads();
    for (int r = 0; r < 16; r++) {
        float acc = bias;
#pragma unroll
        for (int k = 0; k < 16; k++) acc += xl[r * 16 + k] * wv[k];
        int row = row0 + r;
        if (row < N_NODES) out[row * 128 + tid] = __float2half(acc);
    }
}

// ============ MFMA GEMM: in(fp16)[N,128] @ Wsw(fp16,swizzled)[128,128] + b -> out(fp16) ============
__global__ __launch_bounds__(256) void gemm128_k(const __half* __restrict__ in,
                                                 const _Float16* __restrict__ Wsw,
                                                 const float* __restrict__ b,
                                                 __half* __restrict__ out) {
    int l = threadIdx.x & 63, w = threadIdx.x >> 6;
    int row0 = blockIdx.x * 64 + w * 16;
    int m = l & 15, q = l >> 4;
    int row = row0 + m;
    bool rok = row < N_NODES;
    const h8v* inp = (const h8v*)in;
    const h8v* wp = (const h8v*)Wsw;
    h8v az = {0, 0, 0, 0, 0, 0, 0, 0};
    h8v a[4];
#pragma unroll
    for (int kb = 0; kb < 4; kb++)
        a[kb] = rok ? inp[(row * 128 + kb * 32 + q * 8) >> 3] : az;
#pragma unroll
    for (int ct = 0; ct < 8; ct++) {
        f4v acc = {0.f, 0.f, 0.f, 0.f};
#pragma unroll
        for (int kb = 0; kb < 4; kb++) {
            h8v bf = wp[((kb * 128 + ct * 16 + m) * 32 + q * 8) >> 3];
            acc = __builtin_amdgcn_mfma_f32_16x16x32_f16(a[kb], bf, acc, 0, 0, 0);
        }
        int col = ct * 16 + m;
        float bias = b[col];
#pragma unroll
        for (int r = 0; r < 4; r++) {
            int orow = row0 + q * 4 + r;
            if (orow < N_NODES) out[orow * 128 + col] = __float2half(acc[r] + bias);
        }
    }
}

// ============ aggregation: 1 wave per node, half2 lanes, 16x-unrolled gather ============
template <int MODE>
__global__ __launch_bounds__(256) void agg_k(const __half* __restrict__ lin,
                                             const int* __restrict__ offs,
                                             const ushort_t* __restrict__ srcS,
                                             const float* __restrict__ wS,
                                             const float* __restrict__ dinv,
                                             const float* __restrict__ sc,
                                             const float* __restrict__ sh,
                                             __half* __restrict__ outH,
                                             __half* __restrict__ zh,
                                             float* __restrict__ outp) {
    int tid = threadIdx.x;
    int n = blockIdx.x * 4 + (tid >> 6);
    int t = tid & 63;
    const __half2* linv = (const __half2*)lin;
    float dv = dinv[n];
    float2 self = __half22float2(linv[n * 64 + t]);
    float ax = self.x * dv * dv, ay = self.y * dv * dv;
    int e0 = offs[n], e1 = offs[n + 1];
    int e = e0;
    for (; e + 16 <= e1; e += 16) {
        int s[16]; float w[16]; __half2 h[16];
#pragma unroll
        for (int j = 0; j < 16; j++) { s[j] = srcS[e + j]; w[j] = wS[e + j]; }
#pragma unroll
        for (int j = 0; j < 16; j++) h[j] = linv[s[j] * 64 + t];
#pragma unroll
        for (int j = 0; j < 16; j++) {
            float2 f = __half22float2(h[j]);
            ax += w[j] * f.x; ay += w[j] * f.y;
        }
    }
    for (; e + 8 <= e1; e += 8) {
        int s[8]; float w[8]; __half2 h[8];
#pragma unroll
        for (int j = 0; j < 8; j++) { s[j] = srcS[e + j]; w[j] = wS[e + j]; }
#pragma unroll
        for (int j = 0; j < 8; j++) h[j] = linv[s[j] * 64 + t];
#pragma unroll
        for (int j = 0; j < 8; j++) {
            float2 f = __half22float2(h[j]);
            ax += w[j] * f.x; ay += w[j] * f.y;
        }
    }
    for (; e < e1; e++) {
        float2 f = __half22float2(linv[(int)srcS[e] * 64 + t]);
        float w = wS[e];
        ax += w * f.x; ay += w * f.y;
    }
    if (MODE == 0) {
        float2 s2 = *(const float2*)(sc + 2 * t);
        float2 h2 = *(const float2*)(sh + 2 * t);
        float o0 = fmaxf(ax * s2.x + h2.x, 0.f);
        float o1 = fmaxf(ay * s2.y + h2.y, 0.f);
        *(__half2*)(outH + n * 128 + 2 * t) = __floats2half2_rn(o0, o1);
    } else {
        if (t < 32) {
            *(float2*)(outp + OMU_OFF + n * 64 + 2 * t) = make_float2(ax, ay);
            ((__half2*)zh)[n * 32 + t] = __floats2half2_rn(ax, ay);
        } else {
            *(float2*)(outp + OLV_OFF + n * 64 + (2 * t - 64)) = make_float2(ax, ay);
        }
    }
}

// ============ attention via MFMA: p = exp(tanh(zh @ Wa1 + ba1) @ Wa2 + ba2) ============
__global__ __launch_bounds__(256) void att_k(const __half* __restrict__ zh,
                                             const _Float16* __restrict__ Wasw,
                                             const float* __restrict__ ba1,
                                             const float* __restrict__ Wa2,
                                             const float* __restrict__ ba2,
                                             float* __restrict__ p, float* __restrict__ red) {
    __shared__ float rsum[4];
    int l = threadIdx.x & 63, w = threadIdx.x >> 6;
    int row0 = blockIdx.x * 64 + w * 16;
    int m = l & 15, q = l >> 4;
    int row = row0 + m;
    bool rok = row < N_NODES;
    const h8v* zp = (const h8v*)zh;
    const h8v* wp = (const h8v*)Wasw;
    h8v az = {0, 0, 0, 0, 0, 0, 0, 0};
    h8v a[2];
#pragma unroll
    for (int kb = 0; kb < 2; kb++)
        a[kb] = rok ? zp[(row * 64 + kb * 32 + q * 8) >> 3] : az;
    float ysum[4] = {0.f, 0.f, 0.f, 0.f};
#pragma unroll
    for (int ct = 0; ct < 8; ct++) {
        f4v acc = {0.f, 0.f, 0.f, 0.f};
#pragma unroll
        for (int kb = 0; kb < 2; kb++) {
            h8v bf = wp[((kb * 128 + ct * 16 + m) * 32 + q * 8) >> 3];
            acc = __builtin_amdgcn_mfma_f32_16x16x32_f16(a[kb], bf, acc, 0, 0, 0);
        }
        int col = ct * 16 + m;
        float bb = ba1[col], wa2 = Wa2[col];
#pragma unroll
        for (int r = 0; r < 4; r++) ysum[r] += tanhf(acc[r] + bb) * wa2;
    }
#pragma unroll
    for (int off = 1; off < 16; off <<= 1) {
#pragma unroll
        for (int r = 0; r < 4; r++) ysum[r] += __shfl_xor(ysum[r], off, 64);
    }
    float wsum = 0.f;
    if (m == 0) {
        float ba2v = ba2[0];
#pragma unroll
        for (int r = 0; r < 4; r++) {
            int orow = row0 + q * 4 + r;
            if (orow < N_NODES) {
                float pe = expf(ysum[r] + ba2v);
                p[orow] = pe;
                wsum += pe;
            }
        }
    }
    wsum += __shfl_xor(wsum, 16, 64);
    wsum += __shfl_xor(wsum, 32, 64);
    if (l == 0) rsum[w] = wsum;
    __syncthreads();
    if (threadIdx.x == 0)
        atomicAdd(&red[1], rsum[0] + rsum[1] + rsum[2] + rsum[3]);
}

// ============ pooling (4 groups of 64 per block) ============
__global__ __launch_bounds__(256) void pool_k(const __half* __restrict__ zh,
                                              const float* __restrict__ p,
                                              const int* __restrict__ batch,
                                              float* gpool, float* zsum, float* cnt,
                                              const int* __restrict__ flags) {
    int l = threadIdx.x & 63, g = threadIdx.x >> 6;
    int i64 = flags[1];
    int nstart = blockIdx.x * 256 + g * 64;
    float ag = 0.f, az = 0.f, c = 0.f;
    int cur = -1;
    for (int i = 0; i < 64; i++) {
        int n = nstart + i;
        if (n >= N_NODES) break;
        int b = clampi(batch[i64 ? 2 * n : n], 0, NB - 1);
        if (b != cur) {
            if (cur >= 0) {
                atomicAdd(&gpool[cur * 64 + l], ag);
                atomicAdd(&zsum[cur * 64 + l], az);
                if (l == 0) atomicAdd(&cnt[cur], c);
            }
            cur = b; ag = 0.f; az = 0.f; c = 0.f;
        }
        float pe = p[n];
        float zv = __half2float(zh[n * 64 + l]);
        ag += pe * zv; az += zv; c += 1.f;
    }
    if (cur >= 0) {
        atomicAdd(&gpool[cur * 64 + l], ag);
        atomicAdd(&zsum[cur * 64 + l], az);
        if (l == 0) atomicAdd(&cnt[cur], c);
    }
}

// ============ per-graph heads ============
__global__ __launch_bounds__(128) void head_k(const float* __restrict__ gpool,
                                              const float* __restrict__ zsum,
                                              const float* __restrict__ cnt,
                                              const float* __restrict__ red,
                                              const float* Wc1, const float* bc1,
                                              const float* Wc2, const float* bc2,
                                              const float* Wc3, const float* bc3,
                                              const float* Wn1, const float* bn1,
                                              const float* Wn2, const float* bn2,
                                              float* __restrict__ outp) {
    __shared__ float gsh[64], zm[64], p1[128], p2[64], n1[64];
    int b = blockIdx.x, t = threadIdx.x;
    float S = red[1];
    if (t < 64) {
        gsh[t] = gpool[b * 64 + t] / S;
        zm[t] = zsum[b * 64 + t] / fmaxf(cnt[b], 1.f);
    }
    __syncthreads();
    {
        float acc = bc1[t];
        for (int k = 0; k < 64; k++) acc += gsh[k] * Wc1[k * 128 + t];
        p1[t] = fmaxf(acc, 0.f);
    }
    __syncthreads();
    if (t < 64) {
        float acc = bc2[t];
        for (int k = 0; k < 128; k++) acc += p1[k] * Wc2[k * 64 + t];
        p2[t] = fmaxf(acc, 0.f);
    } else {
        int tt = t - 64;
        float acc = bn1[tt];
        for (int k = 0; k < 64; k++) acc += zm[k] * Wn1[k * 64 + tt];
        n1[tt] = fmaxf(acc, 0.f);
    }
    __syncthreads();
    if (t < NC) {
        float acc = bc3[t];
        for (int k = 0; k < 64; k++) acc += p2[k] * Wc3[k * 6 + t];
        outp[OPRED_OFF + b * 6 + t] = acc;
    }
    if (t == 64) {
        float acc = bn2[0];
        for (int k = 0; k < 64; k++) acc += n1[k] * Wn2[k];
        outp[ONOI_OFF + b] = 1.f / (1.f + expf(-acc));
    }
}

extern "C" void kernel_launch(void* const* d_in, const int* in_sizes, int n_in,
                              void* d_out, int out_size, void* d_ws, size_t ws_size,
                              hipStream_t stream) {
    const int*   ei    = (const int*)d_in[1];
    const int*   batch = (const int*)d_in[3];
    const float* x     = (const float*)d_in[0];
    const float* ew    = (const float*)d_in[2];
    const float* Win   = (const float*)d_in[4];
    const float* bin   = (const float*)d_in[5];
    const float* W1    = (const float*)d_in[6];
    const float* b1    = (const float*)d_in[7];
    const float* W2    = (const float*)d_in[8];
    const float* b2    = (const float*)d_in[9];
    const float* Wmu   = (const float*)d_in[10];
    const float* bmu   = (const float*)d_in[11];
    const float* Wlv   = (const float*)d_in[12];
    const float* blv   = (const float*)d_in[13];
    const float* g1    = (const float*)d_in[14];
    const float* be1   = (const float*)d_in[15];
    const float* rm1   = (const float*)d_in[16];
    const float* rv1   = (const float*)d_in[17];
    const float* g2    = (const float*)d_in[18];
    const float* be2   = (const float*)d_in[19];
    const float* rm2   = (const float*)d_in[20];
    const float* rv2   = (const float*)d_in[21];
    const float* Wa1   = (const float*)d_in[22];
    const float* ba1   = (const float*)d_in[23];
    const float* Wa2   = (const float*)d_in[24];
    const float* ba2   = (const float*)d_in[25];
    const float* Wc1   = (const float*)d_in[26];
    const float* bc1   = (const float*)d_in[27];
    const float* Wc2   = (const float*)d_in[28];
    const float* bc2   = (const float*)d_in[29];
    const float* Wc3   = (const float*)d_in[30];
    const float* bc3   = (const float*)d_in[31];
    const float* Wn1   = (const float*)d_in[32];
    const float* bn1   = (const float*)d_in[33];
    const float* Wn2   = (const float*)d_in[34];
    const float* bn2   = (const float*)d_in[35];

    float* outp = (float*)d_out;

    // workspace layout
    char* ws = (char*)d_ws;
    size_t o = 0;
    auto alloc = [&](size_t bytes) { size_t r = o; o = (o + bytes + 511) & ~((size_t)511); return r; };
    int*      flags  = (int*)     (ws + alloc(16));
    float*    dinv   = (float*)   (ws + alloc(N_NODES * 4));
    int*      offs   = (int*)     (ws + alloc((N_NODES + 1) * 4));
    int*      bcnt   = (int*)     (ws + alloc(NBUCK * 4));
    uint2*    recP   = (uint2*)   (ws + alloc((size_t)NBUCK * CAPB * 8));   // 14.5 MB
    ushort_t* srcS   = (ushort_t*)(ws + alloc(N_EDGES * 2));
    float*    wS     = (float*)   (ws + alloc(N_EDGES * 4));
    float*    pexp   = (float*)   (ws + alloc(N_NODES * 4));
    _Float16* W1sw   = (_Float16*)(ws + alloc(HF * HF * 2));
    _Float16* W2sw   = (_Float16*)(ws + alloc(HF * HF * 2));
    _Float16* Wcsw   = (_Float16*)(ws + alloc(HF * HF * 2));
    _Float16* Wasw   = (_Float16*)(ws + alloc(LF * HF * 2));
    float*    Weff   = (float*)   (ws + alloc(16 * HF * 4));
    float*    beff   = (float*)   (ws + alloc(HF * 4));
    float*    bcat   = (float*)   (ws + alloc(HF * 4));
    float*    sc1    = (float*)   (ws + alloc(HF * 4));
    float*    sh1    = (float*)   (ws + alloc(HF * 4));
    float*    sc2    = (float*)   (ws + alloc(HF * 4));
    float*    sh2    = (float*)   (ws + alloc(HF * 4));
    float*    red    = (float*)   (ws + alloc(16));
    float*    gpool  = (float*)   (ws + alloc(NB * LF * 4));
    float*    zsum   = (float*)   (ws + alloc(NB * LF * 4));
    float*    cnt    = (float*)   (ws + alloc(NB * 4));
    __half*   bufA   = (__half*)  (ws + alloc((size_t)50048 * 128 * 2));
    __half*   bufB   = (__half*)  (ws + alloc((size_t)50048 * 128 * 2));
    __half*   zh     = (__half*)  (ws + alloc((size_t)50048 * 64 * 2));
    (void)ws_size; (void)n_in; (void)in_sizes; (void)out_size;

    const int GN = (N_NODES + 255) / 256;     // 196
    const int GP = (N_EDGES + EPB - 1) / EPB; // 782

    hipLaunchKernelGGL(init_k, dim3(GN), dim3(256), 0, stream,
                       ei, flags, bcnt, gpool, zsum, cnt, red,
                       W1sw, W2sw, Wcsw, Wasw, bcat, sc1, sh1, sc2, sh2,
                       W1, W2, Wmu, bmu, Wlv, blv, Wa1,
                       g1, be1, rm1, rv1, g2, be2, rm2, rv2);
    hipLaunchKernelGGL(weff_k, dim3(8), dim3(256), 0, stream, Win, bin, W1, b1, Weff, beff);
    hipLaunchKernelGGL(pass1_k, dim3(GP), dim3(256), 0, stream, ei, ew, bcnt, recP, flags);
    hipLaunchKernelGGL(pass2a_k, dim3(NBUCK), dim3(256), 0, stream, recP, bcnt, offs, dinv);
    hipLaunchKernelGGL(pass2b_k, dim3(NBUCK), dim3(256), 0, stream, recP, bcnt, offs, dinv, srcS, wS);

    // encoder (input layer folded into GCN-1 linear)
    hipLaunchKernelGGL(gemm_in_k, dim3(N_NODES / 16), dim3(128), 0, stream, x, Weff, beff, bufB);
    const int GM = (N_NODES + 63) / 64;       // 782
    const int GA = N_NODES / 4;               // 12500
    hipLaunchKernelGGL((agg_k<0>), dim3(GA), dim3(256), 0, stream,
                       bufB, offs, srcS, wS, dinv, sc1, sh1, bufA, (__half*)nullptr, (float*)nullptr);
    hipLaunchKernelGGL(gemm128_k, dim3(GM), dim3(256), 0, stream, bufA, W2sw, b2, bufB);
    hipLaunchKernelGGL((agg_k<0>), dim3(GA), dim3(256), 0, stream,
                       bufB, offs, srcS, wS, dinv, sc2, sh2, bufA, (__half*)nullptr, (float*)nullptr);
    hipLaunchKernelGGL(gemm128_k, dim3(GM), dim3(256), 0, stream, bufA, Wcsw, bcat, bufB);
    hipLaunchKernelGGL((agg_k<1>), dim3(GA), dim3(256), 0, stream,
                       bufB, offs, srcS, wS, dinv, (const float*)nullptr, (const float*)nullptr,
                       (__half*)nullptr, zh, outp);

    // attention + pooling + heads
    hipLaunchKernelGGL(att_k, dim3(GM), dim3(256), 0, stream, zh, Wasw, ba1, Wa2, ba2, pexp, red);
    hipLaunchKernelGGL(pool_k, dim3(GN), dim3(256), 0, stream, zh, pexp, batch, gpool, zsum, cnt, flags);
    hipLaunchKernelGGL(head_k, dim3(NB), dim3(128), 0, stream,
                       gpool, zsum, cnt, red, Wc1, bc1, Wc2, bc2, Wc3, bc3,
                       Wn1, bn1, Wn2, bn2, outp);
}

// Round 11
// 435.595 us; speedup vs baseline: 3.4340x; 1.1185x over previous
//
#include <hip/hip_runtime.h>
#include <hip/hip_fp16.h>

typedef unsigned short ushort_t;
typedef _Float16 h8v __attribute__((ext_vector_type(8)));
typedef float f4v __attribute__((ext_vector_type(4)));

#define N_NODES 50000
#define N_EDGES 1600000
#define NB      64
#define HF      128
#define LF      64
#define NC      6
#define EPSBN   1e-5f
#define NBUCK   196          // dst buckets of 256 nodes
#define CAPB    9216         // per-bucket padded capacity
#define EPB     2048         // edges per pass1 block

// output element offsets (fp32 out confirmed in round 3)
#define OPRED_OFF 0
#define OMU_OFF   384
#define OLV_OFF   3200384
#define ONOI_OFF  6400384

__device__ __forceinline__ int clampi(int v, int lo, int hi) {
    return v < lo ? lo : (v > hi ? hi : v);
}

// ============ init: detect int width, zero counters/pools, fold BN, swizzle weights ============
__global__ void init_k(const int* ei_raw, int* flags,
                       int* bcnt, float* gpool, float* zsum, float* cnt, float* red,
                       _Float16* W2sw, _Float16* Wcsw, _Float16* Wasw,
                       float* bcat, float* sc1, float* sh1, float* sc2, float* sh2,
                       const float* W2,
                       const float* Wmu, const float* bmu, const float* Wlv, const float* blv,
                       const float* Wa1,
                       const float* g1, const float* be1, const float* rm1, const float* rv1,
                       const float* g2, const float* be2, const float* rm2, const float* rv2) {
    int i = blockIdx.x * 256 + threadIdx.x;
    if (blockIdx.x == 0) {
        __shared__ int c1s;
        if (threadIdx.x == 0) c1s = 0;
        __syncthreads();
        if (ei_raw[2 * threadIdx.x + 1] != 0) atomicAdd(&c1s, 1);
        __syncthreads();
        if (threadIdx.x == 0) flags[1] = (c1s == 0) ? 1 : 0;
    }
    if (i < NBUCK) bcnt[i] = 0;
    if (i < NB * LF) { gpool[i] = 0.f; zsum[i] = 0.f; }
    if (i < NB) cnt[i] = 0.f;
    if (i < 4) red[i] = 0.f;
    if (i < HF * HF) {
        int k = i >> 7, c = i & 127;
        int idx = ((k >> 5) * 128 + c) * 32 + (k & 31);
        W2sw[idx] = (_Float16)W2[i];
        float wc = (c < 64) ? Wmu[k * 64 + c] : Wlv[k * 64 + (c - 64)];
        Wcsw[idx] = (_Float16)wc;
    }
    if (i < LF * HF) {
        int k = i >> 7, c = i & 127;
        int idx = ((k >> 5) * 128 + c) * 32 + (k & 31);
        Wasw[idx] = (_Float16)Wa1[i];
    }
    if (i < HF) {
        bcat[i] = (i < 64) ? bmu[i] : blv[i - 64];
        float s1 = g1[i] * rsqrtf(rv1[i] + EPSBN);
        sc1[i] = s1; sh1[i] = be1[i] - rm1[i] * s1;
        float s2 = g2[i] * rsqrtf(rv2[i] + EPSBN);
        sc2[i] = s2; sh2[i] = be2[i] - rm2[i] * s2;
    }
}

// ============ fold input layer into GCN-1 linear: Weff = Win@W1, beff = bin@W1 + b1 ============
__global__ __launch_bounds__(256) void weff_k(const float* __restrict__ Win,
                                              const float* __restrict__ bin,
                                              const float* __restrict__ W1,
                                              const float* __restrict__ b1,
                                              float* __restrict__ Weff,
                                              float* __restrict__ beff) {
    int i = blockIdx.x * 256 + threadIdx.x;
    if (i < 16 * 128) {
        int k = i >> 7, c = i & 127;
        float acc = 0.f;
        for (int j = 0; j < 128; j++) acc += Win[k * 128 + j] * W1[j * 128 + c];
        Weff[i] = acc;
    }
    if (i < 128) {
        float acc = b1[i];
        for (int j = 0; j < 128; j++) acc += bin[j] * W1[j * 128 + i];
        beff[i] = acc;
    }
}

// ============ pass 1: block-local LDS counting sort + run-append to padded buckets ============
__global__ __launch_bounds__(256) void pass1_k(const int* __restrict__ ei,
                                               const float* __restrict__ ew,
                                               int* __restrict__ bcnt,
                                               uint2* __restrict__ recP,
                                               const int* __restrict__ flags) {
    __shared__ uint2 stg[EPB];
    __shared__ int lh[NBUCK];
    __shared__ int lcur[NBUCK];
    __shared__ int gb[NBUCK];
    __shared__ int loff[256];
    int tid = threadIdx.x;
    for (int i = tid; i < NBUCK; i += 256) lh[i] = 0;
    __syncthreads();
    int e0 = blockIdx.x * EPB;
    int i64 = flags[1];
    uint2 myrec[8]; int myb[8];
#pragma unroll
    for (int j = 0; j < 8; j++) {
        int e = e0 + j * 256 + tid;
        if (e < N_EDGES) {
            int di = N_EDGES + e;
            int s = clampi(ei[i64 ? 2 * e : e], 0, N_NODES - 1);
            int d = clampi(ei[i64 ? 2 * di : di], 0, N_NODES - 1);
            myrec[j] = make_uint2((unsigned)s | ((unsigned)d << 16), __float_as_uint(ew[e]));
            myb[j] = d >> 8;
            atomicAdd(&lh[myb[j]], 1);
        } else myb[j] = -1;
    }
    __syncthreads();
    loff[tid] = (tid < NBUCK) ? lh[tid] : 0;
    __syncthreads();
    for (int dth = 1; dth < 256; dth <<= 1) {
        int x = (tid >= dth) ? loff[tid - dth] : 0;
        __syncthreads();
        loff[tid] += x;
        __syncthreads();
    }
    if (tid < NBUCK) lcur[tid] = loff[tid] - lh[tid];
    __syncthreads();
#pragma unroll
    for (int j = 0; j < 8; j++) {
        if (myb[j] >= 0) {
            int p = atomicAdd(&lcur[myb[j]], 1);
            stg[p] = myrec[j];
        }
    }
    if (tid < NBUCK) {
        int c = lh[tid];
        gb[tid] = (c > 0) ? atomicAdd(&bcnt[tid], c) : 0;
    }
    __syncthreads();
    int total = N_EDGES - e0; if (total > EPB) total = EPB;
    for (int idx = tid; idx < total; idx += 256) {
        uint2 r = stg[idx];
        int b = (int)(r.x >> 24);
        int within = idx - (loff[b] - lh[b]);
        int pos = gb[b] + within;
        if (pos < CAPB) recP[b * CAPB + pos] = r;
    }
}

// ============ pass 2a: per-bucket hist + degree -> nodeInfo (start|cnt packed), dinv ============
// nodeInfo[n] = (b*CAPB + excl) | (cnt << 21);  start is padded recP/epack coords (21 bits).
__global__ __launch_bounds__(256) void pass2a_k(const uint2* __restrict__ recP,
                                                const int* __restrict__ bcnt,
                                                unsigned* __restrict__ nodeInfo,
                                                float* __restrict__ dinv) {
    __shared__ int cnt[256];
    __shared__ float degs[256];
    __shared__ int off[256];
    int b = blockIdx.x, t = threadIdx.x;
    cnt[t] = 0; degs[t] = 0.f;
    __syncthreads();
    int cb = bcnt[b]; if (cb > CAPB) cb = CAPB;
    int n0 = b * CAPB;
    for (int i = t; i < cb; i += 256) {
        uint2 r = recP[n0 + i];
        int dl = (r.x >> 16) & 255;
        atomicAdd(&cnt[dl], 1);
        atomicAdd(&degs[dl], __uint_as_float(r.y));
    }
    __syncthreads();
    int v = cnt[t];
    off[t] = v;
    __syncthreads();
    for (int dth = 1; dth < 256; dth <<= 1) {
        int x = (t >= dth) ? off[t - dth] : 0;
        __syncthreads();
        off[t] += x;
        __syncthreads();
    }
    int excl = off[t] - v;
    int n = (b << 8) + t;
    if (n < N_NODES) {
        int cv = v > 2047 ? 2047 : v;
        nodeInfo[n] = (unsigned)(n0 + excl) | ((unsigned)cv << 21);
        dinv[n] = rsqrtf(1.f + degs[t]);
    }
}

// ============ pass 2b: in-bucket sort into packed 4B records: src | fp16(ew)<<16 ============
__global__ __launch_bounds__(256) void pass2b_k(const uint2* __restrict__ recP,
                                                const int* __restrict__ bcnt,
                                                const unsigned* __restrict__ nodeInfo,
                                                unsigned* __restrict__ epack) {
    __shared__ int cur[256];
    int b = blockIdx.x, t = threadIdx.x;
    int n = (b << 8) + t;
    cur[t] = (n < N_NODES) ? (int)(nodeInfo[n] & 0x1FFFFFu) : 0;
    __syncthreads();
    int cb = bcnt[b]; if (cb > CAPB) cb = CAPB;
    int n0 = b * CAPB;
    for (int i = t; i < cb; i += 256) {
        uint2 r = recP[n0 + i];
        int s = (int)(r.x & 0xFFFFu);
        int dl = (r.x >> 16) & 255;
        int p = atomicAdd(&cur[dl], 1);
        __half hw = __float2half(__uint_as_float(r.y));
        epack[p] = (unsigned)s | ((unsigned)__half_as_ushort(hw) << 16);
    }
}

// ============ agg16: 16-dim aggregation of raw x (pre-linear), 8 lanes per node ============
// aggx[d] = dinv_d * (sum_e ew*dinv_s*x[s] + dinv_d*x[d]);  Sd = dinv_d*(sum ew*dinv_s + dinv_d)
__global__ __launch_bounds__(256) void agg16_k(const float* __restrict__ x,
                                               const unsigned* __restrict__ epack,
                                               const unsigned* __restrict__ nodeInfo,
                                               const float* __restrict__ dinv,
                                               __half* __restrict__ aggx,
                                               float* __restrict__ Sd) {
    int tid = threadIdx.x;
    int n = blockIdx.x * 32 + (tid >> 3);
    if (n >= N_NODES) return;
    int f = tid & 7;
    unsigned info = nodeInfo[n];
    int e0 = (int)(info & 0x1FFFFFu);
    int e1 = e0 + (int)(info >> 21);
    float dv = dinv[n];
    float2 xs = *(const float2*)(x + n * 16 + f * 2);
    float ax = dv * xs.x, ay = dv * xs.y;
    float ss = dv;
    int e = e0;
    for (; e + 8 <= e1; e += 8) {
        unsigned r[8];
#pragma unroll
        for (int j = 0; j < 8; j++) r[j] = epack[e + j];
        float2 v[8]; float w[8];
#pragma unroll
        for (int j = 0; j < 8; j++) {
            int s = (int)(r[j] & 0xFFFFu);
            w[j] = __half2float(__ushort_as_half((ushort_t)(r[j] >> 16))) * dinv[s];
            v[j] = *(const float2*)(x + s * 16 + f * 2);
        }
#pragma unroll
        for (int j = 0; j < 8; j++) {
            ax += w[j] * v[j].x; ay += w[j] * v[j].y; ss += w[j];
        }
    }
    for (; e < e1; e++) {
        unsigned r = epack[e];
        int s = (int)(r & 0xFFFFu);
        float w = __half2float(__ushort_as_half((ushort_t)(r >> 16))) * dinv[s];
        float2 v = *(const float2*)(x + s * 16 + f * 2);
        ax += w * v.x; ay += w * v.y; ss += w;
    }
    *(__half2*)(aggx + n * 16 + 2 * f) = __floats2half2_rn(ax * dv, ay * dv);
    if (f == 0) Sd[n] = dv * ss;
}

// ============ layer-1 linear + BN + ReLU: h1 = relu(sc1*(aggx@Weff + Sd*beff) + sh1) ============
__global__ __launch_bounds__(128) void gemmbn_k(const __half* __restrict__ aggx,
                                                const float* __restrict__ Sd,
                                                const float* __restrict__ Weff,
                                                const float* __restrict__ beff,
                                                const float* __restrict__ sc1,
                                                const float* __restrict__ sh1,
                                                __half* __restrict__ out) {
    __shared__ float xl[16 * 16];
    __shared__ float sdl[16];
    int tid = threadIdx.x;
    int row0 = blockIdx.x * 16;
    if (tid < 64) {
        int r = tid >> 2, k4 = tid & 3;
        int row = row0 + r;
        float4 v4 = make_float4(0.f, 0.f, 0.f, 0.f);
        if (row < N_NODES) {
            __half2 h0 = *(const __half2*)(aggx + row * 16 + k4 * 4);
            __half2 h1 = *(const __half2*)(aggx + row * 16 + k4 * 4 + 2);
            float2 f0 = __half22float2(h0), f1 = __half22float2(h1);
            v4 = make_float4(f0.x, f0.y, f1.x, f1.y);
        }
        *(float4*)(xl + r * 16 + k4 * 4) = v4;
    }
    if (tid < 16) {
        int row = row0 + tid;
        sdl[tid] = (row < N_NODES) ? Sd[row] : 0.f;
    }
    float wv[16];
#pragma unroll
    for (int k = 0; k < 16; k++) wv[k] = Weff[k * 128 + tid];
    float bias = beff[tid];
    float s1 = sc1[tid], h1v = sh1[tid];
    __syncthreads();
    for (int r = 0; r < 16; r++) {
        float acc = sdl[r] * bias;
#pragma unroll
        for (int k = 0; k < 16; k++) acc += xl[r * 16 + k] * wv[k];
        int row = row0 + r;
        if (row < N_NODES) {
            float o = fmaxf(acc * s1 + h1v, 0.f);
            out[row * 128 + tid] = __float2half(o);
        }
    }
}

// ============ MFMA GEMM: in(fp16)[N,128] @ Wsw + b, epilogue scales rows by dinv -> fp16 ============
__global__ __launch_bounds__(256) void gemm128_k(const __half* __restrict__ in,
                                                 const _Float16* __restrict__ Wsw,
                                                 const float* __restrict__ b,
                                                 const float* __restrict__ dinv,
                                                 __half* __restrict__ out) {
    int l = threadIdx.x & 63, w = threadIdx.x >> 6;
    int row0 = blockIdx.x * 64 + w * 16;
    int m = l & 15, q = l >> 4;
    int row = row0 + m;
    bool rok = row < N_NODES;
    const h8v* inp = (const h8v*)in;
    const h8v* wp = (const h8v*)Wsw;
    h8v az = {0, 0, 0, 0, 0, 0, 0, 0};
    h8v a[4];
#pragma unroll
    for (int kb = 0; kb < 4; kb++)
        a[kb] = rok ? inp[(row * 128 + kb * 32 + q * 8) >> 3] : az;
    float dv4[4];
#pragma unroll
    for (int r = 0; r < 4; r++) {
        int orow = row0 + q * 4 + r;
        dv4[r] = (orow < N_NODES) ? dinv[orow] : 0.f;
    }
#pragma unroll
    for (int ct = 0; ct < 8; ct++) {
        f4v acc = {0.f, 0.f, 0.f, 0.f};
#pragma unroll
        for (int kb = 0; kb < 4; kb++) {
            h8v bf = wp[((kb * 128 + ct * 16 + m) * 32 + q * 8) >> 3];
            acc = __builtin_amdgcn_mfma_f32_16x16x32_f16(a[kb], bf, acc, 0, 0, 0);
        }
        int col = ct * 16 + m;
        float bias = b[col];
#pragma unroll
        for (int r = 0; r < 4; r++) {
            int orow = row0 + q * 4 + r;
            if (orow < N_NODES) out[orow * 128 + col] = __float2half((acc[r] + bias) * dv4[r]);
        }
    }
}

// ============ aggregation over dinv-scaled rows t: out = dv*(sum ew*t[s] + t[d]) ============
// MODE 0: + BN+ReLU -> outH fp16.  MODE 1: mu/logvar fp32 outs + zh fp16.
template <int MODE>
__global__ __launch_bounds__(256) void agg_k(const __half* __restrict__ lin,
                                             const unsigned* __restrict__ nodeInfo,
                                             const unsigned* __restrict__ epack,
                                             const float* __restrict__ dinv,
                                             const float* __restrict__ sc,
                                             const float* __restrict__ sh,
                                             __half* __restrict__ outH,
                                             __half* __restrict__ zh,
                                             float* __restrict__ outp) {
    int tid = threadIdx.x;
    int n = blockIdx.x * 4 + (tid >> 6);
    int t = tid & 63;
    const __half2* linv = (const __half2*)lin;
    unsigned info = nodeInfo[n];
    int e0 = (int)(info & 0x1FFFFFu);
    int e1 = e0 + (int)(info >> 21);
    float dv = dinv[n];
    float2 self = __half22float2(linv[n * 64 + t]);
    float ax = self.x, ay = self.y;
    int e = e0;
    for (; e + 16 <= e1; e += 16) {
        unsigned r[16]; __half2 h[16];
#pragma unroll
        for (int j = 0; j < 16; j++) r[j] = epack[e + j];
#pragma unroll
        for (int j = 0; j < 16; j++) h[j] = linv[(int)(r[j] & 0xFFFFu) * 64 + t];
#pragma unroll
        for (int j = 0; j < 16; j++) {
            float w = __half2float(__ushort_as_half((ushort_t)(r[j] >> 16)));
            float2 f = __half22float2(h[j]);
            ax += w * f.x; ay += w * f.y;
        }
    }
    for (; e + 8 <= e1; e += 8) {
        unsigned r[8]; __half2 h[8];
#pragma unroll
        for (int j = 0; j < 8; j++) r[j] = epack[e + j];
#pragma unroll
        for (int j = 0; j < 8; j++) h[j] = linv[(int)(r[j] & 0xFFFFu) * 64 + t];
#pragma unroll
        for (int j = 0; j < 8; j++) {
            float w = __half2float(__ushort_as_half((ushort_t)(r[j] >> 16)));
            float2 f = __half22float2(h[j]);
            ax += w * f.x; ay += w * f.y;
        }
    }
    for (; e < e1; e++) {
        unsigned r = epack[e];
        float w = __half2float(__ushort_as_half((ushort_t)(r >> 16)));
        float2 f = __half22float2(linv[(int)(r & 0xFFFFu) * 64 + t]);
        ax += w * f.x; ay += w * f.y;
    }
    ax *= dv; ay *= dv;
    if (MODE == 0) {
        float2 s2 = *(const float2*)(sc + 2 * t);
        float2 h2 = *(const float2*)(sh + 2 * t);
        float o0 = fmaxf(ax * s2.x + h2.x, 0.f);
        float o1 = fmaxf(ay * s2.y + h2.y, 0.f);
        *(__half2*)(outH + n * 128 + 2 * t) = __floats2half2_rn(o0, o1);
    } else {
        if (t < 32) {
            *(float2*)(outp + OMU_OFF + n * 64 + 2 * t) = make_float2(ax, ay);
            ((__half2*)zh)[n * 32 + t] = __floats2half2_rn(ax, ay);
        } else {
            *(float2*)(outp + OLV_OFF + n * 64 + (2 * t - 64)) = make_float2(ax, ay);
        }
    }
}

// ============ attention via MFMA: p = exp(tanh(zh @ Wa1 + ba1) @ Wa2 + ba2) ============
__global__ __launch_bounds__(256) void att_k(const __half* __restrict__ zh,
                                             const _Float16* __restrict__ Wasw,
                                             const float* __restrict__ ba1,
                                             const float* __restrict__ Wa2,
                                             const float* __restrict__ ba2,
                                             float* __restrict__ p, float* __restrict__ red) {
    __shared__ float rsum[4];
    int l = threadIdx.x & 63, w = threadIdx.x >> 6;
    int row0 = blockIdx.x * 64 + w * 16;
    int m = l & 15, q = l >> 4;
    int row = row0 + m;
    bool rok = row < N_NODES;
    const h8v* zp = (const h8v*)zh;
    const h8v* wp = (const h8v*)Wasw;
    h8v az = {0, 0, 0, 0, 0, 0, 0, 0};
    h8v a[2];
#pragma unroll
    for (int kb = 0; kb < 2; kb++)
        a[kb] = rok ? zp[(row * 64 + kb * 32 + q * 8) >> 3] : az;
    float ysum[4] = {0.f, 0.f, 0.f, 0.f};
#pragma unroll
    for (int ct = 0; ct < 8; ct++) {
        f4v acc = {0.f, 0.f, 0.f, 0.f};
#pragma unroll
        for (int kb = 0; kb < 2; kb++) {
            h8v bf = wp[((kb * 128 + ct * 16 + m) * 32 + q * 8) >> 3];
            acc = __builtin_amdgcn_mfma_f32_16x16x32_f16(a[kb], bf, acc, 0, 0, 0);
        }
        int col = ct * 16 + m;
        float bb = ba1[col], wa2 = Wa2[col];
#pragma unroll
        for (int r = 0; r < 4; r++) ysum[r] += tanhf(acc[r] + bb) * wa2;
    }
#pragma unroll
    for (int off = 1; off < 16; off <<= 1) {
#pragma unroll
        for (int r = 0; r < 4; r++) ysum[r] += __shfl_xor(ysum[r], off, 64);
    }
    float wsum = 0.f;
    if (m == 0) {
        float ba2v = ba2[0];
#pragma unroll
        for (int r = 0; r < 4; r++) {
            int orow = row0 + q * 4 + r;
            if (orow < N_NODES) {
                float pe = expf(ysum[r] + ba2v);
                p[orow] = pe;
                wsum += pe;
            }
        }
    }
    wsum += __shfl_xor(wsum, 16, 64);
    wsum += __shfl_xor(wsum, 32, 64);
    if (l == 0) rsum[w] = wsum;
    __syncthreads();
    if (threadIdx.x == 0)
        atomicAdd(&red[1], rsum[0] + rsum[1] + rsum[2] + rsum[3]);
}

// ============ pooling (4 groups of 64 per block) ============
__global__ __launch_bounds__(256) void pool_k(const __half* __restrict__ zh,
                                              const float* __restrict__ p,
                                              const int* __restrict__ batch,
                                              float* gpool, float* zsum, float* cnt,
                                              const int* __restrict__ flags) {
    int l = threadIdx.x & 63, g = threadIdx.x >> 6;
    int i64 = flags[1];
    int nstart = blockIdx.x * 256 + g * 64;
    float ag = 0.f, az = 0.f, c = 0.f;
    int cur = -1;
    for (int i = 0; i < 64; i++) {
        int n = nstart + i;
        if (n >= N_NODES) break;
        int b = clampi(batch[i64 ? 2 * n : n], 0, NB - 1);
        if (b != cur) {
            if (cur >= 0) {
                atomicAdd(&gpool[cur * 64 + l], ag);
                atomicAdd(&zsum[cur * 64 + l], az);
                if (l == 0) atomicAdd(&cnt[cur], c);
            }
            cur = b; ag = 0.f; az = 0.f; c = 0.f;
        }
        float pe = p[n];
        float zv = __half2float(zh[n * 64 + l]);
        ag += pe * zv; az += zv; c += 1.f;
    }
    if (cur >= 0) {
        atomicAdd(&gpool[cur * 64 + l], ag);
        atomicAdd(&zsum[cur * 64 + l], az);
        if (l == 0) atomicAdd(&cnt[cur], c);
    }
}

// ============ per-graph heads ============
__global__ __launch_bounds__(128) void head_k(const float* __restrict__ gpool,
                                              const float* __restrict__ zsum,
                                              const float* __restrict__ cnt,
                                              const float* __restrict__ red,
                                              const float* Wc1, const float* bc1,
                                              const float* Wc2, const float* bc2,
                                              const float* Wc3, const float* bc3,
                                              const float* Wn1, const float* bn1,
                                              const float* Wn2, const float* bn2,
                                              float* __restrict__ outp) {
    __shared__ float gsh[64], zm[64], p1[128], p2[64], n1[64];
    int b = blockIdx.x, t = threadIdx.x;
    float S = red[1];
    if (t < 64) {
        gsh[t] = gpool[b * 64 + t] / S;
        zm[t] = zsum[b * 64 + t] / fmaxf(cnt[b], 1.f);
    }
    __syncthreads();
    {
        float acc = bc1[t];
        for (int k = 0; k < 64; k++) acc += gsh[k] * Wc1[k * 128 + t];
        p1[t] = fmaxf(acc, 0.f);
    }
    __syncthreads();
    if (t < 64) {
        float acc = bc2[t];
        for (int k = 0; k < 128; k++) acc += p1[k] * Wc2[k * 64 + t];
        p2[t] = fmaxf(acc, 0.f);
    } else {
        int tt = t - 64;
        float acc = bn1[tt];
        for (int k = 0; k < 64; k++) acc += zm[k] * Wn1[k * 64 + tt];
        n1[tt] = fmaxf(acc, 0.f);
    }
    __syncthreads();
    if (t < NC) {
        float acc = bc3[t];
        for (int k = 0; k < 64; k++) acc += p2[k] * Wc3[k * 6 + t];
        outp[OPRED_OFF + b * 6 + t] = acc;
    }
    if (t == 64) {
        float acc = bn2[0];
        for (int k = 0; k < 64; k++) acc += n1[k] * Wn2[k];
        outp[ONOI_OFF + b] = 1.f / (1.f + expf(-acc));
    }
}

extern "C" void kernel_launch(void* const* d_in, const int* in_sizes, int n_in,
                              void* d_out, int out_size, void* d_ws, size_t ws_size,
                              hipStream_t stream) {
    const int*   ei    = (const int*)d_in[1];
    const int*   batch = (const int*)d_in[3];
    const float* x     = (const float*)d_in[0];
    const float* ew    = (const float*)d_in[2];
    const float* Win   = (const float*)d_in[4];
    const float* bin   = (const float*)d_in[5];
    const float* W1    = (const float*)d_in[6];
    const float* b1    = (const float*)d_in[7];
    const float* W2    = (const float*)d_in[8];
    const float* b2    = (const float*)d_in[9];
    const float* Wmu   = (const float*)d_in[10];
    const float* bmu   = (const float*)d_in[11];
    const float* Wlv   = (const float*)d_in[12];
    const float* blv   = (const float*)d_in[13];
    const float* g1    = (const float*)d_in[14];
    const float* be1   = (const float*)d_in[15];
    const float* rm1   = (const float*)d_in[16];
    const float* rv1   = (const float*)d_in[17];
    const float* g2    = (const float*)d_in[18];
    const float* be2   = (const float*)d_in[19];
    const float* rm2   = (const float*)d_in[20];
    const float* rv2   = (const float*)d_in[21];
    const float* Wa1   = (const float*)d_in[22];
    const float* ba1   = (const float*)d_in[23];
    const float* Wa2   = (const float*)d_in[24];
    const float* ba2   = (const float*)d_in[25];
    const float* Wc1   = (const float*)d_in[26];
    const float* bc1   = (const float*)d_in[27];
    const float* Wc2   = (const float*)d_in[28];
    const float* bc2   = (const float*)d_in[29];
    const float* Wc3   = (const float*)d_in[30];
    const float* bc3   = (const float*)d_in[31];
    const float* Wn1   = (const float*)d_in[32];
    const float* bn1   = (const float*)d_in[33];
    const float* Wn2   = (const float*)d_in[34];
    const float* bn2   = (const float*)d_in[35];

    float* outp = (float*)d_out;

    // workspace layout
    char* ws = (char*)d_ws;
    size_t o = 0;
    auto alloc = [&](size_t bytes) { size_t r = o; o = (o + bytes + 511) & ~((size_t)511); return r; };
    int*      flags  = (int*)     (ws + alloc(16));
    float*    dinv   = (float*)   (ws + alloc(N_NODES * 4));
    unsigned* nodeInfo=(unsigned*)(ws + alloc(N_NODES * 4));
    int*      bcnt   = (int*)     (ws + alloc(NBUCK * 4));
    uint2*    recP   = (uint2*)   (ws + alloc((size_t)NBUCK * CAPB * 8));   // 14.5 MB
    unsigned* epack  = (unsigned*)(ws + alloc((size_t)NBUCK * CAPB * 4));   // 7.2 MB
    float*    pexp   = (float*)   (ws + alloc(N_NODES * 4));
    float*    Sd     = (float*)   (ws + alloc(N_NODES * 4));
    __half*   aggx   = (__half*)  (ws + alloc((size_t)N_NODES * 16 * 2));
    _Float16* W2sw   = (_Float16*)(ws + alloc(HF * HF * 2));
    _Float16* Wcsw   = (_Float16*)(ws + alloc(HF * HF * 2));
    _Float16* Wasw   = (_Float16*)(ws + alloc(LF * HF * 2));
    float*    Weff   = (float*)   (ws + alloc(16 * HF * 4));
    float*    beff   = (float*)   (ws + alloc(HF * 4));
    float*    bcat   = (float*)   (ws + alloc(HF * 4));
    float*    sc1    = (float*)   (ws + alloc(HF * 4));
    float*    sh1    = (float*)   (ws + alloc(HF * 4));
    float*    sc2    = (float*)   (ws + alloc(HF * 4));
    float*    sh2    = (float*)   (ws + alloc(HF * 4));
    float*    red    = (float*)   (ws + alloc(16));
    float*    gpool  = (float*)   (ws + alloc(NB * LF * 4));
    float*    zsum   = (float*)   (ws + alloc(NB * LF * 4));
    float*    cnt    = (float*)   (ws + alloc(NB * 4));
    __half*   bufA   = (__half*)  (ws + alloc((size_t)50048 * 128 * 2));
    __half*   bufB   = (__half*)  (ws + alloc((size_t)50048 * 128 * 2));
    __half*   zh     = (__half*)  (ws + alloc((size_t)50048 * 64 * 2));
    (void)ws_size; (void)n_in; (void)in_sizes; (void)out_size;

    const int GN = (N_NODES + 255) / 256;     // 196
    const int GP = (N_EDGES + EPB - 1) / EPB; // 782

    hipLaunchKernelGGL(init_k, dim3(GN), dim3(256), 0, stream,
                       ei, flags, bcnt, gpool, zsum, cnt, red,
                       W2sw, Wcsw, Wasw, bcat, sc1, sh1, sc2, sh2,
                       W2, Wmu, bmu, Wlv, blv, Wa1,
                       g1, be1, rm1, rv1, g2, be2, rm2, rv2);
    hipLaunchKernelGGL(weff_k, dim3(8), dim3(256), 0, stream, Win, bin, W1, b1, Weff, beff);
    hipLaunchKernelGGL(pass1_k, dim3(GP), dim3(256), 0, stream, ei, ew, bcnt, recP, flags);
    hipLaunchKernelGGL(pass2a_k, dim3(NBUCK), dim3(256), 0, stream, recP, bcnt, nodeInfo, dinv);
    hipLaunchKernelGGL(pass2b_k, dim3(NBUCK), dim3(256), 0, stream, recP, bcnt, nodeInfo, epack);

    // encoder
    const int G16 = (N_NODES + 31) / 32;      // 1563
    const int GM  = (N_NODES + 63) / 64;      // 782
    const int GA  = N_NODES / 4;              // 12500
    hipLaunchKernelGGL(agg16_k, dim3(G16), dim3(256), 0, stream, x, epack, nodeInfo, dinv, aggx, Sd);
    hipLaunchKernelGGL(gemmbn_k, dim3(N_NODES / 16), dim3(128), 0, stream,
                       aggx, Sd, Weff, beff, sc1, sh1, bufA);                      // h1 -> A
    hipLaunchKernelGGL(gemm128_k, dim3(GM), dim3(256), 0, stream, bufA, W2sw, b2, dinv, bufB);  // t2 -> B
    hipLaunchKernelGGL((agg_k<0>), dim3(GA), dim3(256), 0, stream,
                       bufB, nodeInfo, epack, dinv, sc2, sh2, bufA, (__half*)nullptr, (float*)nullptr); // h2 -> A
    hipLaunchKernelGGL(gemm128_k, dim3(GM), dim3(256), 0, stream, bufA, Wcsw, bcat, dinv, bufB);  // t3 -> B
    hipLaunchKernelGGL((agg_k<1>), dim3(GA), dim3(256), 0, stream,
                       bufB, nodeInfo, epack, dinv, (const float*)nullptr, (const float*)nullptr,
                       (__half*)nullptr, zh, outp);

    // attention + pooling + heads
    hipLaunchKernelGGL(att_k, dim3(GM), dim3(256), 0, stream, zh, Wasw, ba1, Wa2, ba2, pexp, red);
    hipLaunchKernelGGL(pool_k, dim3(GN), dim3(256), 0, stream, zh, pexp, batch, gpool, zsum, cnt, flags);
    hipLaunchKernelGGL(head_k, dim3(NB), dim3(128), 0, stream,
                       gpool, zsum, cnt, red, Wc1, bc1, Wc2, bc2, Wc3, bc3,
                       Wn1, bn1, Wn2, bn2, outp);
}